// Round 3
// baseline (4486.419 us; speedup 1.0000x reference)
//
#include <hip/hip_runtime.h>
#include <cstddef>
#include <cstdint>

#define T_STEPS 200
#define BB 64
#define SS 8
#define DD 128
#define RR 512
#define ZZ 256
#define HH 1024
#define DT 0.05f
#define SQRT_DT 0.22360679774997896f
#define LOG2PIF 1.8378770664093453f

typedef __attribute__((ext_vector_type(8))) short bf16x8;
typedef __attribute__((ext_vector_type(4))) float f32x4;
#define MFMA __builtin_amdgcn_mfma_f32_16x16x32_bf16

static __device__ __forceinline__ unsigned short f2bf(float x) {
    unsigned int u = __builtin_bit_cast(unsigned int, x);
    u += 0x7fffu + ((u >> 16) & 1u);
    return (unsigned short)(u >> 16);
}
static __device__ __forceinline__ float bf2f(unsigned short h) {
    unsigned int u = ((unsigned int)h) << 16;
    return __builtin_bit_cast(float, u);
}
static __device__ __forceinline__ float fast_tanh(float x) {
    float e = __expf(2.0f * x);
    return 1.0f - 2.0f / (e + 1.0f);
}

// ---------------------------------------------------------------------------
// Pack row-major fp32 W[K][N] into bf16 MFMA B-fragment order:
// frag p = nt*(K/32)*64 + ks*64 + lane holds 8 elems: n = nt*16 + (lane&15),
// k = ks*32 + (lane>>4)*8 + i.
// ---------------------------------------------------------------------------
__global__ void pack_w(const float* __restrict__ src, int K, int N,
                       unsigned short* __restrict__ dst) {
    int total = (K >> 5) * (N >> 4) * 64;
    int p = blockIdx.x * blockDim.x + threadIdx.x;
    if (p >= total) return;
    int lane = p & 63;
    int ksteps = K >> 5;
    int ks = (p >> 6) % ksteps;
    int nt = p / (ksteps << 6);
    int n = (nt << 4) + (lane & 15);
    int k0 = (ks << 5) + ((lane >> 4) << 3);
    uint4 u4;
    unsigned short* tmp = reinterpret_cast<unsigned short*>(&u4);
    for (int i = 0; i < 8; ++i) tmp[i] = f2bf(src[(size_t)(k0 + i) * N + n]);
    *reinterpret_cast<uint4*>(dst + (size_t)p * 8) = u4;
}

// Mt[t,b] = mean over D of M[t,b,:]
__global__ void mt_kernel(const float* __restrict__ M, float* __restrict__ Mt) {
    int wv = (blockIdx.x * blockDim.x + threadIdx.x) >> 6;
    int lane = threadIdx.x & 63;
    if (wv >= T_STEPS * BB) return;
    const float* row = M + (size_t)wv * DD;
    float s = row[lane] + row[lane + 64];
    for (int off = 32; off; off >>= 1) s += __shfl_down(s, off, 64);
    if (lane == 0) Mt[wv] = s * (1.0f / DD);
}

// ---------------------------------------------------------------------------
// Precompute h-only projections (parallel over T*B, 16 rows/block).
// ---------------------------------------------------------------------------
#define PC_GEMM_1024(Asrc, Bp, biasArr, EMIT)                                    \
    {                                                                            \
        f32x4 acc[16];                                                           \
        f32x4 z4 = {0.f, 0.f, 0.f, 0.f};                                        \
        for (int ntl = 0; ntl < 16; ++ntl) acc[ntl] = z4;                        \
        for (int ks = 0; ks < 16; ++ks) {                                        \
            bf16x8 a = *(const bf16x8*)&Asrc[l][(ks << 5) + (q << 3)];           \
            for (int ntl = 0; ntl < 16; ++ntl) {                                 \
                int ntg = (w << 4) + ntl;                                        \
                bf16x8 bb = *(const bf16x8*)(Bp +                                \
                             (((size_t)ntg * 16 + ks) * 64 + lane) * 8);         \
                acc[ntl] = MFMA(a, bb, acc[ntl], 0, 0, 0);                       \
            }                                                                    \
        }                                                                        \
        for (int ntl = 0; ntl < 16; ++ntl) {                                     \
            int n = (((w << 4) + ntl) << 4) + l;                                 \
            float bv = biasArr[n];                                               \
            for (int i = 0; i < 4; ++i) {                                        \
                int rr = (q << 2) + i;                                           \
                float v = acc[ntl][i] + bv;                                      \
                EMIT;                                                            \
            }                                                                    \
        }                                                                        \
    }

__global__ __launch_bounds__(256)
void precompute_kernel(const float* __restrict__ h, const float* __restrict__ hpos,
                       const float* __restrict__ b1d, const float* __restrict__ b1p,
                       const float* __restrict__ b1f, const float* __restrict__ b2f,
                       const unsigned short* __restrict__ W1h_p,
                       const unsigned short* __restrict__ PW1h_p,
                       const unsigned short* __restrict__ DW1_p,
                       const unsigned short* __restrict__ DW2_p,
                       unsigned short* __restrict__ HprojQ,
                       unsigned short* __restrict__ HpprojQ,
                       unsigned short* __restrict__ PprojQ,
                       float* __restrict__ DiffQ) {
    __shared__ unsigned short Ahh[16][RR + 8];
    __shared__ unsigned short Ahp[16][RR + 8];
    __shared__ unsigned short Adh[16][HH + 8];
    const int tid = threadIdx.x;
    const int lane = tid & 63;
    const int w = tid >> 6;
    const int q = lane >> 4;
    const int l = lane & 15;
    const int r0 = blockIdx.x << 4;

    for (int idx = tid; idx < (RR << 4); idx += 256) {
        int r = idx >> 9, c = idx & (RR - 1);
        Ahh[r][c] = f2bf(h[(size_t)(r0 + r) * RR + c]);
        Ahp[r][c] = f2bf(hpos[(size_t)(r0 + r) * RR + c]);
    }
    __syncthreads();

    PC_GEMM_1024(Ahh, W1h_p,  b1d, (HprojQ [(size_t)(r0 + rr) * HH + n] = f2bf(v)));
    PC_GEMM_1024(Ahp, W1h_p,  b1d, (HpprojQ[(size_t)(r0 + rr) * HH + n] = f2bf(v)));
    PC_GEMM_1024(Ahh, PW1h_p, b1p, (PprojQ [(size_t)(r0 + rr) * HH + n] = f2bf(v)));
    PC_GEMM_1024(Ahh, DW1_p,  b1f, (Adh[rr][n] = f2bf(fmaxf(v, 0.f))));
    __syncthreads();

    {
        f32x4 acc[4];
        f32x4 z4 = {0.f, 0.f, 0.f, 0.f};
        for (int ntl = 0; ntl < 4; ++ntl) acc[ntl] = z4;
        for (int ks = 0; ks < 32; ++ks) {
            bf16x8 a = *(const bf16x8*)&Adh[l][(ks << 5) + (q << 3)];
            for (int ntl = 0; ntl < 4; ++ntl) {
                int ntg = (w << 2) + ntl;
                bf16x8 bb = *(const bf16x8*)(DW2_p +
                             (((size_t)ntg * 32 + ks) * 64 + lane) * 8);
                acc[ntl] = MFMA(a, bb, acc[ntl], 0, 0, 0);
            }
        }
        for (int ntl = 0; ntl < 4; ++ntl) {
            int n = (((w << 2) + ntl) << 4) + l;
            float bv = b2f[n];
            for (int i = 0; i < 4; ++i) {
                int rr = (q << 2) + i;
                DiffQ[(size_t)(r0 + rr) * ZZ + n] = __expf(acc[ntl][i] + bv);
            }
        }
    }
}

// ---------------------------------------------------------------------------
// Sequential scan, 4-way model-parallel: 256 blocks (4 per batch element b,
// all 256 CUs). Block j of group b permanently holds:
//   - W1z[:, 256j:256j+256) as 8 B-frags/wave in VGPRs  (128 KB -> 32 VGPR/lane)
//   - W2[256j:256j+256, :]  as B-frags in LDS            (128 KB)
// loaded ONCE -> zero weight re-streaming across 200 steps (was 1 MB/step/CU,
// the measured per-CU L2 BW bound). Block j's G1 hidden slice == its G2
// K-slice, so the only cross-block exchange is the 8x256 partial-drift sum:
// parity-double-buffered global slots + monotonic per-b counter (release add,
// relaxed spin, acquire fence). z-update is recomputed redundantly in all 4
// blocks (identical inputs, identical order -> bitwise identical).
// Group mapping keeps the 4 blocks of b on one XCD under round-robin
// dispatch (blockIdx % 8 == XCD); correctness is agent-scope, placement-free.
// ---------------------------------------------------------------------------
__global__ __launch_bounds__(1024, 4)
void scan_kernel(const float* __restrict__ cov, const float* __restrict__ noise,
                 const float* __restrict__ b2d,
                 const float* __restrict__ cw1, const float* __restrict__ cb1,
                 const float* __restrict__ cw2, const float* __restrict__ cb2,
                 const unsigned short* __restrict__ W1z_p,
                 const unsigned short* __restrict__ W2_p,
                 const unsigned short* __restrict__ HpprojQ,
                 const float* __restrict__ DiffQ,
                 unsigned short* __restrict__ zhist,
                 float* __restrict__ out,
                 float* __restrict__ dpart,
                 unsigned int* __restrict__ cnt) {
    __shared__ unsigned short W2s[8][16][512];            // 128 KiB W2 K-slice
    __shared__ __align__(16) unsigned short Az[8][264];   // z bf16 (8 rows)
    __shared__ __align__(16) unsigned short Ah[8][264];   // hidden slice bf16
    __shared__ float zf[8][256];                          // fp32 master z
    __shared__ float ch[64];

    const int tid  = threadIdx.x;
    const int lane = tid & 63;
    const int w    = tid >> 6;          // 16 waves
    const int q    = lane >> 4;
    const int l    = lane & 15;
    const int xcd  = blockIdx.x & 7;
    const int slot = blockIdx.x >> 3;
    const int j    = slot & 3;          // weight-quarter index
    const int b    = (xcd << 3) + (slot >> 2);

    // --- one-time weight residency ---
    {   // W2 slice -> LDS: frag(nt=w, ks=8j+kk) -> W2s[kk][w][lane*8]
        const unsigned short* src = W2_p + (((size_t)w * 32 + (j << 3)) * 64 + lane) * 8;
        #pragma unroll
        for (int kk = 0; kk < 8; ++kk)
            *(uint4*)&W2s[kk][w][lane << 3] = *(const uint4*)(src + (size_t)kk * 512);
    }
    bf16x8 w1f[8];
    {   // W1z slice -> VGPRs: frag(nt=16j+w, ks)
        const unsigned short* src = W1z_p + (((size_t)((j << 4) + w) * 8) * 64 + lane) * 8;
        #pragma unroll
        for (int ks = 0; ks < 8; ++ks)
            w1f[ks] = *(const bf16x8*)(src + (size_t)ks * 512);
    }

    // --- prologue: z0 = tanh(MLP(cov)), redundant in all 4 blocks ---
    if (tid < 64) {
        float s = cb1[tid];
        for (int c = 0; c < 16; ++c) s += cov[b * 16 + c] * cw1[c * 64 + tid];
        ch[tid] = fmaxf(s, 0.f);
    }
    __syncthreads();
    if (tid < ZZ) {
        float v = cb2[tid];
        for (int jj = 0; jj < 64; ++jj) v += ch[jj] * cw2[jj * ZZ + tid];
        v = fast_tanh(v);
        unsigned short hv = f2bf(v);
        for (int s = 0; s < SS; ++s) {
            zf[s][tid] = v;
            Az[s][tid] = hv;
            if (j == 0) zhist[((size_t)b * SS + s) * ZZ + tid] = hv;  // slot 0
        }
    }

    float b2dv4[4] = {0.f, 0.f, 0.f, 0.f};
    if (w < SS) {
        #pragma unroll
        for (int c4 = 0; c4 < 4; ++c4) b2dv4[c4] = b2d[lane + (c4 << 6)];
    }
    __syncthreads();   // W2s, Az, zf ready

    for (int t = 0; t < T_STEPS; ++t) {
        const size_t tb = (size_t)t * BB + b;
        const int par = t & 1;

        // per-step activations (tiny): hppr slice + eps/diff for z-update
        float hppr = bf2f(HpprojQ[tb * HH + (j << 8) + (w << 4) + l]);
        float eps4[4], dif4[4];
        if (w < SS) {
            #pragma unroll
            for (int c4 = 0; c4 < 4; ++c4) {
                int c = lane + (c4 << 6);
                eps4[c4] = noise[((tb << 3) + w) * ZZ + c];
                dif4[c4] = DiffQ[tb * ZZ + c];
            }
        }

        // ---- G1: hidden slice = relu(HpprojSlice + z @ W1zSlice) ----
        f32x4 acc1 = {0.f, 0.f, 0.f, 0.f};
        #pragma unroll
        for (int ks = 0; ks < 8; ++ks) {
            bf16x8 a = *(const bf16x8*)&Az[l & 7][(ks << 5) + (q << 3)];
            acc1 = MFMA(a, w1f[ks], acc1, 0, 0, 0);
        }
        if (q < 2) {
            #pragma unroll
            for (int i = 0; i < 4; ++i)
                Ah[(q << 2) + i][(w << 4) + l] = f2bf(fmaxf(hppr + acc1[i], 0.f));
        }
        __syncthreads();

        // ---- G2: partial drift = hiddenSlice @ W2Slice ----
        f32x4 acc2 = {0.f, 0.f, 0.f, 0.f};
        #pragma unroll
        for (int kk = 0; kk < 8; ++kk) {
            bf16x8 a  = *(const bf16x8*)&Ah[l & 7][(kk << 5) + (q << 3)];
            bf16x8 wf = *(const bf16x8*)&W2s[kk][w][lane << 3];
            acc2 = MFMA(a, wf, acc2, 0, 0, 0);
        }
        float* dp = dpart + (((size_t)par * BB + b) * 4 + j) * 2048;
        if (q < 2) {
            #pragma unroll
            for (int i = 0; i < 4; ++i)
                dp[((q << 2) + i) * 256 + (w << 4) + l] = acc2[i];
        }
        __syncthreads();   // barrier drains vmem: partial stores at L2

        // ---- cross-block sync: release add, relaxed spin, acquire fence ----
        if (tid == 0) {
            __hip_atomic_fetch_add(&cnt[b], 1u, __ATOMIC_RELEASE,
                                   __HIP_MEMORY_SCOPE_AGENT);
            const unsigned tgt = 4u * (unsigned)(t + 1);
            while (__hip_atomic_load(&cnt[b], __ATOMIC_RELAXED,
                                     __HIP_MEMORY_SCOPE_AGENT) < tgt)
                __builtin_amdgcn_s_sleep(2);
            __threadfence();   // acquire side: invalidate stale cache lines
        }
        __syncthreads();

        // ---- z-update + normalize (redundant, bitwise identical) ----
        if (w < SS) {
            const float* dpb = dpart + (((size_t)par * BB + b) * 4) * 2048 + (w << 8);
            float v[4];
            #pragma unroll
            for (int c4 = 0; c4 < 4; ++c4) {
                int c = lane + (c4 << 6);
                float s0 = dpb[c] + dpb[2048 + c] + dpb[4096 + c] + dpb[6144 + c];
                float po = 0.1f * fast_tanh(s0 + b2dv4[c4]);
                v[c4] = zf[w][c] + DT * po + SQRT_DT * dif4[c4] * eps4[c4];
            }
            float mn = fminf(fminf(v[0], v[1]), fminf(v[2], v[3]));
            float mx = fmaxf(fmaxf(v[0], v[1]), fmaxf(v[2], v[3]));
            for (int off = 32; off; off >>= 1) {
                mn = fminf(mn, __shfl_xor(mn, off, 64));
                mx = fmaxf(mx, __shfl_xor(mx, off, 64));
            }
            float sc = 1.0f / (mx - mn);
            unsigned short hv[4];
            #pragma unroll
            for (int c4 = 0; c4 < 4; ++c4) {
                int c = lane + (c4 << 6);
                float nv = (v[c4] - mn) * sc;
                zf[w][c] = nv;
                hv[c4] = f2bf(nv);
                Az[w][c] = hv[c4];
            }
            if (j == 0) {
                size_t zo = ((size_t)(t + 1) * BB + b) * (SS * ZZ) + (size_t)w * ZZ;
                #pragma unroll
                for (int c4 = 0; c4 < 4; ++c4)
                    zhist[zo + lane + (c4 << 6)] = hv[c4];
            }
        }
        __syncthreads();   // Az/zf ready for next step's G1
    }

    if (j == 0) {
        for (int idx = tid; idx < SS * ZZ; idx += 1024) {
            int s = idx >> 8, n = idx & 255;
            out[((size_t)b * SS + s) * ZZ + n] = zf[s][n];
        }
    }
}

// ---------------------------------------------------------------------------
// Parallel post-pass 1: prior+poster drift recompute -> kld.
// ---------------------------------------------------------------------------
__global__ __launch_bounds__(512, 4)
void post_drift(const unsigned short* __restrict__ zhist,
                const unsigned short* __restrict__ HprojQ,
                const unsigned short* __restrict__ HpprojQ,
                const float* __restrict__ DiffQ, const float* __restrict__ b2d,
                const unsigned short* __restrict__ W1z_p,
                const unsigned short* __restrict__ W2_p,
                float* __restrict__ loss) {
    __shared__ unsigned short Az[4][16][ZZ + 8];
    __shared__ unsigned short Hp[2][4][16][136];
    __shared__ unsigned short ProjS[2][8][128];
    __shared__ float b2d_s[ZZ];
    __shared__ float red[8];
    const int tid = threadIdx.x;
    const int lane = tid & 63;
    const int w = tid >> 6;      // 8 waves
    const int q = lane >> 4;
    const int l = lane & 15;
    const int rt = w & 3;
    const int half = w >> 2;
    const int p0 = blockIdx.x << 3;   // first flat (t*B+b) pair

    for (int idx = tid; idx < 4096; idx += 512) {
        int r = idx >> 6, c4 = (idx & 63) << 2;
        *(ushort4*)&Az[r >> 4][r & 15][c4] =
            *(const ushort4*)&zhist[((size_t)p0 * SS + r) * ZZ + c4];
    }
    if (tid < ZZ) b2d_s[tid] = b2d[tid];

    f32x4 accP[8], accQ[8];
    {
        f32x4 z4 = {0.f, 0.f, 0.f, 0.f};
        #pragma unroll
        for (int jj = 0; jj < 8; ++jj) { accP[jj] = z4; accQ[jj] = z4; }
    }

    for (int nc = 0; nc < 8; ++nc) {
        {
            int path = tid >> 8, rem = tid & 255;
            int pair = rem >> 5, c4 = (rem & 31) << 2;
            const unsigned short* src =
                (path ? HpprojQ : HprojQ) + (size_t)(p0 + pair) * HH + nc * 128 + c4;
            *(ushort4*)&ProjS[path][pair][c4] = *(const ushort4*)src;
        }
        __syncthreads();

        f32x4 za[4];
        {
            f32x4 z4 = {0.f, 0.f, 0.f, 0.f};
            #pragma unroll
            for (int jj = 0; jj < 4; ++jj) za[jj] = z4;
        }
        {
            const unsigned short* wb = W1z_p + lane * 8;
            bf16x8 wq[4];
            #pragma unroll
            for (int f = 0; f < 4; ++f) {
                int ks = f >> 2, jj = f & 3;
                wq[f] = *(const bf16x8*)(wb +
                    ((size_t)((nc * 8 + half * 4 + jj) * 8 + ks)) * 512);
            }
            #pragma unroll
            for (int f = 0; f < 32; ++f) {
                int ks = f >> 2, jj = f & 3;
                bf16x8 a = *(const bf16x8*)&Az[rt][l][(ks << 5) + (q << 3)];
                za[jj] = MFMA(a, wq[f & 3], za[jj], 0, 0, 0);
                if (f < 28) {
                    int f2 = f + 4, ks2 = f2 >> 2, j2 = f2 & 3;
                    wq[f & 3] = *(const bf16x8*)(wb +
                        ((size_t)((nc * 8 + half * 4 + j2) * 8 + ks2)) * 512);
                }
            }
        }
        #pragma unroll
        for (int jj = 0; jj < 4; ++jj) {
            int c = (half * 4 + jj) * 16 + l;
            #pragma unroll
            for (int i = 0; i < 4; ++i) {
                int r = (q << 2) + i;
                int pair = ((rt << 4) + r) >> 3;
                float v = za[jj][i];
                Hp[0][rt][r][c] = f2bf(fmaxf(bf2f(ProjS[0][pair][c]) + v, 0.f));
                Hp[1][rt][r][c] = f2bf(fmaxf(bf2f(ProjS[1][pair][c]) + v, 0.f));
            }
        }
        __syncthreads();

        {
            const unsigned short* wb2 = W2_p + lane * 8;
            bf16x8 wq2[4];
            #pragma unroll
            for (int f = 0; f < 4; ++f) {
                int kk = f >> 3, jj = f & 7;
                wq2[f] = *(const bf16x8*)(wb2 +
                    ((size_t)((half * 8 + jj) * 32 + nc * 4 + kk)) * 512);
            }
            #pragma unroll
            for (int f = 0; f < 32; ++f) {
                int kk = f >> 3, jj = f & 7;
                bf16x8 aP = *(const bf16x8*)&Hp[0][rt][l][(kk << 5) + (q << 3)];
                bf16x8 aQ = *(const bf16x8*)&Hp[1][rt][l][(kk << 5) + (q << 3)];
                accP[jj] = MFMA(aP, wq2[f & 3], accP[jj], 0, 0, 0);
                accQ[jj] = MFMA(aQ, wq2[f & 3], accQ[jj], 0, 0, 0);
                if (f < 28) {
                    int f2 = f + 4, kk2 = f2 >> 3, j2 = f2 & 7;
                    wq2[f & 3] = *(const bf16x8*)(wb2 +
                        ((size_t)((half * 8 + j2) * 32 + nc * 4 + kk2)) * 512);
                }
            }
        }
        __syncthreads();
    }

    float kld_local = 0.f;
    #pragma unroll
    for (int jj = 0; jj < 8; ++jj) {
        int n = ((half << 3) + jj) * 16 + l;
        float bias = b2d_s[n];
        #pragma unroll
        for (int i = 0; i < 4; ++i) {
            int r = (rt << 4) + (q << 2) + i;
            int pair = p0 + (r >> 3);
            float pr = 0.1f * fast_tanh(accP[jj][i] + bias);
            float po = 0.1f * fast_tanh(accQ[jj][i] + bias);
            float e = (pr - po) / DiffQ[(size_t)pair * ZZ + n];
            kld_local += e * e;
        }
    }
    for (int off = 32; off; off >>= 1) kld_local += __shfl_down(kld_local, off, 64);
    if (lane == 0) red[w] = kld_local;
    __syncthreads();
    if (tid == 0) {
        float K = 0.f;
        for (int i = 0; i < 8; ++i) K += red[i];
        float kc = K * (0.5f * DT / (SS * BB));
        atomicAdd(loss + 0, kc);
        atomicAdd(loss + 2, kc);
    }
}

// ---------------------------------------------------------------------------
// Parallel post-pass 2: decoder on z_{t+1} -> recon.
// ---------------------------------------------------------------------------
__global__ __launch_bounds__(512, 4)
void post_dec(const unsigned short* __restrict__ zhist,
              const unsigned short* __restrict__ PprojQ,
              const float* __restrict__ X, const float* __restrict__ MtQ,
              const float* __restrict__ b2p,
              const unsigned short* __restrict__ PW1z_p,
              const unsigned short* __restrict__ PW2_p,
              float* __restrict__ loss) {
    __shared__ unsigned short Az[4][16][ZZ + 8];
    __shared__ unsigned short Hp[4][16][136];
    __shared__ unsigned short ProjS[8][128];
    __shared__ float b2p_s[DD];
    __shared__ float red[8];
    const int tid = threadIdx.x;
    const int lane = tid & 63;
    const int w = tid >> 6;
    const int q = lane >> 4;
    const int l = lane & 15;
    const int rt = w & 3;
    const int half = w >> 2;
    const int p0 = blockIdx.x << 3;

    for (int idx = tid; idx < 4096; idx += 512) {
        int r = idx >> 6, c4 = (idx & 63) << 2;
        *(ushort4*)&Az[r >> 4][r & 15][c4] =
            *(const ushort4*)&zhist[((size_t)(p0 + BB) * SS + r) * ZZ + c4];  // slot t+1
    }
    if (tid < DD) b2p_s[tid] = b2p[tid];

    f32x4 pacc[4];
    {
        f32x4 z4 = {0.f, 0.f, 0.f, 0.f};
        #pragma unroll
        for (int jj = 0; jj < 4; ++jj) pacc[jj] = z4;
    }

    for (int nc = 0; nc < 8; ++nc) {
        if (tid < 256) {
            int pair = tid >> 5, c4 = (tid & 31) << 2;
            *(ushort4*)&ProjS[pair][c4] =
                *(const ushort4*)&PprojQ[(size_t)(p0 + pair) * HH + nc * 128 + c4];
        }
        __syncthreads();

        f32x4 za[4];
        {
            f32x4 z4 = {0.f, 0.f, 0.f, 0.f};
            #pragma unroll
            for (int jj = 0; jj < 4; ++jj) za[jj] = z4;
        }
        {
            const unsigned short* wb = PW1z_p + lane * 8;
            bf16x8 wq[4];
            #pragma unroll
            for (int f = 0; f < 4; ++f) {
                int ks = f >> 2, jj = f & 3;
                wq[f] = *(const bf16x8*)(wb +
                    ((size_t)((nc * 8 + half * 4 + jj) * 8 + ks)) * 512);
            }
            #pragma unroll
            for (int f = 0; f < 32; ++f) {
                int ks = f >> 2, jj = f & 3;
                bf16x8 a = *(const bf16x8*)&Az[rt][l][(ks << 5) + (q << 3)];
                za[jj] = MFMA(a, wq[f & 3], za[jj], 0, 0, 0);
                if (f < 28) {
                    int f2 = f + 4, ks2 = f2 >> 2, j2 = f2 & 3;
                    wq[f & 3] = *(const bf16x8*)(wb +
                        ((size_t)((nc * 8 + half * 4 + j2) * 8 + ks2)) * 512);
                }
            }
        }
        #pragma unroll
        for (int jj = 0; jj < 4; ++jj) {
            int c = (half * 4 + jj) * 16 + l;
            #pragma unroll
            for (int i = 0; i < 4; ++i) {
                int r = (q << 2) + i;
                int pair = ((rt << 4) + r) >> 3;
                Hp[rt][r][c] = f2bf(fmaxf(bf2f(ProjS[pair][c]) + za[jj][i], 0.f));
            }
        }
        __syncthreads();

        {
            const unsigned short* wb2 = PW2_p + lane * 8;
            bf16x8 wq2[4];
            #pragma unroll
            for (int f = 0; f < 4; ++f) {
                int kk = f >> 2, jj = f & 3;
                wq2[f] = *(const bf16x8*)(wb2 +
                    ((size_t)((half * 4 + jj) * 32 + nc * 4 + kk)) * 512);
            }
            #pragma unroll
            for (int f = 0; f < 16; ++f) {
                int kk = f >> 2, jj = f & 3;
                bf16x8 a = *(const bf16x8*)&Hp[rt][l][(kk << 5) + (q << 3)];
                pacc[jj] = MFMA(a, wq2[f & 3], pacc[jj], 0, 0, 0);
                if (f < 12) {
                    int f2 = f + 4, kk2 = f2 >> 2, j2 = f2 & 3;
                    wq2[f & 3] = *(const bf16x8*)(wb2 +
                        ((size_t)((half * 4 + j2) * 32 + nc * 4 + kk2)) * 512);
                }
            }
        }
        __syncthreads();
    }

    float rl = 0.f;
    #pragma unroll
    for (int jj = 0; jj < 4; ++jj) {
        int n = ((half << 2) + jj) * 16 + l;
        float bias = b2p_s[n];
        #pragma unroll
        for (int i = 0; i < 4; ++i) {
            int r = (rt << 4) + (q << 2) + i;
            int pair = p0 + (r >> 3);
            float p = pacc[jj][i] + bias;
            float d = X[(size_t)pair * DD + n] - p;
            rl += (0.5f * (LOG2PIF + d * d)) * MtQ[pair];
        }
    }
    rl *= 1.0f / (SS * BB);
    for (int off = 32; off; off >>= 1) rl += __shfl_down(rl, off, 64);
    if (lane == 0) red[w] = rl;
    __syncthreads();
    if (tid == 0) {
        float R = 0.f;
        for (int i = 0; i < 8; ++i) R += red[i];
        atomicAdd(loss + 0, R);
        atomicAdd(loss + 1, R);
    }
}

extern "C" void kernel_launch(void* const* d_in, const int* in_sizes, int n_in,
                              void* d_out, int out_size, void* d_ws, size_t ws_size,
                              hipStream_t stream) {
    (void)in_sizes; (void)n_in; (void)ws_size;
    const float* X         = (const float*)d_in[0];
    const float* M         = (const float*)d_in[1];
    const float* cov       = (const float*)d_in[2];
    const float* path_h    = (const float*)d_in[3];
    const float* path_hpos = (const float*)d_in[4];
    const float* noise     = (const float*)d_in[5];
    const float* drift_w1  = (const float*)d_in[6];
    const float* drift_b1  = (const float*)d_in[7];
    const float* drift_w2  = (const float*)d_in[8];
    const float* drift_b2  = (const float*)d_in[9];
    const float* diff_w1   = (const float*)d_in[10];
    const float* diff_b1   = (const float*)d_in[11];
    const float* diff_w2   = (const float*)d_in[12];
    const float* diff_b2   = (const float*)d_in[13];
    const float* p_w1      = (const float*)d_in[14];
    const float* p_b1      = (const float*)d_in[15];
    const float* p_w2      = (const float*)d_in[16];
    const float* p_b2      = (const float*)d_in[17];
    const float* cov_w1    = (const float*)d_in[18];
    const float* cov_b1    = (const float*)d_in[19];
    const float* cov_w2    = (const float*)d_in[20];
    const float* cov_b2    = (const float*)d_in[21];

    char* ws = (char*)d_ws;
    size_t off = 0;
    auto alloc = [&](size_t bytes) {
        void* p = ws + off;
        off = (off + bytes + 255) & ~(size_t)255;
        return p;
    };
    unsigned short* HprojQ  = (unsigned short*)alloc((size_t)T_STEPS * BB * HH * 2);
    unsigned short* HpprojQ = (unsigned short*)alloc((size_t)T_STEPS * BB * HH * 2);
    unsigned short* PprojQ  = (unsigned short*)alloc((size_t)T_STEPS * BB * HH * 2);
    float*          DiffQ   = (float*)alloc((size_t)T_STEPS * BB * ZZ * 4);
    float*          MtQ     = (float*)alloc((size_t)T_STEPS * BB * 4);
    unsigned short* zhist   = (unsigned short*)alloc((size_t)(T_STEPS + 1) * BB * SS * ZZ * 2);
    unsigned short* W1z_p   = (unsigned short*)alloc((size_t)ZZ * HH * 2);
    unsigned short* W2_p    = (unsigned short*)alloc((size_t)HH * ZZ * 2);
    unsigned short* PW1z_p  = (unsigned short*)alloc((size_t)ZZ * HH * 2);
    unsigned short* PW2_p   = (unsigned short*)alloc((size_t)HH * DD * 2);
    unsigned short* W1h_p   = (unsigned short*)alloc((size_t)RR * HH * 2);
    unsigned short* PW1h_p  = (unsigned short*)alloc((size_t)RR * HH * 2);
    unsigned short* DW1_p   = (unsigned short*)alloc((size_t)RR * HH * 2);
    unsigned short* DW2_p   = (unsigned short*)alloc((size_t)HH * ZZ * 2);
    float*          dpart   = (float*)alloc((size_t)2 * BB * 4 * SS * ZZ * 4);
    unsigned int*   cntW    = (unsigned int*)alloc((size_t)BB * 4);

    hipMemsetAsync(d_out, 0, (size_t)out_size * sizeof(float), stream);
    hipMemsetAsync(cntW, 0, (size_t)BB * 4, stream);

    auto packLaunch = [&](const float* src, int K, int N, unsigned short* dst) {
        int total = (K / 32) * (N / 16) * 64;
        pack_w<<<(total + 255) / 256, 256, 0, stream>>>(src, K, N, dst);
    };
    packLaunch(drift_w1 + (size_t)RR * HH, ZZ, HH, W1z_p);
    packLaunch(drift_w2,                   HH, ZZ, W2_p);
    packLaunch(p_w1 + (size_t)RR * HH,     ZZ, HH, PW1z_p);
    packLaunch(p_w2,                       HH, DD, PW2_p);
    packLaunch(drift_w1, RR, HH, W1h_p);
    packLaunch(p_w1,     RR, HH, PW1h_p);
    packLaunch(diff_w1,  RR, HH, DW1_p);
    packLaunch(diff_w2,  HH, ZZ, DW2_p);

    mt_kernel<<<(T_STEPS * BB * 64) / 256, 256, 0, stream>>>(M, MtQ);

    precompute_kernel<<<(T_STEPS * BB) / 16, 256, 0, stream>>>(
        path_h, path_hpos, drift_b1, p_b1, diff_b1, diff_b2,
        W1h_p, PW1h_p, DW1_p, DW2_p, HprojQ, HpprojQ, PprojQ, DiffQ);

    float* outp = (float*)d_out;
    float* loss = outp + (size_t)BB * SS * ZZ;

    scan_kernel<<<BB * 4, 1024, 0, stream>>>(
        cov, noise, drift_b2, cov_w1, cov_b1, cov_w2, cov_b2,
        W1z_p, W2_p, HpprojQ, DiffQ, zhist, outp, dpart, cntW);

    post_drift<<<(T_STEPS * BB) / 8, 512, 0, stream>>>(
        zhist, HprojQ, HpprojQ, DiffQ, drift_b2, W1z_p, W2_p, loss);

    post_dec<<<(T_STEPS * BB) / 8, 512, 0, stream>>>(
        zhist, PprojQ, X, MtQ, p_b2, PW1z_p, PW2_p, loss);
}

// Round 4
// 2997.553 us; speedup vs baseline: 1.4967x; 1.4967x over previous
//
#include <hip/hip_runtime.h>
#include <cstddef>
#include <cstdint>

#define T_STEPS 200
#define BB 64
#define SS 8
#define DD 128
#define RR 512
#define ZZ 256
#define HH 1024
#define DT 0.05f
#define SQRT_DT 0.22360679774997896f
#define LOG2PIF 1.8378770664093453f

typedef __attribute__((ext_vector_type(8))) short bf16x8;
typedef __attribute__((ext_vector_type(4))) float f32x4;
typedef long f8x8;   // 8 fp8-e4m3 values (2 VGPRs)
#define MFMA __builtin_amdgcn_mfma_f32_16x16x32_bf16
#define MFMA8 __builtin_amdgcn_mfma_f32_16x16x32_fp8_fp8

static __device__ __forceinline__ unsigned short f2bf(float x) {
    unsigned int u = __builtin_bit_cast(unsigned int, x);
    u += 0x7fffu + ((u >> 16) & 1u);
    return (unsigned short)(u >> 16);
}
static __device__ __forceinline__ float bf2f(unsigned short h) {
    unsigned int u = ((unsigned int)h) << 16;
    return __builtin_bit_cast(float, u);
}
static __device__ __forceinline__ float fast_tanh(float x) {
    float e = __expf(2.0f * x);
    return 1.0f - 2.0f / (e + 1.0f);
}
// f32 -> fp8 e4m3 via HW converter (consistent with gfx950 fp8 MFMA decode).
static __device__ __forceinline__ unsigned char f2fp8(float x) {
    unsigned int r = 0;
    asm volatile("v_cvt_pk_fp8_f32 %0, %1, %1" : "+v"(r) : "v"(x));
    return (unsigned char)(r & 0xffu);
}

// Issue a 16B/lane load the compiler's waitcnt pass can't see.
static __device__ __forceinline__ void aload(bf16x8& d,
                                             const unsigned short* base, int off) {
    asm volatile("global_load_dwordx4 %0, %1, %2"
                 : "=v"(d) : "v"(off), "s"(base));
}
// 8B/lane fp8-fragment load, same hidden-queue discipline.
static __device__ __forceinline__ void aload8(f8x8& d,
                                              const unsigned char* base, int off) {
    asm volatile("global_load_dwordx2 %0, %1, %2"
                 : "=v"(d) : "v"(off), "s"(base));
}
// Fence: frag v is ready once <=7 vmem ops are outstanding (depth-8 queue).
static __device__ __forceinline__ void vfence8(f8x8& v) {
    asm volatile("s_waitcnt vmcnt(7)" : "+v"(v));
}

// ---------------------------------------------------------------------------
// Pack row-major fp32 W[K][N] into bf16 MFMA B-fragment order:
// frag p = nt*(K/32)*64 + ks*64 + lane holds 8 elems: n = nt*16 + (lane&15),
// k = ks*32 + (lane>>4)*8 + i.
// ---------------------------------------------------------------------------
__global__ void pack_w(const float* __restrict__ src, int K, int N,
                       unsigned short* __restrict__ dst) {
    int total = (K >> 5) * (N >> 4) * 64;
    int p = blockIdx.x * blockDim.x + threadIdx.x;
    if (p >= total) return;
    int lane = p & 63;
    int ksteps = K >> 5;
    int ks = (p >> 6) % ksteps;
    int nt = p / (ksteps << 6);
    int n = (nt << 4) + (lane & 15);
    int k0 = (ks << 5) + ((lane >> 4) << 3);
    uint4 u4;
    unsigned short* tmp = reinterpret_cast<unsigned short*>(&u4);
    for (int i = 0; i < 8; ++i) tmp[i] = f2bf(src[(size_t)(k0 + i) * N + n]);
    *reinterpret_cast<uint4*>(dst + (size_t)p * 8) = u4;
}

// Same fragment order, fp8-e4m3 payload (8 B per lane-frag).
__global__ void pack_w_fp8(const float* __restrict__ src, int K, int N,
                           unsigned char* __restrict__ dst) {
    int total = (K >> 5) * (N >> 4) * 64;
    int p = blockIdx.x * blockDim.x + threadIdx.x;
    if (p >= total) return;
    int lane = p & 63;
    int ksteps = K >> 5;
    int ks = (p >> 6) % ksteps;
    int nt = p / (ksteps << 6);
    int n = (nt << 4) + (lane & 15);
    int k0 = (ks << 5) + ((lane >> 4) << 3);
    unsigned long long acc = 0ull;
    for (int i = 0; i < 8; ++i)
        acc |= (unsigned long long)f2fp8(src[(size_t)(k0 + i) * N + n]) << (8 * i);
    *reinterpret_cast<unsigned long long*>(dst + (size_t)p * 8) = acc;
}

// Mt[t,b] = mean over D of M[t,b,:]
__global__ void mt_kernel(const float* __restrict__ M, float* __restrict__ Mt) {
    int wv = (blockIdx.x * blockDim.x + threadIdx.x) >> 6;
    int lane = threadIdx.x & 63;
    if (wv >= T_STEPS * BB) return;
    const float* row = M + (size_t)wv * DD;
    float s = row[lane] + row[lane + 64];
    for (int off = 32; off; off >>= 1) s += __shfl_down(s, off, 64);
    if (lane == 0) Mt[wv] = s * (1.0f / DD);
}

// ---------------------------------------------------------------------------
// Precompute h-only projections (parallel over T*B, 16 rows/block).
// ---------------------------------------------------------------------------
#define PC_GEMM_1024(Asrc, Bp, biasArr, EMIT)                                    \
    {                                                                            \
        f32x4 acc[16];                                                           \
        f32x4 z4 = {0.f, 0.f, 0.f, 0.f};                                        \
        for (int ntl = 0; ntl < 16; ++ntl) acc[ntl] = z4;                        \
        for (int ks = 0; ks < 16; ++ks) {                                        \
            bf16x8 a = *(const bf16x8*)&Asrc[l][(ks << 5) + (q << 3)];           \
            for (int ntl = 0; ntl < 16; ++ntl) {                                 \
                int ntg = (w << 4) + ntl;                                        \
                bf16x8 bb = *(const bf16x8*)(Bp +                                \
                             (((size_t)ntg * 16 + ks) * 64 + lane) * 8);         \
                acc[ntl] = MFMA(a, bb, acc[ntl], 0, 0, 0);                       \
            }                                                                    \
        }                                                                        \
        for (int ntl = 0; ntl < 16; ++ntl) {                                     \
            int n = (((w << 4) + ntl) << 4) + l;                                 \
            float bv = biasArr[n];                                               \
            for (int i = 0; i < 4; ++i) {                                        \
                int rr = (q << 2) + i;                                           \
                float v = acc[ntl][i] + bv;                                      \
                EMIT;                                                            \
            }                                                                    \
        }                                                                        \
    }

__global__ __launch_bounds__(256)
void precompute_kernel(const float* __restrict__ h, const float* __restrict__ hpos,
                       const float* __restrict__ b1d, const float* __restrict__ b1p,
                       const float* __restrict__ b1f, const float* __restrict__ b2f,
                       const unsigned short* __restrict__ W1h_p,
                       const unsigned short* __restrict__ PW1h_p,
                       const unsigned short* __restrict__ DW1_p,
                       const unsigned short* __restrict__ DW2_p,
                       unsigned short* __restrict__ HprojQ,
                       unsigned short* __restrict__ HpprojQ,
                       unsigned short* __restrict__ PprojQ,
                       float* __restrict__ DiffQ) {
    __shared__ unsigned short Ahh[16][RR + 8];
    __shared__ unsigned short Ahp[16][RR + 8];
    __shared__ unsigned short Adh[16][HH + 8];
    const int tid = threadIdx.x;
    const int lane = tid & 63;
    const int w = tid >> 6;
    const int q = lane >> 4;
    const int l = lane & 15;
    const int r0 = blockIdx.x << 4;

    for (int idx = tid; idx < (RR << 4); idx += 256) {
        int r = idx >> 9, c = idx & (RR - 1);
        Ahh[r][c] = f2bf(h[(size_t)(r0 + r) * RR + c]);
        Ahp[r][c] = f2bf(hpos[(size_t)(r0 + r) * RR + c]);
    }
    __syncthreads();

    PC_GEMM_1024(Ahh, W1h_p,  b1d, (HprojQ [(size_t)(r0 + rr) * HH + n] = f2bf(v)));
    PC_GEMM_1024(Ahp, W1h_p,  b1d, (HpprojQ[(size_t)(r0 + rr) * HH + n] = f2bf(v)));
    PC_GEMM_1024(Ahh, PW1h_p, b1p, (PprojQ [(size_t)(r0 + rr) * HH + n] = f2bf(v)));
    PC_GEMM_1024(Ahh, DW1_p,  b1f, (Adh[rr][n] = f2bf(fmaxf(v, 0.f))));
    __syncthreads();

    {
        f32x4 acc[4];
        f32x4 z4 = {0.f, 0.f, 0.f, 0.f};
        for (int ntl = 0; ntl < 4; ++ntl) acc[ntl] = z4;
        for (int ks = 0; ks < 32; ++ks) {
            bf16x8 a = *(const bf16x8*)&Adh[l][(ks << 5) + (q << 3)];
            for (int ntl = 0; ntl < 4; ++ntl) {
                int ntg = (w << 2) + ntl;
                bf16x8 bb = *(const bf16x8*)(DW2_p +
                             (((size_t)ntg * 32 + ks) * 64 + lane) * 8);
                acc[ntl] = MFMA(a, bb, acc[ntl], 0, 0, 0);
            }
        }
        for (int ntl = 0; ntl < 4; ++ntl) {
            int n = (((w << 2) + ntl) << 4) + l;
            float bv = b2f[n];
            for (int i = 0; i < 4; ++i) {
                int rr = (q << 2) + i;
                DiffQ[(size_t)(r0 + rr) * ZZ + n] = __expf(acc[ntl][i] + bv);
            }
        }
    }
}

// ---------------------------------------------------------------------------
// Sequential scan, posterior path only. 64 blocks x 1024 thr (16 waves).
// Round-2 structure (verified 1947 us) with the weight stream halved to
// fp8-e4m3: fragments are 8 B/lane, consumed by mfma_f32_16x16x32_fp8_fp8.
// Activations (z, hidden) quantized to fp8 in LDS at write time; master z,
// Hpproj accumulate, Euler update, normalize all stay f32/bf16.
// Weight B-fragments streamed into depth-8 VGPR queues via inline-asm
// global_load_dwordx2 + manual vmcnt(7) fences (invisible to the compiler's
// waitcnt pass -> no forced drains). Cross-stage/cross-step prefetch in the
// loop tails; barriers merely complete in-flight loads (regs keep the data).
// ---------------------------------------------------------------------------
__global__ __launch_bounds__(1024)
void scan_kernel(const float* __restrict__ cov, const float* __restrict__ noise,
                 const float* __restrict__ b2d,
                 const float* __restrict__ cw1, const float* __restrict__ cb1,
                 const float* __restrict__ cw2, const float* __restrict__ cb2,
                 const unsigned char* __restrict__ W1z_f8,
                 const unsigned char* __restrict__ W2_f8,
                 const unsigned short* __restrict__ HpprojQ,
                 const float* __restrict__ DiffQ,
                 unsigned short* __restrict__ zhist,
                 float* __restrict__ out) {
    __shared__ __align__(8) unsigned char Az8[8][272];    // z fp8 (8 rows)
    __shared__ __align__(8) unsigned char Ah8[8][1040];   // poster hidden fp8
    __shared__ float zf[8][256];                          // fp32 master z
    __shared__ float ch[64];

    const int tid = threadIdx.x;
    const int lane = tid & 63;
    const int w = tid >> 6;   // 16 waves
    const int q = lane >> 4;
    const int l = lane & 15;
    const int b = blockIdx.x;

    // shared per-wave byte offset into both packed fp8 weight streams
    const int baseoff8 = (w << 14) + (lane << 3);
    // G1 frag j (j=ks*4+ntl): baseoff8 + ntl*4096 + ks*512
    // G2 frag j (j=kk):       baseoff8 + kk*512

    // --- prologue: z0 = tanh(MLP(cov)) ---
    if (tid < 64) {
        float s = cb1[tid];
        for (int c = 0; c < 16; ++c) s += cov[b * 16 + c] * cw1[c * 64 + tid];
        ch[tid] = fmaxf(s, 0.f);
    }
    __syncthreads();
    if (tid < ZZ) {
        float v = cb2[tid];
        for (int j = 0; j < 64; ++j) v += ch[j] * cw2[j * ZZ + tid];
        v = fast_tanh(v);
        unsigned short hv = f2bf(v);
        unsigned char zb = f2fp8(v);
        for (int s = 0; s < SS; ++s) {
            zf[s][tid] = v;
            Az8[s][tid] = zb;
            zhist[((size_t)b * SS + s) * ZZ + tid] = hv;   // slot 0
        }
    }

    float b2dr = 0.f;
    if (q < 2) b2dr = b2d[(w << 4) + l];

    // preload G1 frags 0..7 for t=0
    f8x8 fq[8];
    #pragma unroll
    for (int j = 0; j < 8; ++j)
        aload8(fq[j], W1z_f8, baseoff8 + (j & 3) * 4096 + (j >> 2) * 512);

    for (int t = 0; t < T_STEPS; ++t) {
        const size_t tb = (size_t)t * BB + b;

        // per-step scalars (all lanes; upper half duplicates) — pinned complete
        float eps[4], hppr[4], difr;
        const int sq = q & 1;
        #pragma unroll
        for (int i = 0; i < 4; ++i)
            eps[i] = noise[((tb << 3) + (sq << 2) + i) * ZZ + (w << 4) + l];
        #pragma unroll
        for (int ntl = 0; ntl < 4; ++ntl)
            hppr[ntl] = bf2f(HpprojQ[tb * HH + ((w << 2) + ntl) * 16 + l]);
        difr = DiffQ[tb * ZZ + (w << 4) + l];
        asm volatile("" :: "v"(eps[0]), "v"(eps[1]), "v"(eps[2]), "v"(eps[3]),
                           "v"(hppr[0]), "v"(hppr[1]), "v"(hppr[2]), "v"(hppr[3]),
                           "v"(difr));
        __syncthreads();   // Az8 from prev normalize ready

        // ---- G1: hidden = relu(Hpp + z @ W1z); 32 frags, tail prefetches G2
        f32x4 acc1[4];
        {
            f32x4 z4 = {0.f, 0.f, 0.f, 0.f};
            #pragma unroll
            for (int ntl = 0; ntl < 4; ++ntl) acc1[ntl] = z4;
        }
        f8x8 a1 = 0;
        #pragma unroll
        for (int j = 0; j < 32; ++j) {
            const int ks = j >> 2, ntl = j & 3;
            vfence8(fq[j & 7]);
            if (ntl == 0) a1 = *(const f8x8*)&Az8[l & 7][(ks << 5) + (q << 3)];
            acc1[ntl] = MFMA8(a1, fq[j & 7], acc1[ntl], 0, 0, 0);
            if (j < 24) {
                const int j2 = j + 8;
                aload8(fq[j & 7], W1z_f8, baseoff8 + (j2 & 3) * 4096 + (j2 >> 2) * 512);
            } else {
                aload8(fq[j & 7], W2_f8, baseoff8 + (j - 24) * 512);
            }
        }
        if (q < 2) {
            #pragma unroll
            for (int ntl = 0; ntl < 4; ++ntl) {
                int n = (((w << 2) + ntl) << 4) + l;
                #pragma unroll
                for (int i = 0; i < 4; ++i)
                    Ah8[(q << 2) + i][n] = f2fp8(fmaxf(hppr[ntl] + acc1[ntl][i], 0.f));
            }
        }
        __syncthreads();

        // ---- G2: drift_pre = hidden @ W2; 32 frags, tail prefetches next G1
        f32x4 a2a = {0.f, 0.f, 0.f, 0.f};
        f32x4 a2b = {0.f, 0.f, 0.f, 0.f};
        #pragma unroll
        for (int j = 0; j < 32; ++j) {
            vfence8(fq[j & 7]);
            f8x8 a2 = *(const f8x8*)&Ah8[l & 7][(j << 5) + (q << 3)];
            if (j & 1) a2b = MFMA8(a2, fq[j & 7], a2b, 0, 0, 0);
            else       a2a = MFMA8(a2, fq[j & 7], a2a, 0, 0, 0);
            if (j < 24) {
                aload8(fq[j & 7], W2_f8, baseoff8 + (j + 8) * 512);
            } else {
                const int j2 = j - 24;
                aload8(fq[j & 7], W1z_f8, baseoff8 + (j2 & 3) * 4096 + (j2 >> 2) * 512);
            }
        }
        if (q < 2) {
            int n = (w << 4) + l;
            #pragma unroll
            for (int i = 0; i < 4; ++i) {
                int s = (q << 2) + i;
                float pre = a2a[i] + a2b[i] + b2dr;
                float po = 0.1f * fast_tanh(pre);
                zf[s][n] += DT * po + SQRT_DT * difr * eps[i];
            }
        }
        __syncthreads();

        // ---- normalize (waves 0-7; wave s handles row s) + log zhist
        if (w < SS) {
            float v0 = zf[w][lane], v1 = zf[w][lane + 64];
            float v2 = zf[w][lane + 128], v3 = zf[w][lane + 192];
            float mn = fminf(fminf(v0, v1), fminf(v2, v3));
            float mx = fmaxf(fmaxf(v0, v1), fmaxf(v2, v3));
            for (int off = 32; off; off >>= 1) {
                mn = fminf(mn, __shfl_xor(mn, off, 64));
                mx = fmaxf(mx, __shfl_xor(mx, off, 64));
            }
            float sc = 1.0f / (mx - mn);
            v0 = (v0 - mn) * sc; v1 = (v1 - mn) * sc;
            v2 = (v2 - mn) * sc; v3 = (v3 - mn) * sc;
            zf[w][lane] = v0; zf[w][lane + 64] = v1;
            zf[w][lane + 128] = v2; zf[w][lane + 192] = v3;
            Az8[w][lane] = f2fp8(v0); Az8[w][lane + 64] = f2fp8(v1);
            Az8[w][lane + 128] = f2fp8(v2); Az8[w][lane + 192] = f2fp8(v3);
            unsigned short h0 = f2bf(v0), h1 = f2bf(v1), h2 = f2bf(v2), h3 = f2bf(v3);
            size_t zo = ((size_t)(t + 1) * BB + b) * (SS * ZZ) + (size_t)w * ZZ;
            volatile unsigned short* zh = (volatile unsigned short*)zhist;
            zh[zo + lane] = h0; zh[zo + lane + 64] = h1;
            zh[zo + lane + 128] = h2; zh[zo + lane + 192] = h3;
        }
        // loop-top barrier separates Az8 writes from next G1 reads
    }
    __syncthreads();

    for (int idx = tid; idx < SS * ZZ; idx += 1024) {
        int s = idx >> 8, n = idx & 255;
        out[((size_t)b * SS + s) * ZZ + n] = zf[s][n];
    }
}

// ---------------------------------------------------------------------------
// Parallel post-pass 1: prior+poster drift recompute -> kld. (bf16, unchanged)
// ---------------------------------------------------------------------------
__global__ __launch_bounds__(512, 4)
void post_drift(const unsigned short* __restrict__ zhist,
                const unsigned short* __restrict__ HprojQ,
                const unsigned short* __restrict__ HpprojQ,
                const float* __restrict__ DiffQ, const float* __restrict__ b2d,
                const unsigned short* __restrict__ W1z_p,
                const unsigned short* __restrict__ W2_p,
                float* __restrict__ loss) {
    __shared__ unsigned short Az[4][16][ZZ + 8];
    __shared__ unsigned short Hp[2][4][16][136];
    __shared__ unsigned short ProjS[2][8][128];
    __shared__ float b2d_s[ZZ];
    __shared__ float red[8];
    const int tid = threadIdx.x;
    const int lane = tid & 63;
    const int w = tid >> 6;      // 8 waves
    const int q = lane >> 4;
    const int l = lane & 15;
    const int rt = w & 3;
    const int half = w >> 2;
    const int p0 = blockIdx.x << 3;   // first flat (t*B+b) pair

    for (int idx = tid; idx < 4096; idx += 512) {
        int r = idx >> 6, c4 = (idx & 63) << 2;
        *(ushort4*)&Az[r >> 4][r & 15][c4] =
            *(const ushort4*)&zhist[((size_t)p0 * SS + r) * ZZ + c4];
    }
    if (tid < ZZ) b2d_s[tid] = b2d[tid];

    f32x4 accP[8], accQ[8];
    {
        f32x4 z4 = {0.f, 0.f, 0.f, 0.f};
        #pragma unroll
        for (int j = 0; j < 8; ++j) { accP[j] = z4; accQ[j] = z4; }
    }

    for (int nc = 0; nc < 8; ++nc) {
        {
            int path = tid >> 8, rem = tid & 255;
            int pair = rem >> 5, c4 = (rem & 31) << 2;
            const unsigned short* src =
                (path ? HpprojQ : HprojQ) + (size_t)(p0 + pair) * HH + nc * 128 + c4;
            *(ushort4*)&ProjS[path][pair][c4] = *(const ushort4*)src;
        }
        __syncthreads();

        f32x4 za[4];
        {
            f32x4 z4 = {0.f, 0.f, 0.f, 0.f};
            #pragma unroll
            for (int j = 0; j < 4; ++j) za[j] = z4;
        }
        {
            const unsigned short* wb = W1z_p + lane * 8;
            bf16x8 wq[4];
            #pragma unroll
            for (int f = 0; f < 4; ++f) {
                int ks = f >> 2, j = f & 3;
                wq[f] = *(const bf16x8*)(wb +
                    ((size_t)((nc * 8 + half * 4 + j) * 8 + ks)) * 512);
            }
            #pragma unroll
            for (int f = 0; f < 32; ++f) {
                int ks = f >> 2, j = f & 3;
                bf16x8 a = *(const bf16x8*)&Az[rt][l][(ks << 5) + (q << 3)];
                za[j] = MFMA(a, wq[f & 3], za[j], 0, 0, 0);
                if (f < 28) {
                    int f2 = f + 4, ks2 = f2 >> 2, j2 = f2 & 3;
                    wq[f & 3] = *(const bf16x8*)(wb +
                        ((size_t)((nc * 8 + half * 4 + j2) * 8 + ks2)) * 512);
                }
            }
        }
        #pragma unroll
        for (int j = 0; j < 4; ++j) {
            int c = (half * 4 + j) * 16 + l;
            #pragma unroll
            for (int i = 0; i < 4; ++i) {
                int r = (q << 2) + i;
                int pair = ((rt << 4) + r) >> 3;
                float v = za[j][i];
                Hp[0][rt][r][c] = f2bf(fmaxf(bf2f(ProjS[0][pair][c]) + v, 0.f));
                Hp[1][rt][r][c] = f2bf(fmaxf(bf2f(ProjS[1][pair][c]) + v, 0.f));
            }
        }
        __syncthreads();

        {
            const unsigned short* wb2 = W2_p + lane * 8;
            bf16x8 wq2[4];
            #pragma unroll
            for (int f = 0; f < 4; ++f) {
                int kk = f >> 3, j = f & 7;
                wq2[f] = *(const bf16x8*)(wb2 +
                    ((size_t)((half * 8 + j) * 32 + nc * 4 + kk)) * 512);
            }
            #pragma unroll
            for (int f = 0; f < 32; ++f) {
                int kk = f >> 3, j = f & 7;
                bf16x8 aP = *(const bf16x8*)&Hp[0][rt][l][(kk << 5) + (q << 3)];
                bf16x8 aQ = *(const bf16x8*)&Hp[1][rt][l][(kk << 5) + (q << 3)];
                accP[j] = MFMA(aP, wq2[f & 3], accP[j], 0, 0, 0);
                accQ[j] = MFMA(aQ, wq2[f & 3], accQ[j], 0, 0, 0);
                if (f < 28) {
                    int f2 = f + 4, kk2 = f2 >> 3, j2 = f2 & 7;
                    wq2[f & 3] = *(const bf16x8*)(wb2 +
                        ((size_t)((half * 8 + j2) * 32 + nc * 4 + kk2)) * 512);
                }
            }
        }
        __syncthreads();
    }

    float kld_local = 0.f;
    #pragma unroll
    for (int j = 0; j < 8; ++j) {
        int n = ((half << 3) + j) * 16 + l;
        float bias = b2d_s[n];
        #pragma unroll
        for (int i = 0; i < 4; ++i) {
            int r = (rt << 4) + (q << 2) + i;
            int pair = p0 + (r >> 3);
            float pr = 0.1f * fast_tanh(accP[j][i] + bias);
            float po = 0.1f * fast_tanh(accQ[j][i] + bias);
            float e = (pr - po) / DiffQ[(size_t)pair * ZZ + n];
            kld_local += e * e;
        }
    }
    for (int off = 32; off; off >>= 1) kld_local += __shfl_down(kld_local, off, 64);
    if (lane == 0) red[w] = kld_local;
    __syncthreads();
    if (tid == 0) {
        float K = 0.f;
        for (int i = 0; i < 8; ++i) K += red[i];
        float kc = K * (0.5f * DT / (SS * BB));
        atomicAdd(loss + 0, kc);
        atomicAdd(loss + 2, kc);
    }
}

// ---------------------------------------------------------------------------
// Parallel post-pass 2: decoder on z_{t+1} -> recon. (bf16, unchanged)
// ---------------------------------------------------------------------------
__global__ __launch_bounds__(512, 4)
void post_dec(const unsigned short* __restrict__ zhist,
              const unsigned short* __restrict__ PprojQ,
              const float* __restrict__ X, const float* __restrict__ MtQ,
              const float* __restrict__ b2p,
              const unsigned short* __restrict__ PW1z_p,
              const unsigned short* __restrict__ PW2_p,
              float* __restrict__ loss) {
    __shared__ unsigned short Az[4][16][ZZ + 8];
    __shared__ unsigned short Hp[4][16][136];
    __shared__ unsigned short ProjS[8][128];
    __shared__ float b2p_s[DD];
    __shared__ float red[8];
    const int tid = threadIdx.x;
    const int lane = tid & 63;
    const int w = tid >> 6;
    const int q = lane >> 4;
    const int l = lane & 15;
    const int rt = w & 3;
    const int half = w >> 2;
    const int p0 = blockIdx.x << 3;

    for (int idx = tid; idx < 4096; idx += 512) {
        int r = idx >> 6, c4 = (idx & 63) << 2;
        *(ushort4*)&Az[r >> 4][r & 15][c4] =
            *(const ushort4*)&zhist[((size_t)(p0 + BB) * SS + r) * ZZ + c4];  // slot t+1
    }
    if (tid < DD) b2p_s[tid] = b2p[tid];

    f32x4 pacc[4];
    {
        f32x4 z4 = {0.f, 0.f, 0.f, 0.f};
        #pragma unroll
        for (int j = 0; j < 4; ++j) pacc[j] = z4;
    }

    for (int nc = 0; nc < 8; ++nc) {
        if (tid < 256) {
            int pair = tid >> 5, c4 = (tid & 31) << 2;
            *(ushort4*)&ProjS[pair][c4] =
                *(const ushort4*)&PprojQ[(size_t)(p0 + pair) * HH + nc * 128 + c4];
        }
        __syncthreads();

        f32x4 za[4];
        {
            f32x4 z4 = {0.f, 0.f, 0.f, 0.f};
            #pragma unroll
            for (int j = 0; j < 4; ++j) za[j] = z4;
        }
        {
            const unsigned short* wb = PW1z_p + lane * 8;
            bf16x8 wq[4];
            #pragma unroll
            for (int f = 0; f < 4; ++f) {
                int ks = f >> 2, j = f & 3;
                wq[f] = *(const bf16x8*)(wb +
                    ((size_t)((nc * 8 + half * 4 + j) * 8 + ks)) * 512);
            }
            #pragma unroll
            for (int f = 0; f < 32; ++f) {
                int ks = f >> 2, j = f & 3;
                bf16x8 a = *(const bf16x8*)&Az[rt][l][(ks << 5) + (q << 3)];
                za[j] = MFMA(a, wq[f & 3], za[j], 0, 0, 0);
                if (f < 28) {
                    int f2 = f + 4, ks2 = f2 >> 2, j2 = f2 & 3;
                    wq[f & 3] = *(const bf16x8*)(wb +
                        ((size_t)((nc * 8 + half * 4 + j2) * 8 + ks2)) * 512);
                }
            }
        }
        #pragma unroll
        for (int j = 0; j < 4; ++j) {
            int c = (half * 4 + j) * 16 + l;
            #pragma unroll
            for (int i = 0; i < 4; ++i) {
                int r = (q << 2) + i;
                int pair = ((rt << 4) + r) >> 3;
                Hp[rt][r][c] = f2bf(fmaxf(bf2f(ProjS[pair][c]) + za[j][i], 0.f));
            }
        }
        __syncthreads();

        {
            const unsigned short* wb2 = PW2_p + lane * 8;
            bf16x8 wq2[4];
            #pragma unroll
            for (int f = 0; f < 4; ++f) {
                int kk = f >> 2, j = f & 3;
                wq2[f] = *(const bf16x8*)(wb2 +
                    ((size_t)((half * 4 + j) * 32 + nc * 4 + kk)) * 512);
            }
            #pragma unroll
            for (int f = 0; f < 16; ++f) {
                int kk = f >> 2, j = f & 3;
                bf16x8 a = *(const bf16x8*)&Hp[rt][l][(kk << 5) + (q << 3)];
                pacc[j] = MFMA(a, wq2[f & 3], pacc[j], 0, 0, 0);
                if (f < 12) {
                    int f2 = f + 4, kk2 = f2 >> 2, j2 = f2 & 3;
                    wq2[f & 3] = *(const bf16x8*)(wb2 +
                        ((size_t)((half * 4 + j2) * 32 + nc * 4 + kk2)) * 512);
                }
            }
        }
        __syncthreads();
    }

    float rl = 0.f;
    #pragma unroll
    for (int j = 0; j < 4; ++j) {
        int n = ((half << 2) + j) * 16 + l;
        float bias = b2p_s[n];
        #pragma unroll
        for (int i = 0; i < 4; ++i) {
            int r = (rt << 4) + (q << 2) + i;
            int pair = p0 + (r >> 3);
            float p = pacc[j][i] + bias;
            float d = X[(size_t)pair * DD + n] - p;
            rl += (0.5f * (LOG2PIF + d * d)) * MtQ[pair];
        }
    }
    rl *= 1.0f / (SS * BB);
    for (int off = 32; off; off >>= 1) rl += __shfl_down(rl, off, 64);
    if (lane == 0) red[w] = rl;
    __syncthreads();
    if (tid == 0) {
        float R = 0.f;
        for (int i = 0; i < 8; ++i) R += red[i];
        atomicAdd(loss + 0, R);
        atomicAdd(loss + 1, R);
    }
}

extern "C" void kernel_launch(void* const* d_in, const int* in_sizes, int n_in,
                              void* d_out, int out_size, void* d_ws, size_t ws_size,
                              hipStream_t stream) {
    (void)in_sizes; (void)n_in; (void)ws_size;
    const float* X         = (const float*)d_in[0];
    const float* M         = (const float*)d_in[1];
    const float* cov       = (const float*)d_in[2];
    const float* path_h    = (const float*)d_in[3];
    const float* path_hpos = (const float*)d_in[4];
    const float* noise     = (const float*)d_in[5];
    const float* drift_w1  = (const float*)d_in[6];
    const float* drift_b1  = (const float*)d_in[7];
    const float* drift_w2  = (const float*)d_in[8];
    const float* drift_b2  = (const float*)d_in[9];
    const float* diff_w1   = (const float*)d_in[10];
    const float* diff_b1   = (const float*)d_in[11];
    const float* diff_w2   = (const float*)d_in[12];
    const float* diff_b2   = (const float*)d_in[13];
    const float* p_w1      = (const float*)d_in[14];
    const float* p_b1      = (const float*)d_in[15];
    const float* p_w2      = (const float*)d_in[16];
    const float* p_b2      = (const float*)d_in[17];
    const float* cov_w1    = (const float*)d_in[18];
    const float* cov_b1    = (const float*)d_in[19];
    const float* cov_w2    = (const float*)d_in[20];
    const float* cov_b2    = (const float*)d_in[21];

    char* ws = (char*)d_ws;
    size_t off = 0;
    auto alloc = [&](size_t bytes) {
        void* p = ws + off;
        off = (off + bytes + 255) & ~(size_t)255;
        return p;
    };
    unsigned short* HprojQ  = (unsigned short*)alloc((size_t)T_STEPS * BB * HH * 2);
    unsigned short* HpprojQ = (unsigned short*)alloc((size_t)T_STEPS * BB * HH * 2);
    unsigned short* PprojQ  = (unsigned short*)alloc((size_t)T_STEPS * BB * HH * 2);
    float*          DiffQ   = (float*)alloc((size_t)T_STEPS * BB * ZZ * 4);
    float*          MtQ     = (float*)alloc((size_t)T_STEPS * BB * 4);
    unsigned short* zhist   = (unsigned short*)alloc((size_t)(T_STEPS + 1) * BB * SS * ZZ * 2);
    unsigned short* W1z_p   = (unsigned short*)alloc((size_t)ZZ * HH * 2);
    unsigned short* W2_p    = (unsigned short*)alloc((size_t)HH * ZZ * 2);
    unsigned short* PW1z_p  = (unsigned short*)alloc((size_t)ZZ * HH * 2);
    unsigned short* PW2_p   = (unsigned short*)alloc((size_t)HH * DD * 2);
    unsigned short* W1h_p   = (unsigned short*)alloc((size_t)RR * HH * 2);
    unsigned short* PW1h_p  = (unsigned short*)alloc((size_t)RR * HH * 2);
    unsigned short* DW1_p   = (unsigned short*)alloc((size_t)RR * HH * 2);
    unsigned short* DW2_p   = (unsigned short*)alloc((size_t)HH * ZZ * 2);
    unsigned char*  W1z_f8  = (unsigned char*)alloc((size_t)ZZ * HH);
    unsigned char*  W2_f8   = (unsigned char*)alloc((size_t)HH * ZZ);

    hipMemsetAsync(d_out, 0, (size_t)out_size * sizeof(float), stream);

    auto packLaunch = [&](const float* src, int K, int N, unsigned short* dst) {
        int total = (K / 32) * (N / 16) * 64;
        pack_w<<<(total + 255) / 256, 256, 0, stream>>>(src, K, N, dst);
    };
    auto packLaunch8 = [&](const float* src, int K, int N, unsigned char* dst) {
        int total = (K / 32) * (N / 16) * 64;
        pack_w_fp8<<<(total + 255) / 256, 256, 0, stream>>>(src, K, N, dst);
    };
    packLaunch(drift_w1 + (size_t)RR * HH, ZZ, HH, W1z_p);
    packLaunch(drift_w2,                   HH, ZZ, W2_p);
    packLaunch(p_w1 + (size_t)RR * HH,     ZZ, HH, PW1z_p);
    packLaunch(p_w2,                       HH, DD, PW2_p);
    packLaunch(drift_w1, RR, HH, W1h_p);
    packLaunch(p_w1,     RR, HH, PW1h_p);
    packLaunch(diff_w1,  RR, HH, DW1_p);
    packLaunch(diff_w2,  HH, ZZ, DW2_p);
    packLaunch8(drift_w1 + (size_t)RR * HH, ZZ, HH, W1z_f8);
    packLaunch8(drift_w2,                   HH, ZZ, W2_f8);

    mt_kernel<<<(T_STEPS * BB * 64) / 256, 256, 0, stream>>>(M, MtQ);

    precompute_kernel<<<(T_STEPS * BB) / 16, 256, 0, stream>>>(
        path_h, path_hpos, drift_b1, p_b1, diff_b1, diff_b2,
        W1h_p, PW1h_p, DW1_p, DW2_p, HprojQ, HpprojQ, PprojQ, DiffQ);

    float* outp = (float*)d_out;
    float* loss = outp + (size_t)BB * SS * ZZ;

    scan_kernel<<<BB, 1024, 0, stream>>>(
        cov, noise, drift_b2, cov_w1, cov_b1, cov_w2, cov_b2,
        W1z_f8, W2_f8, HpprojQ, DiffQ, zhist, outp);

    post_drift<<<(T_STEPS * BB) / 8, 512, 0, stream>>>(
        zhist, HprojQ, HpprojQ, DiffQ, drift_b2, W1z_p, W2_p, loss);

    post_dec<<<(T_STEPS * BB) / 8, 512, 0, stream>>>(
        zhist, PprojQ, X, MtQ, p_b2, PW1z_p, PW2_p, loss);
}

// Round 5
// 2238.626 us; speedup vs baseline: 2.0041x; 1.3390x over previous
//
#include <hip/hip_runtime.h>
#include <cstddef>
#include <cstdint>

#define T_STEPS 200
#define BB 64
#define SS 8
#define DD 128
#define RR 512
#define ZZ 256
#define HH 1024
#define DT 0.05f
#define SQRT_DT 0.22360679774997896f
#define LOG2PIF 1.8378770664093453f

typedef __attribute__((ext_vector_type(8))) short bf16x8;
typedef __attribute__((ext_vector_type(4))) float f32x4;
typedef long f8x8;   // 8 fp8-e4m3 values (2 VGPRs)
#define MFMA __builtin_amdgcn_mfma_f32_16x16x32_bf16
#define MFMA8 __builtin_amdgcn_mfma_f32_16x16x32_fp8_fp8

static __device__ __forceinline__ unsigned short f2bf(float x) {
    unsigned int u = __builtin_bit_cast(unsigned int, x);
    u += 0x7fffu + ((u >> 16) & 1u);
    return (unsigned short)(u >> 16);
}
static __device__ __forceinline__ float bf2f(unsigned short h) {
    unsigned int u = ((unsigned int)h) << 16;
    return __builtin_bit_cast(float, u);
}
static __device__ __forceinline__ float fast_tanh(float x) {
    float e = __expf(2.0f * x);
    return 1.0f - 2.0f / (e + 1.0f);
}
// f32 -> fp8 e4m3 via HW converter (consistent with gfx950 fp8 MFMA decode).
static __device__ __forceinline__ unsigned char f2fp8(float x) {
    unsigned int r = 0;
    asm volatile("v_cvt_pk_fp8_f32 %0, %1, %1" : "+v"(r) : "v"(x));
    return (unsigned char)(r & 0xffu);
}

// LDS-ordering barrier WITHOUT the vmcnt(0) drain __syncthreads would emit:
// producer ds_writes complete (lgkmcnt), all waves meet, no load-queue flush.
// sched_barrier(0) stops post-barrier LDS reads from hoisting above it.
static __device__ __forceinline__ void bar_lds() {
    asm volatile("s_waitcnt lgkmcnt(0)" ::: "memory");
    __builtin_amdgcn_s_barrier();
    __builtin_amdgcn_sched_barrier(0);
}

// ---------------------------------------------------------------------------
// Pack row-major fp32 W[K][N] into bf16 MFMA B-fragment order:
// frag p = nt*(K/32)*64 + ks*64 + lane holds 8 elems: n = nt*16 + (lane&15),
// k = ks*32 + (lane>>4)*8 + i.
// ---------------------------------------------------------------------------
__global__ void pack_w(const float* __restrict__ src, int K, int N,
                       unsigned short* __restrict__ dst) {
    int total = (K >> 5) * (N >> 4) * 64;
    int p = blockIdx.x * blockDim.x + threadIdx.x;
    if (p >= total) return;
    int lane = p & 63;
    int ksteps = K >> 5;
    int ks = (p >> 6) % ksteps;
    int nt = p / (ksteps << 6);
    int n = (nt << 4) + (lane & 15);
    int k0 = (ks << 5) + ((lane >> 4) << 3);
    uint4 u4;
    unsigned short* tmp = reinterpret_cast<unsigned short*>(&u4);
    for (int i = 0; i < 8; ++i) tmp[i] = f2bf(src[(size_t)(k0 + i) * N + n]);
    *reinterpret_cast<uint4*>(dst + (size_t)p * 8) = u4;
}

// Same fragment order, fp8-e4m3 payload (8 B per lane-frag).
__global__ void pack_w_fp8(const float* __restrict__ src, int K, int N,
                           unsigned char* __restrict__ dst) {
    int total = (K >> 5) * (N >> 4) * 64;
    int p = blockIdx.x * blockDim.x + threadIdx.x;
    if (p >= total) return;
    int lane = p & 63;
    int ksteps = K >> 5;
    int ks = (p >> 6) % ksteps;
    int nt = p / (ksteps << 6);
    int n = (nt << 4) + (lane & 15);
    int k0 = (ks << 5) + ((lane >> 4) << 3);
    unsigned long long acc = 0ull;
    for (int i = 0; i < 8; ++i)
        acc |= (unsigned long long)f2fp8(src[(size_t)(k0 + i) * N + n]) << (8 * i);
    *reinterpret_cast<unsigned long long*>(dst + (size_t)p * 8) = acc;
}

// Mt[t,b] = mean over D of M[t,b,:]
__global__ void mt_kernel(const float* __restrict__ M, float* __restrict__ Mt) {
    int wv = (blockIdx.x * blockDim.x + threadIdx.x) >> 6;
    int lane = threadIdx.x & 63;
    if (wv >= T_STEPS * BB) return;
    const float* row = M + (size_t)wv * DD;
    float s = row[lane] + row[lane + 64];
    for (int off = 32; off; off >>= 1) s += __shfl_down(s, off, 64);
    if (lane == 0) Mt[wv] = s * (1.0f / DD);
}

// ---------------------------------------------------------------------------
// Precompute h-only projections (parallel over T*B, 16 rows/block).
// ---------------------------------------------------------------------------
#define PC_GEMM_1024(Asrc, Bp, biasArr, EMIT)                                    \
    {                                                                            \
        f32x4 acc[16];                                                           \
        f32x4 z4 = {0.f, 0.f, 0.f, 0.f};                                        \
        for (int ntl = 0; ntl < 16; ++ntl) acc[ntl] = z4;                        \
        for (int ks = 0; ks < 16; ++ks) {                                        \
            bf16x8 a = *(const bf16x8*)&Asrc[l][(ks << 5) + (q << 3)];           \
            for (int ntl = 0; ntl < 16; ++ntl) {                                 \
                int ntg = (w << 4) + ntl;                                        \
                bf16x8 bb = *(const bf16x8*)(Bp +                                \
                             (((size_t)ntg * 16 + ks) * 64 + lane) * 8);         \
                acc[ntl] = MFMA(a, bb, acc[ntl], 0, 0, 0);                       \
            }                                                                    \
        }                                                                        \
        for (int ntl = 0; ntl < 16; ++ntl) {                                     \
            int n = (((w << 4) + ntl) << 4) + l;                                 \
            float bv = biasArr[n];                                               \
            for (int i = 0; i < 4; ++i) {                                        \
                int rr = (q << 2) + i;                                           \
                float v = acc[ntl][i] + bv;                                      \
                EMIT;                                                            \
            }                                                                    \
        }                                                                        \
    }

__global__ __launch_bounds__(256)
void precompute_kernel(const float* __restrict__ h, const float* __restrict__ hpos,
                       const float* __restrict__ b1d, const float* __restrict__ b1p,
                       const float* __restrict__ b1f, const float* __restrict__ b2f,
                       const unsigned short* __restrict__ W1h_p,
                       const unsigned short* __restrict__ PW1h_p,
                       const unsigned short* __restrict__ DW1_p,
                       const unsigned short* __restrict__ DW2_p,
                       unsigned short* __restrict__ HprojQ,
                       unsigned short* __restrict__ HpprojQ,
                       unsigned short* __restrict__ PprojQ,
                       float* __restrict__ DiffQ) {
    __shared__ unsigned short Ahh[16][RR + 8];
    __shared__ unsigned short Ahp[16][RR + 8];
    __shared__ unsigned short Adh[16][HH + 8];
    const int tid = threadIdx.x;
    const int lane = tid & 63;
    const int w = tid >> 6;
    const int q = lane >> 4;
    const int l = lane & 15;
    const int r0 = blockIdx.x << 4;

    for (int idx = tid; idx < (RR << 4); idx += 256) {
        int r = idx >> 9, c = idx & (RR - 1);
        Ahh[r][c] = f2bf(h[(size_t)(r0 + r) * RR + c]);
        Ahp[r][c] = f2bf(hpos[(size_t)(r0 + r) * RR + c]);
    }
    __syncthreads();

    PC_GEMM_1024(Ahh, W1h_p,  b1d, (HprojQ [(size_t)(r0 + rr) * HH + n] = f2bf(v)));
    PC_GEMM_1024(Ahp, W1h_p,  b1d, (HpprojQ[(size_t)(r0 + rr) * HH + n] = f2bf(v)));
    PC_GEMM_1024(Ahh, PW1h_p, b1p, (PprojQ [(size_t)(r0 + rr) * HH + n] = f2bf(v)));
    PC_GEMM_1024(Ahh, DW1_p,  b1f, (Adh[rr][n] = f2bf(fmaxf(v, 0.f))));
    __syncthreads();

    {
        f32x4 acc[4];
        f32x4 z4 = {0.f, 0.f, 0.f, 0.f};
        for (int ntl = 0; ntl < 4; ++ntl) acc[ntl] = z4;
        for (int ks = 0; ks < 32; ++ks) {
            bf16x8 a = *(const bf16x8*)&Adh[l][(ks << 5) + (q << 3)];
            for (int ntl = 0; ntl < 4; ++ntl) {
                int ntg = (w << 2) + ntl;
                bf16x8 bb = *(const bf16x8*)(DW2_p +
                             (((size_t)ntg * 32 + ks) * 64 + lane) * 8);
                acc[ntl] = MFMA(a, bb, acc[ntl], 0, 0, 0);
            }
        }
        for (int ntl = 0; ntl < 4; ++ntl) {
            int n = (((w << 2) + ntl) << 4) + l;
            float bv = b2f[n];
            for (int i = 0; i < 4; ++i) {
                int rr = (q << 2) + i;
                DiffQ[(size_t)(r0 + rr) * ZZ + n] = __expf(acc[ntl][i] + bv);
            }
        }
    }
}

// ---------------------------------------------------------------------------
// Sequential scan, WEIGHT-RESIDENT fp8. 64 blocks x 512 thr (8 waves).
// fp8 total weights = 512 KB: W1z fully in VGPRs (64 frags/wave = 128 VGPR),
// W2 tile-A in VGPRs (32 frags = 64 VGPR), W2 tile-B in LDS (128 KB).
// Loaded ONCE; 200 steps of pure reg/LDS MFMA — no per-step weight loads.
// Round 2/4 showed the stream was latency-serialized (bf16 and fp8 identical
// 9.6us/step despite 2x bytes): the fix is removing the loads, not the bytes.
// Per-step globals (eps/Hpproj/Diff, ~11 KB) prefetched one step ahead;
// barriers are lgkmcnt-only raw s_barrier (no vmcnt drain) so prefetches
// survive. Arithmetic bit-identical to round-4 fp8 scan (same quantization,
// same even/odd K-accumulation order).
// ---------------------------------------------------------------------------
__global__ __launch_bounds__(512, 2)
void scan_kernel(const float* __restrict__ cov, const float* __restrict__ noise,
                 const float* __restrict__ b2d,
                 const float* __restrict__ cw1, const float* __restrict__ cb1,
                 const float* __restrict__ cw2, const float* __restrict__ cb2,
                 const unsigned char* __restrict__ W1z_f8,
                 const unsigned char* __restrict__ W2_f8,
                 const unsigned short* __restrict__ HpprojQ,
                 const float* __restrict__ DiffQ,
                 unsigned short* __restrict__ zhist,
                 float* __restrict__ out) {
    __shared__ __align__(16) long W2L[256][64];           // 128 KiB: W2 tile-B frags
    __shared__ __align__(8) unsigned char Az8[8][272];    // z fp8 (8 rows)
    __shared__ __align__(8) unsigned char Ah8[8][1040];   // poster hidden fp8
    __shared__ float zf[8][256];                          // fp32 master z
    __shared__ float ch[64];

    const int tid = threadIdx.x;
    const int lane = tid & 63;
    const int w = tid >> 6;   // 8 waves
    const int q = lane >> 4;
    const int l = lane & 15;
    const int b = blockIdx.x;

    // ---- one-time weight residency ----
    // G1: wave w owns hidden N-tiles nt = w*8 .. w*8+7 (cols w*128..w*128+128)
    f8x8 w1r[8][8];
    #pragma unroll
    for (int ntl = 0; ntl < 8; ++ntl)
        #pragma unroll
        for (int ks = 0; ks < 8; ++ks)
            w1r[ntl][ks] = *(const f8x8*)(W1z_f8 +
                ((((size_t)(w * 8 + ntl) * 8 + ks) * 64 + lane) << 3));
    // G2: wave w owns z N-tiles w*2 (regs) and w*2+1 (LDS); K = 1024 = 32 ks
    f8x8 w2r[32];
    #pragma unroll
    for (int ks = 0; ks < 32; ++ks)
        w2r[ks] = *(const f8x8*)(W2_f8 +
            ((((size_t)(w * 2) * 32 + ks) * 64 + lane) << 3));
    #pragma unroll
    for (int ks = 0; ks < 32; ++ks)
        W2L[w * 32 + ks][lane] = *(const long*)(W2_f8 +
            ((((size_t)(w * 2 + 1) * 32 + ks) * 64 + lane) << 3));

    // ---- prologue: z0 = tanh(MLP(cov)) ----
    if (tid < 64) {
        float s = cb1[tid];
        for (int c = 0; c < 16; ++c) s += cov[b * 16 + c] * cw1[c * 64 + tid];
        ch[tid] = fmaxf(s, 0.f);
    }
    __syncthreads();
    if (tid < ZZ) {
        float v = cb2[tid];
        for (int j = 0; j < 64; ++j) v += ch[j] * cw2[j * ZZ + tid];
        v = fast_tanh(v);
        unsigned short hv = f2bf(v);
        unsigned char zb = f2fp8(v);
        for (int s = 0; s < SS; ++s) {
            zf[s][tid] = v;
            Az8[s][tid] = zb;
            zhist[((size_t)b * SS + s) * ZZ + tid] = hv;   // slot 0
        }
    }

    const int colA = (w << 5) + l;       // z col for G2 tile A
    const int colB = colA + 16;          // tile B
    float b2dA = b2d[colA], b2dB = b2d[colB];

    // per-step scalars, prefetched one step ahead (live across barriers:
    // bar_lds() does not drain vmcnt)
    float epsA[4], epsB[4], difA = 0.f, difB = 0.f;
    unsigned short hpr[8];
#define LOAD_SCALARS(TI)                                                        \
    do {                                                                        \
        const size_t tb_ = (size_t)(TI) * BB + b;                               \
        if (q < 2) {                                                            \
            _Pragma("unroll")                                                   \
            for (int i = 0; i < 4; ++i) {                                       \
                epsA[i] = noise[((tb_ << 3) + (q << 2) + i) * ZZ + colA];       \
                epsB[i] = noise[((tb_ << 3) + (q << 2) + i) * ZZ + colB];       \
            }                                                                   \
            difA = DiffQ[tb_ * ZZ + colA];                                      \
            difB = DiffQ[tb_ * ZZ + colB];                                      \
            _Pragma("unroll")                                                   \
            for (int ntl = 0; ntl < 8; ++ntl)                                   \
                hpr[ntl] = HpprojQ[tb_ * HH + (size_t)(w * 8 + ntl) * 16 + l];  \
        }                                                                       \
    } while (0)

    LOAD_SCALARS(0);
    __syncthreads();   // z0/weights visible (one-time full drain is fine)

    for (int t = 0; t < T_STEPS; ++t) {
        // ---- G1: hidden[8][1024] = relu(Hpp + z @ W1z), all from regs/LDS
        #pragma unroll
        for (int h = 0; h < 2; ++h) {
            f32x4 acc[4];
            {
                f32x4 z4 = {0.f, 0.f, 0.f, 0.f};
                #pragma unroll
                for (int j = 0; j < 4; ++j) acc[j] = z4;
            }
            #pragma unroll
            for (int ks = 0; ks < 8; ++ks) {
                f8x8 a1 = *(const f8x8*)&Az8[l & 7][(ks << 5) + (q << 3)];
                #pragma unroll
                for (int j = 0; j < 4; ++j)
                    acc[j] = MFMA8(a1, w1r[h * 4 + j][ks], acc[j], 0, 0, 0);
            }
            if (q < 2) {
                #pragma unroll
                for (int j = 0; j < 4; ++j) {
                    int ntl = h * 4 + j;
                    int n = (w * 8 + ntl) * 16 + l;
                    float hp = bf2f(hpr[ntl]);
                    #pragma unroll
                    for (int i = 0; i < 4; ++i)
                        Ah8[(q << 2) + i][n] = f2fp8(fmaxf(hp + acc[j][i], 0.f));
                }
            }
        }
        bar_lds();

        // ---- G2: drift[8][256] = hidden @ W2 (tile A regs, tile B LDS)
        f32x4 aA[2], aB[2];
        {
            f32x4 z4 = {0.f, 0.f, 0.f, 0.f};
            aA[0] = z4; aA[1] = z4; aB[0] = z4; aB[1] = z4;
        }
        #pragma unroll
        for (int ks = 0; ks < 32; ++ks) {
            f8x8 a2 = *(const f8x8*)&Ah8[l & 7][(ks << 5) + (q << 3)];
            f8x8 bB = (f8x8)W2L[w * 32 + ks][lane];
            aA[ks & 1] = MFMA8(a2, w2r[ks], aA[ks & 1], 0, 0, 0);
            aB[ks & 1] = MFMA8(a2, bB, aB[ks & 1], 0, 0, 0);
        }
        if (q < 2) {
            #pragma unroll
            for (int i = 0; i < 4; ++i) {
                int s = (q << 2) + i;
                float preA = aA[0][i] + aA[1][i] + b2dA;
                float preB = aB[0][i] + aB[1][i] + b2dB;
                zf[s][colA] += DT * (0.1f * fast_tanh(preA)) + SQRT_DT * difA * epsA[i];
                zf[s][colB] += DT * (0.1f * fast_tanh(preB)) + SQRT_DT * difB * epsB[i];
            }
        }
        // prefetch next step's scalars now (last use of eps/dif was above;
        // hpr's was in G1) — loads stay in flight across the raw barriers
        if (t + 1 < T_STEPS) LOAD_SCALARS(t + 1);
        bar_lds();

        // ---- normalize: wave w owns z-row w; write Az8 + zhist(t+1)
        {
            float v0 = zf[w][lane], v1 = zf[w][lane + 64];
            float v2 = zf[w][lane + 128], v3 = zf[w][lane + 192];
            float mn = fminf(fminf(v0, v1), fminf(v2, v3));
            float mx = fmaxf(fmaxf(v0, v1), fmaxf(v2, v3));
            for (int off = 32; off; off >>= 1) {
                mn = fminf(mn, __shfl_xor(mn, off, 64));
                mx = fmaxf(mx, __shfl_xor(mx, off, 64));
            }
            float sc = 1.0f / (mx - mn);
            v0 = (v0 - mn) * sc; v1 = (v1 - mn) * sc;
            v2 = (v2 - mn) * sc; v3 = (v3 - mn) * sc;
            zf[w][lane] = v0; zf[w][lane + 64] = v1;
            zf[w][lane + 128] = v2; zf[w][lane + 192] = v3;
            Az8[w][lane] = f2fp8(v0); Az8[w][lane + 64] = f2fp8(v1);
            Az8[w][lane + 128] = f2fp8(v2); Az8[w][lane + 192] = f2fp8(v3);
            unsigned short h0 = f2bf(v0), h1 = f2bf(v1), h2 = f2bf(v2), h3 = f2bf(v3);
            size_t zo = ((size_t)(t + 1) * BB + b) * (SS * ZZ) + (size_t)w * ZZ;
            volatile unsigned short* zh = (volatile unsigned short*)zhist;
            zh[zo + lane] = h0; zh[zo + lane + 64] = h1;
            zh[zo + lane + 128] = h2; zh[zo + lane + 192] = h3;
        }
        bar_lds();   // Az8/zf ready for next step's G1
    }
    __syncthreads();

    for (int idx = tid; idx < SS * ZZ; idx += 512) {
        int s = idx >> 8, n = idx & 255;
        out[((size_t)b * SS + s) * ZZ + n] = zf[s][n];
    }
#undef LOAD_SCALARS
}

// ---------------------------------------------------------------------------
// Parallel post-pass 1: prior+poster drift recompute -> kld. (bf16, unchanged)
// ---------------------------------------------------------------------------
__global__ __launch_bounds__(512, 4)
void post_drift(const unsigned short* __restrict__ zhist,
                const unsigned short* __restrict__ HprojQ,
                const unsigned short* __restrict__ HpprojQ,
                const float* __restrict__ DiffQ, const float* __restrict__ b2d,
                const unsigned short* __restrict__ W1z_p,
                const unsigned short* __restrict__ W2_p,
                float* __restrict__ loss) {
    __shared__ unsigned short Az[4][16][ZZ + 8];
    __shared__ unsigned short Hp[2][4][16][136];
    __shared__ unsigned short ProjS[2][8][128];
    __shared__ float b2d_s[ZZ];
    __shared__ float red[8];
    const int tid = threadIdx.x;
    const int lane = tid & 63;
    const int w = tid >> 6;      // 8 waves
    const int q = lane >> 4;
    const int l = lane & 15;
    const int rt = w & 3;
    const int half = w >> 2;
    const int p0 = blockIdx.x << 3;   // first flat (t*B+b) pair

    for (int idx = tid; idx < 4096; idx += 512) {
        int r = idx >> 6, c4 = (idx & 63) << 2;
        *(ushort4*)&Az[r >> 4][r & 15][c4] =
            *(const ushort4*)&zhist[((size_t)p0 * SS + r) * ZZ + c4];
    }
    if (tid < ZZ) b2d_s[tid] = b2d[tid];

    f32x4 accP[8], accQ[8];
    {
        f32x4 z4 = {0.f, 0.f, 0.f, 0.f};
        #pragma unroll
        for (int j = 0; j < 8; ++j) { accP[j] = z4; accQ[j] = z4; }
    }

    for (int nc = 0; nc < 8; ++nc) {
        {
            int path = tid >> 8, rem = tid & 255;
            int pair = rem >> 5, c4 = (rem & 31) << 2;
            const unsigned short* src =
                (path ? HpprojQ : HprojQ) + (size_t)(p0 + pair) * HH + nc * 128 + c4;
            *(ushort4*)&ProjS[path][pair][c4] = *(const ushort4*)src;
        }
        __syncthreads();

        f32x4 za[4];
        {
            f32x4 z4 = {0.f, 0.f, 0.f, 0.f};
            #pragma unroll
            for (int j = 0; j < 4; ++j) za[j] = z4;
        }
        {
            const unsigned short* wb = W1z_p + lane * 8;
            bf16x8 wq[4];
            #pragma unroll
            for (int f = 0; f < 4; ++f) {
                int ks = f >> 2, j = f & 3;
                wq[f] = *(const bf16x8*)(wb +
                    ((size_t)((nc * 8 + half * 4 + j) * 8 + ks)) * 512);
            }
            #pragma unroll
            for (int f = 0; f < 32; ++f) {
                int ks = f >> 2, j = f & 3;
                bf16x8 a = *(const bf16x8*)&Az[rt][l][(ks << 5) + (q << 3)];
                za[j] = MFMA(a, wq[f & 3], za[j], 0, 0, 0);
                if (f < 28) {
                    int f2 = f + 4, ks2 = f2 >> 2, j2 = f2 & 3;
                    wq[f & 3] = *(const bf16x8*)(wb +
                        ((size_t)((nc * 8 + half * 4 + j2) * 8 + ks2)) * 512);
                }
            }
        }
        #pragma unroll
        for (int j = 0; j < 4; ++j) {
            int c = (half * 4 + j) * 16 + l;
            #pragma unroll
            for (int i = 0; i < 4; ++i) {
                int r = (q << 2) + i;
                int pair = ((rt << 4) + r) >> 3;
                float v = za[j][i];
                Hp[0][rt][r][c] = f2bf(fmaxf(bf2f(ProjS[0][pair][c]) + v, 0.f));
                Hp[1][rt][r][c] = f2bf(fmaxf(bf2f(ProjS[1][pair][c]) + v, 0.f));
            }
        }
        __syncthreads();

        {
            const unsigned short* wb2 = W2_p + lane * 8;
            bf16x8 wq2[4];
            #pragma unroll
            for (int f = 0; f < 4; ++f) {
                int kk = f >> 3, j = f & 7;
                wq2[f] = *(const bf16x8*)(wb2 +
                    ((size_t)((half * 8 + j) * 32 + nc * 4 + kk)) * 512);
            }
            #pragma unroll
            for (int f = 0; f < 32; ++f) {
                int kk = f >> 3, j = f & 7;
                bf16x8 aP = *(const bf16x8*)&Hp[0][rt][l][(kk << 5) + (q << 3)];
                bf16x8 aQ = *(const bf16x8*)&Hp[1][rt][l][(kk << 5) + (q << 3)];
                accP[j] = MFMA(aP, wq2[f & 3], accP[j], 0, 0, 0);
                accQ[j] = MFMA(aQ, wq2[f & 3], accQ[j], 0, 0, 0);
                if (f < 28) {
                    int f2 = f + 4, kk2 = f2 >> 3, j2 = f2 & 7;
                    wq2[f & 3] = *(const bf16x8*)(wb2 +
                        ((size_t)((half * 8 + j2) * 32 + nc * 4 + kk2)) * 512);
                }
            }
        }
        __syncthreads();
    }

    float kld_local = 0.f;
    #pragma unroll
    for (int j = 0; j < 8; ++j) {
        int n = ((half << 3) + j) * 16 + l;
        float bias = b2d_s[n];
        #pragma unroll
        for (int i = 0; i < 4; ++i) {
            int r = (rt << 4) + (q << 2) + i;
            int pair = p0 + (r >> 3);
            float pr = 0.1f * fast_tanh(accP[j][i] + bias);
            float po = 0.1f * fast_tanh(accQ[j][i] + bias);
            float e = (pr - po) / DiffQ[(size_t)pair * ZZ + n];
            kld_local += e * e;
        }
    }
    for (int off = 32; off; off >>= 1) kld_local += __shfl_down(kld_local, off, 64);
    if (lane == 0) red[w] = kld_local;
    __syncthreads();
    if (tid == 0) {
        float K = 0.f;
        for (int i = 0; i < 8; ++i) K += red[i];
        float kc = K * (0.5f * DT / (SS * BB));
        atomicAdd(loss + 0, kc);
        atomicAdd(loss + 2, kc);
    }
}

// ---------------------------------------------------------------------------
// Parallel post-pass 2: decoder on z_{t+1} -> recon. (bf16, unchanged)
// ---------------------------------------------------------------------------
__global__ __launch_bounds__(512, 4)
void post_dec(const unsigned short* __restrict__ zhist,
              const unsigned short* __restrict__ PprojQ,
              const float* __restrict__ X, const float* __restrict__ MtQ,
              const float* __restrict__ b2p,
              const unsigned short* __restrict__ PW1z_p,
              const unsigned short* __restrict__ PW2_p,
              float* __restrict__ loss) {
    __shared__ unsigned short Az[4][16][ZZ + 8];
    __shared__ unsigned short Hp[4][16][136];
    __shared__ unsigned short ProjS[8][128];
    __shared__ float b2p_s[DD];
    __shared__ float red[8];
    const int tid = threadIdx.x;
    const int lane = tid & 63;
    const int w = tid >> 6;
    const int q = lane >> 4;
    const int l = lane & 15;
    const int rt = w & 3;
    const int half = w >> 2;
    const int p0 = blockIdx.x << 3;

    for (int idx = tid; idx < 4096; idx += 512) {
        int r = idx >> 6, c4 = (idx & 63) << 2;
        *(ushort4*)&Az[r >> 4][r & 15][c4] =
            *(const ushort4*)&zhist[((size_t)(p0 + BB) * SS + r) * ZZ + c4];  // slot t+1
    }
    if (tid < DD) b2p_s[tid] = b2p[tid];

    f32x4 pacc[4];
    {
        f32x4 z4 = {0.f, 0.f, 0.f, 0.f};
        #pragma unroll
        for (int j = 0; j < 4; ++j) pacc[j] = z4;
    }

    for (int nc = 0; nc < 8; ++nc) {
        if (tid < 256) {
            int pair = tid >> 5, c4 = (tid & 31) << 2;
            *(ushort4*)&ProjS[pair][c4] =
                *(const ushort4*)&PprojQ[(size_t)(p0 + pair) * HH + nc * 128 + c4];
        }
        __syncthreads();

        f32x4 za[4];
        {
            f32x4 z4 = {0.f, 0.f, 0.f, 0.f};
            #pragma unroll
            for (int j = 0; j < 4; ++j) za[j] = z4;
        }
        {
            const unsigned short* wb = PW1z_p + lane * 8;
            bf16x8 wq[4];
            #pragma unroll
            for (int f = 0; f < 4; ++f) {
                int ks = f >> 2, j = f & 3;
                wq[f] = *(const bf16x8*)(wb +
                    ((size_t)((nc * 8 + half * 4 + j) * 8 + ks)) * 512);
            }
            #pragma unroll
            for (int f = 0; f < 32; ++f) {
                int ks = f >> 2, j = f & 3;
                bf16x8 a = *(const bf16x8*)&Az[rt][l][(ks << 5) + (q << 3)];
                za[j] = MFMA(a, wq[f & 3], za[j], 0, 0, 0);
                if (f < 28) {
                    int f2 = f + 4, ks2 = f2 >> 2, j2 = f2 & 3;
                    wq[f & 3] = *(const bf16x8*)(wb +
                        ((size_t)((nc * 8 + half * 4 + j2) * 8 + ks2)) * 512);
                }
            }
        }
        #pragma unroll
        for (int j = 0; j < 4; ++j) {
            int c = (half * 4 + j) * 16 + l;
            #pragma unroll
            for (int i = 0; i < 4; ++i) {
                int r = (q << 2) + i;
                int pair = ((rt << 4) + r) >> 3;
                Hp[rt][r][c] = f2bf(fmaxf(bf2f(ProjS[pair][c]) + za[j][i], 0.f));
            }
        }
        __syncthreads();

        {
            const unsigned short* wb2 = PW2_p + lane * 8;
            bf16x8 wq2[4];
            #pragma unroll
            for (int f = 0; f < 4; ++f) {
                int kk = f >> 2, j = f & 3;
                wq2[f] = *(const bf16x8*)(wb2 +
                    ((size_t)((half * 4 + j) * 32 + nc * 4 + kk)) * 512);
            }
            #pragma unroll
            for (int f = 0; f < 16; ++f) {
                int kk = f >> 2, j = f & 3;
                bf16x8 a = *(const bf16x8*)&Hp[rt][l][(kk << 5) + (q << 3)];
                pacc[j] = MFMA(a, wq2[f & 3], pacc[j], 0, 0, 0);
                if (f < 12) {
                    int f2 = f + 4, kk2 = f2 >> 2, j2 = f2 & 3;
                    wq2[f & 3] = *(const bf16x8*)(wb2 +
                        ((size_t)((half * 4 + j2) * 32 + nc * 4 + kk2)) * 512);
                }
            }
        }
        __syncthreads();
    }

    float rl = 0.f;
    #pragma unroll
    for (int j = 0; j < 4; ++j) {
        int n = ((half << 2) + j) * 16 + l;
        float bias = b2p_s[n];
        #pragma unroll
        for (int i = 0; i < 4; ++i) {
            int r = (rt << 4) + (q << 2) + i;
            int pair = p0 + (r >> 3);
            float p = pacc[j][i] + bias;
            float d = X[(size_t)pair * DD + n] - p;
            rl += (0.5f * (LOG2PIF + d * d)) * MtQ[pair];
        }
    }
    rl *= 1.0f / (SS * BB);
    for (int off = 32; off; off >>= 1) rl += __shfl_down(rl, off, 64);
    if (lane == 0) red[w] = rl;
    __syncthreads();
    if (tid == 0) {
        float R = 0.f;
        for (int i = 0; i < 8; ++i) R += red[i];
        atomicAdd(loss + 0, R);
        atomicAdd(loss + 1, R);
    }
}

extern "C" void kernel_launch(void* const* d_in, const int* in_sizes, int n_in,
                              void* d_out, int out_size, void* d_ws, size_t ws_size,
                              hipStream_t stream) {
    (void)in_sizes; (void)n_in; (void)ws_size;
    const float* X         = (const float*)d_in[0];
    const float* M         = (const float*)d_in[1];
    const float* cov       = (const float*)d_in[2];
    const float* path_h    = (const float*)d_in[3];
    const float* path_hpos = (const float*)d_in[4];
    const float* noise     = (const float*)d_in[5];
    const float* drift_w1  = (const float*)d_in[6];
    const float* drift_b1  = (const float*)d_in[7];
    const float* drift_w2  = (const float*)d_in[8];
    const float* drift_b2  = (const float*)d_in[9];
    const float* diff_w1   = (const float*)d_in[10];
    const float* diff_b1   = (const float*)d_in[11];
    const float* diff_w2   = (const float*)d_in[12];
    const float* diff_b2   = (const float*)d_in[13];
    const float* p_w1      = (const float*)d_in[14];
    const float* p_b1      = (const float*)d_in[15];
    const float* p_w2      = (const float*)d_in[16];
    const float* p_b2      = (const float*)d_in[17];
    const float* cov_w1    = (const float*)d_in[18];
    const float* cov_b1    = (const float*)d_in[19];
    const float* cov_w2    = (const float*)d_in[20];
    const float* cov_b2    = (const float*)d_in[21];

    char* ws = (char*)d_ws;
    size_t off = 0;
    auto alloc = [&](size_t bytes) {
        void* p = ws + off;
        off = (off + bytes + 255) & ~(size_t)255;
        return p;
    };
    unsigned short* HprojQ  = (unsigned short*)alloc((size_t)T_STEPS * BB * HH * 2);
    unsigned short* HpprojQ = (unsigned short*)alloc((size_t)T_STEPS * BB * HH * 2);
    unsigned short* PprojQ  = (unsigned short*)alloc((size_t)T_STEPS * BB * HH * 2);
    float*          DiffQ   = (float*)alloc((size_t)T_STEPS * BB * ZZ * 4);
    float*          MtQ     = (float*)alloc((size_t)T_STEPS * BB * 4);
    unsigned short* zhist   = (unsigned short*)alloc((size_t)(T_STEPS + 1) * BB * SS * ZZ * 2);
    unsigned short* W1z_p   = (unsigned short*)alloc((size_t)ZZ * HH * 2);
    unsigned short* W2_p    = (unsigned short*)alloc((size_t)HH * ZZ * 2);
    unsigned short* PW1z_p  = (unsigned short*)alloc((size_t)ZZ * HH * 2);
    unsigned short* PW2_p   = (unsigned short*)alloc((size_t)HH * DD * 2);
    unsigned short* W1h_p   = (unsigned short*)alloc((size_t)RR * HH * 2);
    unsigned short* PW1h_p  = (unsigned short*)alloc((size_t)RR * HH * 2);
    unsigned short* DW1_p   = (unsigned short*)alloc((size_t)RR * HH * 2);
    unsigned short* DW2_p   = (unsigned short*)alloc((size_t)HH * ZZ * 2);
    unsigned char*  W1z_f8  = (unsigned char*)alloc((size_t)ZZ * HH);
    unsigned char*  W2_f8   = (unsigned char*)alloc((size_t)HH * ZZ);

    hipMemsetAsync(d_out, 0, (size_t)out_size * sizeof(float), stream);

    auto packLaunch = [&](const float* src, int K, int N, unsigned short* dst) {
        int total = (K / 32) * (N / 16) * 64;
        pack_w<<<(total + 255) / 256, 256, 0, stream>>>(src, K, N, dst);
    };
    auto packLaunch8 = [&](const float* src, int K, int N, unsigned char* dst) {
        int total = (K / 32) * (N / 16) * 64;
        pack_w_fp8<<<(total + 255) / 256, 256, 0, stream>>>(src, K, N, dst);
    };
    packLaunch(drift_w1 + (size_t)RR * HH, ZZ, HH, W1z_p);
    packLaunch(drift_w2,                   HH, ZZ, W2_p);
    packLaunch(p_w1 + (size_t)RR * HH,     ZZ, HH, PW1z_p);
    packLaunch(p_w2,                       HH, DD, PW2_p);
    packLaunch(drift_w1, RR, HH, W1h_p);
    packLaunch(p_w1,     RR, HH, PW1h_p);
    packLaunch(diff_w1,  RR, HH, DW1_p);
    packLaunch(diff_w2,  HH, ZZ, DW2_p);
    packLaunch8(drift_w1 + (size_t)RR * HH, ZZ, HH, W1z_f8);
    packLaunch8(drift_w2,                   HH, ZZ, W2_f8);

    mt_kernel<<<(T_STEPS * BB * 64) / 256, 256, 0, stream>>>(M, MtQ);

    precompute_kernel<<<(T_STEPS * BB) / 16, 256, 0, stream>>>(
        path_h, path_hpos, drift_b1, p_b1, diff_b1, diff_b2,
        W1h_p, PW1h_p, DW1_p, DW2_p, HprojQ, HpprojQ, PprojQ, DiffQ);

    float* outp = (float*)d_out;
    float* loss = outp + (size_t)BB * SS * ZZ;

    scan_kernel<<<BB, 512, 0, stream>>>(
        cov, noise, drift_b2, cov_w1, cov_b1, cov_w2, cov_b2,
        W1z_f8, W2_f8, HpprojQ, DiffQ, zhist, outp);

    post_drift<<<(T_STEPS * BB) / 8, 512, 0, stream>>>(
        zhist, HprojQ, HpprojQ, DiffQ, drift_b2, W1z_p, W2_p, loss);

    post_dec<<<(T_STEPS * BB) / 8, 512, 0, stream>>>(
        zhist, PprojQ, X, MtQ, p_b2, PW1z_p, PW2_p, loss);
}

// Round 6
// 2034.327 us; speedup vs baseline: 2.2054x; 1.1004x over previous
//
#include <hip/hip_runtime.h>
#include <cstddef>
#include <cstdint>

#define T_STEPS 200
#define BB 64
#define SS 8
#define DD 128
#define RR 512
#define ZZ 256
#define HH 1024
#define DT 0.05f
#define SQRT_DT 0.22360679774997896f
#define LOG2PIF 1.8378770664093453f

typedef __attribute__((ext_vector_type(8))) short bf16x8;
typedef __attribute__((ext_vector_type(4))) float f32x4;
typedef long f8x8;   // 8 fp8-e4m3 values (2 VGPRs)
#define MFMA __builtin_amdgcn_mfma_f32_16x16x32_bf16
#define MFMA8 __builtin_amdgcn_mfma_f32_16x16x32_fp8_fp8

static __device__ __forceinline__ unsigned short f2bf(float x) {
    unsigned int u = __builtin_bit_cast(unsigned int, x);
    u += 0x7fffu + ((u >> 16) & 1u);
    return (unsigned short)(u >> 16);
}
static __device__ __forceinline__ float bf2f(unsigned short h) {
    unsigned int u = ((unsigned int)h) << 16;
    return __builtin_bit_cast(float, u);
}
static __device__ __forceinline__ float fast_tanh(float x) {
    float e = __expf(2.0f * x);
    return 1.0f - 2.0f / (e + 1.0f);
}
// f32 -> fp8 e4m3 via HW converter (consistent with gfx950 fp8 MFMA decode).
static __device__ __forceinline__ unsigned char f2fp8(float x) {
    unsigned int r = 0;
    asm volatile("v_cvt_pk_fp8_f32 %0, %1, %1" : "+v"(r) : "v"(x));
    return (unsigned char)(r & 0xffu);
}

// LDS-ordering barrier WITHOUT the vmcnt(0) drain __syncthreads would emit:
// producer ds_writes complete (lgkmcnt), all waves meet, no load-queue flush.
// sched_barrier(0) stops post-barrier LDS reads from hoisting above it.
static __device__ __forceinline__ void bar_lds() {
    asm volatile("s_waitcnt lgkmcnt(0)" ::: "memory");
    __builtin_amdgcn_s_barrier();
    __builtin_amdgcn_sched_barrier(0);
}

// ---------------------------------------------------------------------------
// Pack row-major fp32 W[K][N] into bf16 MFMA B-fragment order:
// frag p = nt*(K/32)*64 + ks*64 + lane holds 8 elems: n = nt*16 + (lane&15),
// k = ks*32 + (lane>>4)*8 + i.
// ---------------------------------------------------------------------------
__global__ void pack_w(const float* __restrict__ src, int K, int N,
                       unsigned short* __restrict__ dst) {
    int total = (K >> 5) * (N >> 4) * 64;
    int p = blockIdx.x * blockDim.x + threadIdx.x;
    if (p >= total) return;
    int lane = p & 63;
    int ksteps = K >> 5;
    int ks = (p >> 6) % ksteps;
    int nt = p / (ksteps << 6);
    int n = (nt << 4) + (lane & 15);
    int k0 = (ks << 5) + ((lane >> 4) << 3);
    uint4 u4;
    unsigned short* tmp = reinterpret_cast<unsigned short*>(&u4);
    for (int i = 0; i < 8; ++i) tmp[i] = f2bf(src[(size_t)(k0 + i) * N + n]);
    *reinterpret_cast<uint4*>(dst + (size_t)p * 8) = u4;
}

// Same fragment order, fp8-e4m3 payload (8 B per lane-frag).
__global__ void pack_w_fp8(const float* __restrict__ src, int K, int N,
                           unsigned char* __restrict__ dst) {
    int total = (K >> 5) * (N >> 4) * 64;
    int p = blockIdx.x * blockDim.x + threadIdx.x;
    if (p >= total) return;
    int lane = p & 63;
    int ksteps = K >> 5;
    int ks = (p >> 6) % ksteps;
    int nt = p / (ksteps << 6);
    int n = (nt << 4) + (lane & 15);
    int k0 = (ks << 5) + ((lane >> 4) << 3);
    unsigned long long acc = 0ull;
    for (int i = 0; i < 8; ++i)
        acc |= (unsigned long long)f2fp8(src[(size_t)(k0 + i) * N + n]) << (8 * i);
    *reinterpret_cast<unsigned long long*>(dst + (size_t)p * 8) = acc;
}

// Mt[t,b] = mean over D of M[t,b,:]
__global__ void mt_kernel(const float* __restrict__ M, float* __restrict__ Mt) {
    int wv = (blockIdx.x * blockDim.x + threadIdx.x) >> 6;
    int lane = threadIdx.x & 63;
    if (wv >= T_STEPS * BB) return;
    const float* row = M + (size_t)wv * DD;
    float s = row[lane] + row[lane + 64];
    for (int off = 32; off; off >>= 1) s += __shfl_down(s, off, 64);
    if (lane == 0) Mt[wv] = s * (1.0f / DD);
}

// ---------------------------------------------------------------------------
// Precompute h-only projections (parallel over T*B, 16 rows/block).
// ---------------------------------------------------------------------------
#define PC_GEMM_1024(Asrc, Bp, biasArr, EMIT)                                    \
    {                                                                            \
        f32x4 acc[16];                                                           \
        f32x4 z4 = {0.f, 0.f, 0.f, 0.f};                                        \
        for (int ntl = 0; ntl < 16; ++ntl) acc[ntl] = z4;                        \
        for (int ks = 0; ks < 16; ++ks) {                                        \
            bf16x8 a = *(const bf16x8*)&Asrc[l][(ks << 5) + (q << 3)];           \
            for (int ntl = 0; ntl < 16; ++ntl) {                                 \
                int ntg = (w << 4) + ntl;                                        \
                bf16x8 bb = *(const bf16x8*)(Bp +                                \
                             (((size_t)ntg * 16 + ks) * 64 + lane) * 8);         \
                acc[ntl] = MFMA(a, bb, acc[ntl], 0, 0, 0);                       \
            }                                                                    \
        }                                                                        \
        for (int ntl = 0; ntl < 16; ++ntl) {                                     \
            int n = (((w << 4) + ntl) << 4) + l;                                 \
            float bv = biasArr[n];                                               \
            for (int i = 0; i < 4; ++i) {                                        \
                int rr = (q << 2) + i;                                           \
                float v = acc[ntl][i] + bv;                                      \
                EMIT;                                                            \
            }                                                                    \
        }                                                                        \
    }

__global__ __launch_bounds__(256)
void precompute_kernel(const float* __restrict__ h, const float* __restrict__ hpos,
                       const float* __restrict__ b1d, const float* __restrict__ b1p,
                       const float* __restrict__ b1f, const float* __restrict__ b2f,
                       const unsigned short* __restrict__ W1h_p,
                       const unsigned short* __restrict__ PW1h_p,
                       const unsigned short* __restrict__ DW1_p,
                       const unsigned short* __restrict__ DW2_p,
                       unsigned short* __restrict__ HprojQ,
                       unsigned short* __restrict__ HpprojQ,
                       unsigned short* __restrict__ PprojQ,
                       float* __restrict__ DiffQ) {
    __shared__ unsigned short Ahh[16][RR + 8];
    __shared__ unsigned short Ahp[16][RR + 8];
    __shared__ unsigned short Adh[16][HH + 8];
    const int tid = threadIdx.x;
    const int lane = tid & 63;
    const int w = tid >> 6;
    const int q = lane >> 4;
    const int l = lane & 15;
    const int r0 = blockIdx.x << 4;

    for (int idx = tid; idx < (RR << 4); idx += 256) {
        int r = idx >> 9, c = idx & (RR - 1);
        Ahh[r][c] = f2bf(h[(size_t)(r0 + r) * RR + c]);
        Ahp[r][c] = f2bf(hpos[(size_t)(r0 + r) * RR + c]);
    }
    __syncthreads();

    PC_GEMM_1024(Ahh, W1h_p,  b1d, (HprojQ [(size_t)(r0 + rr) * HH + n] = f2bf(v)));
    PC_GEMM_1024(Ahp, W1h_p,  b1d, (HpprojQ[(size_t)(r0 + rr) * HH + n] = f2bf(v)));
    PC_GEMM_1024(Ahh, PW1h_p, b1p, (PprojQ [(size_t)(r0 + rr) * HH + n] = f2bf(v)));
    PC_GEMM_1024(Ahh, DW1_p,  b1f, (Adh[rr][n] = f2bf(fmaxf(v, 0.f))));
    __syncthreads();

    {
        f32x4 acc[4];
        f32x4 z4 = {0.f, 0.f, 0.f, 0.f};
        for (int ntl = 0; ntl < 4; ++ntl) acc[ntl] = z4;
        for (int ks = 0; ks < 32; ++ks) {
            bf16x8 a = *(const bf16x8*)&Adh[l][(ks << 5) + (q << 3)];
            for (int ntl = 0; ntl < 4; ++ntl) {
                int ntg = (w << 2) + ntl;
                bf16x8 bb = *(const bf16x8*)(DW2_p +
                             (((size_t)ntg * 32 + ks) * 64 + lane) * 8);
                acc[ntl] = MFMA(a, bb, acc[ntl], 0, 0, 0);
            }
        }
        for (int ntl = 0; ntl < 4; ++ntl) {
            int n = (((w << 2) + ntl) << 4) + l;
            float bv = b2f[n];
            for (int i = 0; i < 4; ++i) {
                int rr = (q << 2) + i;
                DiffQ[(size_t)(r0 + rr) * ZZ + n] = __expf(acc[ntl][i] + bv);
            }
        }
    }
}

// ---------------------------------------------------------------------------
// Sequential scan, WEIGHT-RESIDENT fp8, PRIOR PATH FUSED. 64 blocks x 512 thr.
// MFMA rows 0-7 = posterior samples, rows 8-15 = prior path: A-rows 8-15
// duplicate z, so C-rows 8-15 already hold z@W1z — the G1 epilogue adds
// Hproj (prior) instead of Hpproj (posterior) and G2's A-read uses Ah8[l]
// (rows 8-15 = prior hidden). Prior drift pre lands 32 lanes above its
// posterior partner -> one shfl_xor(32) pairs them; kld accumulated
// in-register across all 200 steps; post_drift kernel DELETED.
// Zero additional MFMA; posterior math bit-identical to round 5.
// ---------------------------------------------------------------------------
__global__ __launch_bounds__(512, 2)
void scan_kernel(const float* __restrict__ cov, const float* __restrict__ noise,
                 const float* __restrict__ b2d,
                 const float* __restrict__ cw1, const float* __restrict__ cb1,
                 const float* __restrict__ cw2, const float* __restrict__ cb2,
                 const unsigned char* __restrict__ W1z_f8,
                 const unsigned char* __restrict__ W2_f8,
                 const unsigned short* __restrict__ HpprojQ,
                 const unsigned short* __restrict__ HprojQ,
                 const float* __restrict__ DiffQ,
                 unsigned short* __restrict__ zhist,
                 float* __restrict__ out,
                 float* __restrict__ loss) {
    __shared__ __align__(16) long W2L[256][64];           // 128 KiB: W2 tile-B frags
    __shared__ __align__(8) unsigned char Az8[8][272];    // z fp8 (8 rows)
    __shared__ __align__(8) unsigned char Ah8[16][1040];  // hidden fp8 (post|prior)
    __shared__ float zf[8][256];                          // fp32 master z
    __shared__ float ch[64];

    const int tid = threadIdx.x;
    const int lane = tid & 63;
    const int w = tid >> 6;   // 8 waves
    const int q = lane >> 4;
    const int l = lane & 15;
    const int b = blockIdx.x;

    // ---- one-time weight residency ----
    f8x8 w1r[8][8];
    #pragma unroll
    for (int ntl = 0; ntl < 8; ++ntl)
        #pragma unroll
        for (int ks = 0; ks < 8; ++ks)
            w1r[ntl][ks] = *(const f8x8*)(W1z_f8 +
                ((((size_t)(w * 8 + ntl) * 8 + ks) * 64 + lane) << 3));
    f8x8 w2r[32];
    #pragma unroll
    for (int ks = 0; ks < 32; ++ks)
        w2r[ks] = *(const f8x8*)(W2_f8 +
            ((((size_t)(w * 2) * 32 + ks) * 64 + lane) << 3));
    #pragma unroll
    for (int ks = 0; ks < 32; ++ks)
        W2L[w * 32 + ks][lane] = *(const long*)(W2_f8 +
            ((((size_t)(w * 2 + 1) * 32 + ks) * 64 + lane) << 3));

    // ---- prologue: z0 = tanh(MLP(cov)) ----
    if (tid < 64) {
        float s = cb1[tid];
        for (int c = 0; c < 16; ++c) s += cov[b * 16 + c] * cw1[c * 64 + tid];
        ch[tid] = fmaxf(s, 0.f);
    }
    __syncthreads();
    if (tid < ZZ) {
        float v = cb2[tid];
        for (int j = 0; j < 64; ++j) v += ch[j] * cw2[j * ZZ + tid];
        v = fast_tanh(v);
        unsigned short hv = f2bf(v);
        unsigned char zb = f2fp8(v);
        for (int s = 0; s < SS; ++s) {
            zf[s][tid] = v;
            Az8[s][tid] = zb;
            zhist[((size_t)b * SS + s) * ZZ + tid] = hv;   // slot 0
        }
    }

    const int colA = (w << 5) + l;       // z col for G2 tile A
    const int colB = colA + 16;          // tile B
    float b2dA = b2d[colA], b2dB = b2d[colB];
    float kacc = 0.f;                    // kld accumulator (q<2 lanes)

    // per-step scalars, prefetched one step ahead (live across barriers:
    // bar_lds() does not drain vmcnt). hpr: lower lanes = posterior proj,
    // upper lanes = prior proj (each lane only feeds its own output rows).
    float epsA[4], epsB[4], difA = 0.f, difB = 0.f;
    unsigned short hpr[8];
#define LOAD_SCALARS(TI)                                                        \
    do {                                                                        \
        const size_t tb_ = (size_t)(TI) * BB + b;                               \
        const unsigned short* ps_ = (q < 2) ? HpprojQ : HprojQ;                 \
        _Pragma("unroll")                                                       \
        for (int ntl = 0; ntl < 8; ++ntl)                                       \
            hpr[ntl] = ps_[tb_ * HH + (size_t)(w * 8 + ntl) * 16 + l];          \
        if (q < 2) {                                                            \
            _Pragma("unroll")                                                   \
            for (int i = 0; i < 4; ++i) {                                       \
                epsA[i] = noise[((tb_ << 3) + (q << 2) + i) * ZZ + colA];       \
                epsB[i] = noise[((tb_ << 3) + (q << 2) + i) * ZZ + colB];       \
            }                                                                   \
            difA = DiffQ[tb_ * ZZ + colA];                                      \
            difB = DiffQ[tb_ * ZZ + colB];                                      \
        }                                                                       \
    } while (0)

    LOAD_SCALARS(0);
    __syncthreads();   // z0/weights visible (one-time full drain is fine)

    for (int t = 0; t < T_STEPS; ++t) {
        // ---- G1: hidden[16][1024] = relu(proj + z @ W1z); rows 8-15 reuse
        //      the duplicate-z MFMA rows for the PRIOR path (free).
        #pragma unroll
        for (int h = 0; h < 2; ++h) {
            f32x4 acc[4];
            {
                f32x4 z4 = {0.f, 0.f, 0.f, 0.f};
                #pragma unroll
                for (int j = 0; j < 4; ++j) acc[j] = z4;
            }
            #pragma unroll
            for (int ks = 0; ks < 8; ++ks) {
                f8x8 a1 = *(const f8x8*)&Az8[l & 7][(ks << 5) + (q << 3)];
                #pragma unroll
                for (int j = 0; j < 4; ++j)
                    acc[j] = MFMA8(a1, w1r[h * 4 + j][ks], acc[j], 0, 0, 0);
            }
            #pragma unroll
            for (int j = 0; j < 4; ++j) {
                int ntl = h * 4 + j;
                int n = (w * 8 + ntl) * 16 + l;
                float hp = bf2f(hpr[ntl]);
                #pragma unroll
                for (int i = 0; i < 4; ++i)
                    Ah8[(q << 2) + i][n] = f2fp8(fmaxf(hp + acc[j][i], 0.f));
            }
        }
        bar_lds();

        // ---- G2: drift[16][256] = hidden @ W2 (rows 0-7 post, 8-15 prior)
        f32x4 aA[2], aB[2];
        {
            f32x4 z4 = {0.f, 0.f, 0.f, 0.f};
            aA[0] = z4; aA[1] = z4; aB[0] = z4; aB[1] = z4;
        }
        #pragma unroll
        for (int ks = 0; ks < 32; ++ks) {
            f8x8 a2 = *(const f8x8*)&Ah8[l][(ks << 5) + (q << 3)];
            f8x8 bB = (f8x8)W2L[w * 32 + ks][lane];
            aA[ks & 1] = MFMA8(a2, w2r[ks], aA[ks & 1], 0, 0, 0);
            aB[ks & 1] = MFMA8(a2, bB, aB[ks & 1], 0, 0, 0);
        }
        #pragma unroll
        for (int i = 0; i < 4; ++i) {
            float preA = aA[0][i] + aA[1][i] + b2dA;
            float preB = aB[0][i] + aB[1][i] + b2dB;
            float opA = __shfl_xor(preA, 32, 64);   // prior pre for lower half
            float opB = __shfl_xor(preB, 32, 64);
            if (q < 2) {
                int s = (q << 2) + i;
                float poA = 0.1f * fast_tanh(preA);
                float poB = 0.1f * fast_tanh(preB);
                float prA = 0.1f * fast_tanh(opA);
                float prB = 0.1f * fast_tanh(opB);
                float eA = (prA - poA) / difA;
                float eB = (prB - poB) / difB;
                kacc += eA * eA + eB * eB;
                zf[s][colA] += DT * poA + SQRT_DT * difA * epsA[i];
                zf[s][colB] += DT * poB + SQRT_DT * difB * epsB[i];
            }
        }
        // prefetch next step's scalars (loads stay in flight across raw barriers)
        if (t + 1 < T_STEPS) LOAD_SCALARS(t + 1);
        bar_lds();

        // ---- normalize: wave w owns z-row w; write Az8 + zhist(t+1)
        {
            float v0 = zf[w][lane], v1 = zf[w][lane + 64];
            float v2 = zf[w][lane + 128], v3 = zf[w][lane + 192];
            float mn = fminf(fminf(v0, v1), fminf(v2, v3));
            float mx = fmaxf(fmaxf(v0, v1), fmaxf(v2, v3));
            for (int off = 32; off; off >>= 1) {
                mn = fminf(mn, __shfl_xor(mn, off, 64));
                mx = fmaxf(mx, __shfl_xor(mx, off, 64));
            }
            float sc = 1.0f / (mx - mn);
            v0 = (v0 - mn) * sc; v1 = (v1 - mn) * sc;
            v2 = (v2 - mn) * sc; v3 = (v3 - mn) * sc;
            zf[w][lane] = v0; zf[w][lane + 64] = v1;
            zf[w][lane + 128] = v2; zf[w][lane + 192] = v3;
            Az8[w][lane] = f2fp8(v0); Az8[w][lane + 64] = f2fp8(v1);
            Az8[w][lane + 128] = f2fp8(v2); Az8[w][lane + 192] = f2fp8(v3);
            unsigned short h0 = f2bf(v0), h1 = f2bf(v1), h2 = f2bf(v2), h3 = f2bf(v3);
            size_t zo = ((size_t)(t + 1) * BB + b) * (SS * ZZ) + (size_t)w * ZZ;
            volatile unsigned short* zh = (volatile unsigned short*)zhist;
            zh[zo + lane] = h0; zh[zo + lane + 64] = h1;
            zh[zo + lane + 128] = h2; zh[zo + lane + 192] = h3;
        }
        bar_lds();   // Az8/zf ready for next step's G1
    }
    __syncthreads();

    for (int idx = tid; idx < SS * ZZ; idx += 512) {
        int s = idx >> 8, n = idx & 255;
        out[((size_t)b * SS + s) * ZZ + n] = zf[s][n];
    }

    // ---- kld reduction: wave -> block -> one atomic per block ----
    for (int off = 32; off; off >>= 1) kacc += __shfl_down(kacc, off, 64);
    if (lane == 0) ch[w] = kacc;
    __syncthreads();
    if (tid == 0) {
        float K = 0.f;
        for (int i = 0; i < 8; ++i) K += ch[i];
        float kc = K * (0.5f * DT / (SS * BB));
        atomicAdd(loss + 0, kc);
        atomicAdd(loss + 2, kc);
    }
#undef LOAD_SCALARS
}

// ---------------------------------------------------------------------------
// Parallel post-pass: decoder on z_{t+1} -> recon. (bf16, unchanged)
// ---------------------------------------------------------------------------
__global__ __launch_bounds__(512, 4)
void post_dec(const unsigned short* __restrict__ zhist,
              const unsigned short* __restrict__ PprojQ,
              const float* __restrict__ X, const float* __restrict__ MtQ,
              const float* __restrict__ b2p,
              const unsigned short* __restrict__ PW1z_p,
              const unsigned short* __restrict__ PW2_p,
              float* __restrict__ loss) {
    __shared__ unsigned short Az[4][16][ZZ + 8];
    __shared__ unsigned short Hp[4][16][136];
    __shared__ unsigned short ProjS[8][128];
    __shared__ float b2p_s[DD];
    __shared__ float red[8];
    const int tid = threadIdx.x;
    const int lane = tid & 63;
    const int w = tid >> 6;
    const int q = lane >> 4;
    const int l = lane & 15;
    const int rt = w & 3;
    const int half = w >> 2;
    const int p0 = blockIdx.x << 3;

    for (int idx = tid; idx < 4096; idx += 512) {
        int r = idx >> 6, c4 = (idx & 63) << 2;
        *(ushort4*)&Az[r >> 4][r & 15][c4] =
            *(const ushort4*)&zhist[((size_t)(p0 + BB) * SS + r) * ZZ + c4];  // slot t+1
    }
    if (tid < DD) b2p_s[tid] = b2p[tid];

    f32x4 pacc[4];
    {
        f32x4 z4 = {0.f, 0.f, 0.f, 0.f};
        #pragma unroll
        for (int j = 0; j < 4; ++j) pacc[j] = z4;
    }

    for (int nc = 0; nc < 8; ++nc) {
        if (tid < 256) {
            int pair = tid >> 5, c4 = (tid & 31) << 2;
            *(ushort4*)&ProjS[pair][c4] =
                *(const ushort4*)&PprojQ[(size_t)(p0 + pair) * HH + nc * 128 + c4];
        }
        __syncthreads();

        f32x4 za[4];
        {
            f32x4 z4 = {0.f, 0.f, 0.f, 0.f};
            #pragma unroll
            for (int j = 0; j < 4; ++j) za[j] = z4;
        }
        {
            const unsigned short* wb = PW1z_p + lane * 8;
            bf16x8 wq[4];
            #pragma unroll
            for (int f = 0; f < 4; ++f) {
                int ks = f >> 2, j = f & 3;
                wq[f] = *(const bf16x8*)(wb +
                    ((size_t)((nc * 8 + half * 4 + j) * 8 + ks)) * 512);
            }
            #pragma unroll
            for (int f = 0; f < 32; ++f) {
                int ks = f >> 2, j = f & 3;
                bf16x8 a = *(const bf16x8*)&Az[rt][l][(ks << 5) + (q << 3)];
                za[j] = MFMA(a, wq[f & 3], za[j], 0, 0, 0);
                if (f < 28) {
                    int f2 = f + 4, ks2 = f2 >> 2, j2 = f2 & 3;
                    wq[f & 3] = *(const bf16x8*)(wb +
                        ((size_t)((nc * 8 + half * 4 + j2) * 8 + ks2)) * 512);
                }
            }
        }
        #pragma unroll
        for (int j = 0; j < 4; ++j) {
            int c = (half * 4 + j) * 16 + l;
            #pragma unroll
            for (int i = 0; i < 4; ++i) {
                int r = (q << 2) + i;
                int pair = ((rt << 4) + r) >> 3;
                Hp[rt][r][c] = f2bf(fmaxf(bf2f(ProjS[pair][c]) + za[j][i], 0.f));
            }
        }
        __syncthreads();

        {
            const unsigned short* wb2 = PW2_p + lane * 8;
            bf16x8 wq2[4];
            #pragma unroll
            for (int f = 0; f < 4; ++f) {
                int kk = f >> 2, j = f & 3;
                wq2[f] = *(const bf16x8*)(wb2 +
                    ((size_t)((half * 4 + j) * 32 + nc * 4 + kk)) * 512);
            }
            #pragma unroll
            for (int f = 0; f < 16; ++f) {
                int kk = f >> 2, j = f & 3;
                bf16x8 a = *(const bf16x8*)&Hp[rt][l][(kk << 5) + (q << 3)];
                pacc[j] = MFMA(a, wq2[f & 3], pacc[j], 0, 0, 0);
                if (f < 12) {
                    int f2 = f + 4, kk2 = f2 >> 2, j2 = f2 & 3;
                    wq2[f & 3] = *(const bf16x8*)(wb2 +
                        ((size_t)((half * 4 + j2) * 32 + nc * 4 + kk2)) * 512);
                }
            }
        }
        __syncthreads();
    }

    float rl = 0.f;
    #pragma unroll
    for (int j = 0; j < 4; ++j) {
        int n = ((half << 2) + j) * 16 + l;
        float bias = b2p_s[n];
        #pragma unroll
        for (int i = 0; i < 4; ++i) {
            int r = (rt << 4) + (q << 2) + i;
            int pair = p0 + (r >> 3);
            float p = pacc[j][i] + bias;
            float d = X[(size_t)pair * DD + n] - p;
            rl += (0.5f * (LOG2PIF + d * d)) * MtQ[pair];
        }
    }
    rl *= 1.0f / (SS * BB);
    for (int off = 32; off; off >>= 1) rl += __shfl_down(rl, off, 64);
    if (lane == 0) red[w] = rl;
    __syncthreads();
    if (tid == 0) {
        float R = 0.f;
        for (int i = 0; i < 8; ++i) R += red[i];
        atomicAdd(loss + 0, R);
        atomicAdd(loss + 1, R);
    }
}

extern "C" void kernel_launch(void* const* d_in, const int* in_sizes, int n_in,
                              void* d_out, int out_size, void* d_ws, size_t ws_size,
                              hipStream_t stream) {
    (void)in_sizes; (void)n_in; (void)ws_size;
    const float* X         = (const float*)d_in[0];
    const float* M         = (const float*)d_in[1];
    const float* cov       = (const float*)d_in[2];
    const float* path_h    = (const float*)d_in[3];
    const float* path_hpos = (const float*)d_in[4];
    const float* noise     = (const float*)d_in[5];
    const float* drift_w1  = (const float*)d_in[6];
    const float* drift_b1  = (const float*)d_in[7];
    const float* drift_w2  = (const float*)d_in[8];
    const float* drift_b2  = (const float*)d_in[9];
    const float* diff_w1   = (const float*)d_in[10];
    const float* diff_b1   = (const float*)d_in[11];
    const float* diff_w2   = (const float*)d_in[12];
    const float* diff_b2   = (const float*)d_in[13];
    const float* p_w1      = (const float*)d_in[14];
    const float* p_b1      = (const float*)d_in[15];
    const float* p_w2      = (const float*)d_in[16];
    const float* p_b2      = (const float*)d_in[17];
    const float* cov_w1    = (const float*)d_in[18];
    const float* cov_b1    = (const float*)d_in[19];
    const float* cov_w2    = (const float*)d_in[20];
    const float* cov_b2    = (const float*)d_in[21];

    char* ws = (char*)d_ws;
    size_t off = 0;
    auto alloc = [&](size_t bytes) {
        void* p = ws + off;
        off = (off + bytes + 255) & ~(size_t)255;
        return p;
    };
    unsigned short* HprojQ  = (unsigned short*)alloc((size_t)T_STEPS * BB * HH * 2);
    unsigned short* HpprojQ = (unsigned short*)alloc((size_t)T_STEPS * BB * HH * 2);
    unsigned short* PprojQ  = (unsigned short*)alloc((size_t)T_STEPS * BB * HH * 2);
    float*          DiffQ   = (float*)alloc((size_t)T_STEPS * BB * ZZ * 4);
    float*          MtQ     = (float*)alloc((size_t)T_STEPS * BB * 4);
    unsigned short* zhist   = (unsigned short*)alloc((size_t)(T_STEPS + 1) * BB * SS * ZZ * 2);
    unsigned short* PW1z_p  = (unsigned short*)alloc((size_t)ZZ * HH * 2);
    unsigned short* PW2_p   = (unsigned short*)alloc((size_t)HH * DD * 2);
    unsigned short* W1h_p   = (unsigned short*)alloc((size_t)RR * HH * 2);
    unsigned short* PW1h_p  = (unsigned short*)alloc((size_t)RR * HH * 2);
    unsigned short* DW1_p   = (unsigned short*)alloc((size_t)RR * HH * 2);
    unsigned short* DW2_p   = (unsigned short*)alloc((size_t)HH * ZZ * 2);
    unsigned char*  W1z_f8  = (unsigned char*)alloc((size_t)ZZ * HH);
    unsigned char*  W2_f8   = (unsigned char*)alloc((size_t)HH * ZZ);

    hipMemsetAsync(d_out, 0, (size_t)out_size * sizeof(float), stream);

    auto packLaunch = [&](const float* src, int K, int N, unsigned short* dst) {
        int total = (K / 32) * (N / 16) * 64;
        pack_w<<<(total + 255) / 256, 256, 0, stream>>>(src, K, N, dst);
    };
    auto packLaunch8 = [&](const float* src, int K, int N, unsigned char* dst) {
        int total = (K / 32) * (N / 16) * 64;
        pack_w_fp8<<<(total + 255) / 256, 256, 0, stream>>>(src, K, N, dst);
    };
    packLaunch(p_w1 + (size_t)RR * HH,     ZZ, HH, PW1z_p);
    packLaunch(p_w2,                       HH, DD, PW2_p);
    packLaunch(drift_w1, RR, HH, W1h_p);
    packLaunch(p_w1,     RR, HH, PW1h_p);
    packLaunch(diff_w1,  RR, HH, DW1_p);
    packLaunch(diff_w2,  HH, ZZ, DW2_p);
    packLaunch8(drift_w1 + (size_t)RR * HH, ZZ, HH, W1z_f8);
    packLaunch8(drift_w2,                   HH, ZZ, W2_f8);

    mt_kernel<<<(T_STEPS * BB * 64) / 256, 256, 0, stream>>>(M, MtQ);

    precompute_kernel<<<(T_STEPS * BB) / 16, 256, 0, stream>>>(
        path_h, path_hpos, drift_b1, p_b1, diff_b1, diff_b2,
        W1h_p, PW1h_p, DW1_p, DW2_p, HprojQ, HpprojQ, PprojQ, DiffQ);

    float* outp = (float*)d_out;
    float* loss = outp + (size_t)BB * SS * ZZ;

    scan_kernel<<<BB, 512, 0, stream>>>(
        cov, noise, drift_b2, cov_w1, cov_b1, cov_w2, cov_b2,
        W1z_f8, W2_f8, HpprojQ, HprojQ, DiffQ, zhist, outp, loss);

    post_dec<<<(T_STEPS * BB) / 8, 512, 0, stream>>>(
        zhist, PprojQ, X, MtQ, p_b2, PW1z_p, PW2_p, loss);
}

// Round 7
// 1734.994 us; speedup vs baseline: 2.5858x; 1.1725x over previous
//
#include <hip/hip_runtime.h>
#include <cstddef>
#include <cstdint>

#define T_STEPS 200
#define BB 64
#define SS 8
#define DD 128
#define RR 512
#define ZZ 256
#define HH 1024
#define DT 0.05f
#define SQRT_DT 0.22360679774997896f
#define LOG2PIF 1.8378770664093453f

typedef __attribute__((ext_vector_type(8))) short bf16x8;
typedef __attribute__((ext_vector_type(4))) float f32x4;
typedef long f8x8;   // 8 fp8-e4m3 values (2 VGPRs)
#define MFMA __builtin_amdgcn_mfma_f32_16x16x32_bf16
#define MFMA8 __builtin_amdgcn_mfma_f32_16x16x32_fp8_fp8

static __device__ __forceinline__ unsigned short f2bf(float x) {
    unsigned int u = __builtin_bit_cast(unsigned int, x);
    u += 0x7fffu + ((u >> 16) & 1u);
    return (unsigned short)(u >> 16);
}
static __device__ __forceinline__ float bf2f(unsigned short h) {
    unsigned int u = ((unsigned int)h) << 16;
    return __builtin_bit_cast(float, u);
}
static __device__ __forceinline__ float fast_tanh(float x) {
    float e = __expf(2.0f * x);
    return 1.0f - 2.0f / (e + 1.0f);
}
// f32 -> fp8 e4m3 via HW converter (consistent with gfx950 fp8 MFMA decode).
static __device__ __forceinline__ unsigned char f2fp8(float x) {
    unsigned int r = 0;
    asm volatile("v_cvt_pk_fp8_f32 %0, %1, %1" : "+v"(r) : "v"(x));
    return (unsigned char)(r & 0xffu);
}
// Pack 4 f32 -> 4 fp8 bytes (same HW conversion as f2fp8, 2 insts).
static __device__ __forceinline__ unsigned int f2fp8x4(float a, float b,
                                                      float c, float d) {
    unsigned int p01 = 0, p23 = 0;
    asm volatile("v_cvt_pk_fp8_f32 %0, %1, %2" : "+v"(p01) : "v"(a), "v"(b));
    asm volatile("v_cvt_pk_fp8_f32 %0, %1, %2" : "+v"(p23) : "v"(c), "v"(d));
    return (p01 & 0xffffu) | (p23 << 16);
}

// LDS-ordering barrier WITHOUT the vmcnt(0) drain __syncthreads would emit:
// producer ds_writes complete (lgkmcnt), all waves meet, no load-queue flush.
// sched_barrier(0) stops post-barrier LDS reads from hoisting above it.
static __device__ __forceinline__ void bar_lds() {
    asm volatile("s_waitcnt lgkmcnt(0)" ::: "memory");
    __builtin_amdgcn_s_barrier();
    __builtin_amdgcn_sched_barrier(0);
}

// ---------------------------------------------------------------------------
// Pack row-major fp32 W[K][N] into bf16 MFMA B-fragment order:
// frag p = nt*(K/32)*64 + ks*64 + lane holds 8 elems: n = nt*16 + (lane&15),
// k = ks*32 + (lane>>4)*8 + i.
// ---------------------------------------------------------------------------
__global__ void pack_w(const float* __restrict__ src, int K, int N,
                       unsigned short* __restrict__ dst) {
    int total = (K >> 5) * (N >> 4) * 64;
    int p = blockIdx.x * blockDim.x + threadIdx.x;
    if (p >= total) return;
    int lane = p & 63;
    int ksteps = K >> 5;
    int ks = (p >> 6) % ksteps;
    int nt = p / (ksteps << 6);
    int n = (nt << 4) + (lane & 15);
    int k0 = (ks << 5) + ((lane >> 4) << 3);
    uint4 u4;
    unsigned short* tmp = reinterpret_cast<unsigned short*>(&u4);
    for (int i = 0; i < 8; ++i) tmp[i] = f2bf(src[(size_t)(k0 + i) * N + n]);
    *reinterpret_cast<uint4*>(dst + (size_t)p * 8) = u4;
}

// Same fragment order, fp8-e4m3 payload (8 B per lane-frag).
__global__ void pack_w_fp8(const float* __restrict__ src, int K, int N,
                           unsigned char* __restrict__ dst) {
    int total = (K >> 5) * (N >> 4) * 64;
    int p = blockIdx.x * blockDim.x + threadIdx.x;
    if (p >= total) return;
    int lane = p & 63;
    int ksteps = K >> 5;
    int ks = (p >> 6) % ksteps;
    int nt = p / (ksteps << 6);
    int n = (nt << 4) + (lane & 15);
    int k0 = (ks << 5) + ((lane >> 4) << 3);
    unsigned long long acc = 0ull;
    for (int i = 0; i < 8; ++i)
        acc |= (unsigned long long)f2fp8(src[(size_t)(k0 + i) * N + n]) << (8 * i);
    *reinterpret_cast<unsigned long long*>(dst + (size_t)p * 8) = acc;
}

// Mt[t,b] = mean over D of M[t,b,:]
__global__ void mt_kernel(const float* __restrict__ M, float* __restrict__ Mt) {
    int wv = (blockIdx.x * blockDim.x + threadIdx.x) >> 6;
    int lane = threadIdx.x & 63;
    if (wv >= T_STEPS * BB) return;
    const float* row = M + (size_t)wv * DD;
    float s = row[lane] + row[lane + 64];
    for (int off = 32; off; off >>= 1) s += __shfl_down(s, off, 64);
    if (lane == 0) Mt[wv] = s * (1.0f / DD);
}

// ---------------------------------------------------------------------------
// Precompute h-only projections (parallel over T*B, 16 rows/block).
// ---------------------------------------------------------------------------
#define PC_GEMM_1024(Asrc, Bp, biasArr, EMIT)                                    \
    {                                                                            \
        f32x4 acc[16];                                                           \
        f32x4 z4 = {0.f, 0.f, 0.f, 0.f};                                        \
        for (int ntl = 0; ntl < 16; ++ntl) acc[ntl] = z4;                        \
        for (int ks = 0; ks < 16; ++ks) {                                        \
            bf16x8 a = *(const bf16x8*)&Asrc[l][(ks << 5) + (q << 3)];           \
            for (int ntl = 0; ntl < 16; ++ntl) {                                 \
                int ntg = (w << 4) + ntl;                                        \
                bf16x8 bb = *(const bf16x8*)(Bp +                                \
                             (((size_t)ntg * 16 + ks) * 64 + lane) * 8);         \
                acc[ntl] = MFMA(a, bb, acc[ntl], 0, 0, 0);                       \
            }                                                                    \
        }                                                                        \
        for (int ntl = 0; ntl < 16; ++ntl) {                                     \
            int n = (((w << 4) + ntl) << 4) + l;                                 \
            float bv = biasArr[n];                                               \
            for (int i = 0; i < 4; ++i) {                                        \
                int rr = (q << 2) + i;                                           \
                float v = acc[ntl][i] + bv;                                      \
                EMIT;                                                            \
            }                                                                    \
        }                                                                        \
    }

__global__ __launch_bounds__(256)
void precompute_kernel(const float* __restrict__ h, const float* __restrict__ hpos,
                       const float* __restrict__ b1d, const float* __restrict__ b1p,
                       const float* __restrict__ b1f, const float* __restrict__ b2f,
                       const unsigned short* __restrict__ W1h_p,
                       const unsigned short* __restrict__ PW1h_p,
                       const unsigned short* __restrict__ DW1_p,
                       const unsigned short* __restrict__ DW2_p,
                       unsigned short* __restrict__ HprojQ,
                       unsigned short* __restrict__ HpprojQ,
                       unsigned short* __restrict__ PprojQ,
                       float* __restrict__ DiffQ) {
    __shared__ unsigned short Ahh[16][RR + 8];
    __shared__ unsigned short Ahp[16][RR + 8];
    __shared__ unsigned short Adh[16][HH + 8];
    const int tid = threadIdx.x;
    const int lane = tid & 63;
    const int w = tid >> 6;
    const int q = lane >> 4;
    const int l = lane & 15;
    const int r0 = blockIdx.x << 4;

    for (int idx = tid; idx < (RR << 4); idx += 256) {
        int r = idx >> 9, c = idx & (RR - 1);
        Ahh[r][c] = f2bf(h[(size_t)(r0 + r) * RR + c]);
        Ahp[r][c] = f2bf(hpos[(size_t)(r0 + r) * RR + c]);
    }
    __syncthreads();

    PC_GEMM_1024(Ahh, W1h_p,  b1d, (HprojQ [(size_t)(r0 + rr) * HH + n] = f2bf(v)));
    PC_GEMM_1024(Ahp, W1h_p,  b1d, (HpprojQ[(size_t)(r0 + rr) * HH + n] = f2bf(v)));
    PC_GEMM_1024(Ahh, PW1h_p, b1p, (PprojQ [(size_t)(r0 + rr) * HH + n] = f2bf(v)));
    PC_GEMM_1024(Ahh, DW1_p,  b1f, (Adh[rr][n] = f2bf(fmaxf(v, 0.f))));
    __syncthreads();

    {
        f32x4 acc[4];
        f32x4 z4 = {0.f, 0.f, 0.f, 0.f};
        for (int ntl = 0; ntl < 4; ++ntl) acc[ntl] = z4;
        for (int ks = 0; ks < 32; ++ks) {
            bf16x8 a = *(const bf16x8*)&Adh[l][(ks << 5) + (q << 3)];
            for (int ntl = 0; ntl < 4; ++ntl) {
                int ntg = (w << 2) + ntl;
                bf16x8 bb = *(const bf16x8*)(DW2_p +
                             (((size_t)ntg * 32 + ks) * 64 + lane) * 8);
                acc[ntl] = MFMA(a, bb, acc[ntl], 0, 0, 0);
            }
        }
        for (int ntl = 0; ntl < 4; ++ntl) {
            int n = (((w << 2) + ntl) << 4) + l;
            float bv = b2f[n];
            for (int i = 0; i < 4; ++i) {
                int rr = (q << 2) + i;
                DiffQ[(size_t)(r0 + rr) * ZZ + n] = __expf(acc[ntl][i] + bv);
            }
        }
    }
}

// ---------------------------------------------------------------------------
// Sequential scan, WEIGHT-RESIDENT fp8, PRIOR PATH FUSED. 64 blocks x 512 thr.
// Round-7 deltas (bit-exact vs round 6):
//  - Ah8 row stride 1040 -> 1032 (== 8 mod 128): G2's 16-row A-read maps
//    (row,q) onto 16 disjoint even bank-pairs -> 4-cycle optimal (round-6
//    counters showed 9x SQ_LDS_BANK_CONFLICT from the 16-row read at 1040).
//  - normalize vectorized: lane owns 4 CONSECUTIVE cols -> float4 zf
//    read/write, packed v_cvt_pk_fp8_f32 -> one b32 Az8 store, ushort4
//    zhist store. Same 256-value min/max set (exact, order-independent),
//    same rescale ops -> bit-identical output.
// ---------------------------------------------------------------------------
__global__ __launch_bounds__(512, 2)
void scan_kernel(const float* __restrict__ cov, const float* __restrict__ noise,
                 const float* __restrict__ b2d,
                 const float* __restrict__ cw1, const float* __restrict__ cb1,
                 const float* __restrict__ cw2, const float* __restrict__ cb2,
                 const unsigned char* __restrict__ W1z_f8,
                 const unsigned char* __restrict__ W2_f8,
                 const unsigned short* __restrict__ HpprojQ,
                 const unsigned short* __restrict__ HprojQ,
                 const float* __restrict__ DiffQ,
                 unsigned short* __restrict__ zhist,
                 float* __restrict__ out,
                 float* __restrict__ loss) {
    __shared__ __align__(16) long W2L[256][64];           // 128 KiB: W2 tile-B frags
    __shared__ __align__(8) unsigned char Az8[8][272];    // z fp8 (8 rows)
    __shared__ __align__(8) unsigned char Ah8[16][1032];  // hidden fp8 (post|prior)
    __shared__ __align__(16) float zf[8][256];            // fp32 master z
    __shared__ float ch[64];

    const int tid = threadIdx.x;
    const int lane = tid & 63;
    const int w = tid >> 6;   // 8 waves
    const int q = lane >> 4;
    const int l = lane & 15;
    const int b = blockIdx.x;

    // ---- one-time weight residency ----
    f8x8 w1r[8][8];
    #pragma unroll
    for (int ntl = 0; ntl < 8; ++ntl)
        #pragma unroll
        for (int ks = 0; ks < 8; ++ks)
            w1r[ntl][ks] = *(const f8x8*)(W1z_f8 +
                ((((size_t)(w * 8 + ntl) * 8 + ks) * 64 + lane) << 3));
    f8x8 w2r[32];
    #pragma unroll
    for (int ks = 0; ks < 32; ++ks)
        w2r[ks] = *(const f8x8*)(W2_f8 +
            ((((size_t)(w * 2) * 32 + ks) * 64 + lane) << 3));
    #pragma unroll
    for (int ks = 0; ks < 32; ++ks)
        W2L[w * 32 + ks][lane] = *(const long*)(W2_f8 +
            ((((size_t)(w * 2 + 1) * 32 + ks) * 64 + lane) << 3));

    // ---- prologue: z0 = tanh(MLP(cov)) ----
    if (tid < 64) {
        float s = cb1[tid];
        for (int c = 0; c < 16; ++c) s += cov[b * 16 + c] * cw1[c * 64 + tid];
        ch[tid] = fmaxf(s, 0.f);
    }
    __syncthreads();
    if (tid < ZZ) {
        float v = cb2[tid];
        for (int j = 0; j < 64; ++j) v += ch[j] * cw2[j * ZZ + tid];
        v = fast_tanh(v);
        unsigned short hv = f2bf(v);
        unsigned char zb = f2fp8(v);
        for (int s = 0; s < SS; ++s) {
            zf[s][tid] = v;
            Az8[s][tid] = zb;
            zhist[((size_t)b * SS + s) * ZZ + tid] = hv;   // slot 0
        }
    }

    const int colA = (w << 5) + l;       // z col for G2 tile A
    const int colB = colA + 16;          // tile B
    float b2dA = b2d[colA], b2dB = b2d[colB];
    float kacc = 0.f;                    // kld accumulator (q<2 lanes)

    // per-step scalars, prefetched one step ahead (live across barriers:
    // bar_lds() does not drain vmcnt). hpr: lower lanes = posterior proj,
    // upper lanes = prior proj (each lane only feeds its own output rows).
    float epsA[4], epsB[4], difA = 0.f, difB = 0.f;
    unsigned short hpr[8];
#define LOAD_SCALARS(TI)                                                        \
    do {                                                                        \
        const size_t tb_ = (size_t)(TI) * BB + b;                               \
        const unsigned short* ps_ = (q < 2) ? HpprojQ : HprojQ;                 \
        _Pragma("unroll")                                                       \
        for (int ntl = 0; ntl < 8; ++ntl)                                       \
            hpr[ntl] = ps_[tb_ * HH + (size_t)(w * 8 + ntl) * 16 + l];          \
        if (q < 2) {                                                            \
            _Pragma("unroll")                                                   \
            for (int i = 0; i < 4; ++i) {                                       \
                epsA[i] = noise[((tb_ << 3) + (q << 2) + i) * ZZ + colA];       \
                epsB[i] = noise[((tb_ << 3) + (q << 2) + i) * ZZ + colB];       \
            }                                                                   \
            difA = DiffQ[tb_ * ZZ + colA];                                      \
            difB = DiffQ[tb_ * ZZ + colB];                                      \
        }                                                                       \
    } while (0)

    LOAD_SCALARS(0);
    __syncthreads();   // z0/weights visible (one-time full drain is fine)

    for (int t = 0; t < T_STEPS; ++t) {
        // ---- G1: hidden[16][1024] = relu(proj + z @ W1z); rows 8-15 reuse
        //      the duplicate-z MFMA rows for the PRIOR path (free).
        #pragma unroll
        for (int h = 0; h < 2; ++h) {
            f32x4 acc[4];
            {
                f32x4 z4 = {0.f, 0.f, 0.f, 0.f};
                #pragma unroll
                for (int j = 0; j < 4; ++j) acc[j] = z4;
            }
            #pragma unroll
            for (int ks = 0; ks < 8; ++ks) {
                f8x8 a1 = *(const f8x8*)&Az8[l & 7][(ks << 5) + (q << 3)];
                #pragma unroll
                for (int j = 0; j < 4; ++j)
                    acc[j] = MFMA8(a1, w1r[h * 4 + j][ks], acc[j], 0, 0, 0);
            }
            #pragma unroll
            for (int j = 0; j < 4; ++j) {
                int ntl = h * 4 + j;
                int n = (w * 8 + ntl) * 16 + l;
                float hp = bf2f(hpr[ntl]);
                #pragma unroll
                for (int i = 0; i < 4; ++i)
                    Ah8[(q << 2) + i][n] = f2fp8(fmaxf(hp + acc[j][i], 0.f));
            }
        }
        bar_lds();

        // ---- G2: drift[16][256] = hidden @ W2 (rows 0-7 post, 8-15 prior)
        f32x4 aA[2], aB[2];
        {
            f32x4 z4 = {0.f, 0.f, 0.f, 0.f};
            aA[0] = z4; aA[1] = z4; aB[0] = z4; aB[1] = z4;
        }
        #pragma unroll
        for (int ks = 0; ks < 32; ++ks) {
            f8x8 a2 = *(const f8x8*)&Ah8[l][(ks << 5) + (q << 3)];
            f8x8 bB = (f8x8)W2L[w * 32 + ks][lane];
            aA[ks & 1] = MFMA8(a2, w2r[ks], aA[ks & 1], 0, 0, 0);
            aB[ks & 1] = MFMA8(a2, bB, aB[ks & 1], 0, 0, 0);
        }
        #pragma unroll
        for (int i = 0; i < 4; ++i) {
            float preA = aA[0][i] + aA[1][i] + b2dA;
            float preB = aB[0][i] + aB[1][i] + b2dB;
            float opA = __shfl_xor(preA, 32, 64);   // prior pre for lower half
            float opB = __shfl_xor(preB, 32, 64);
            if (q < 2) {
                int s = (q << 2) + i;
                float poA = 0.1f * fast_tanh(preA);
                float poB = 0.1f * fast_tanh(preB);
                float prA = 0.1f * fast_tanh(opA);
                float prB = 0.1f * fast_tanh(opB);
                float eA = (prA - poA) / difA;
                float eB = (prB - poB) / difB;
                kacc += eA * eA + eB * eB;
                zf[s][colA] += DT * poA + SQRT_DT * difA * epsA[i];
                zf[s][colB] += DT * poB + SQRT_DT * difB * epsB[i];
            }
        }
        // prefetch next step's scalars (loads stay in flight across raw barriers)
        if (t + 1 < T_STEPS) LOAD_SCALARS(t + 1);
        bar_lds();

        // ---- normalize: wave w owns z-row w; lane owns cols 4*lane..4*lane+3
        {
            float4 vv = *(const float4*)&zf[w][lane << 2];
            float mn = fminf(fminf(vv.x, vv.y), fminf(vv.z, vv.w));
            float mx = fmaxf(fmaxf(vv.x, vv.y), fmaxf(vv.z, vv.w));
            for (int off = 32; off; off >>= 1) {
                mn = fminf(mn, __shfl_xor(mn, off, 64));
                mx = fmaxf(mx, __shfl_xor(mx, off, 64));
            }
            float sc = 1.0f / (mx - mn);
            vv.x = (vv.x - mn) * sc; vv.y = (vv.y - mn) * sc;
            vv.z = (vv.z - mn) * sc; vv.w = (vv.w - mn) * sc;
            *(float4*)&zf[w][lane << 2] = vv;
            *(unsigned int*)&Az8[w][lane << 2] = f2fp8x4(vv.x, vv.y, vv.z, vv.w);
            ushort4 hv4;
            hv4.x = f2bf(vv.x); hv4.y = f2bf(vv.y);
            hv4.z = f2bf(vv.z); hv4.w = f2bf(vv.w);
            size_t zo = ((size_t)(t + 1) * BB + b) * (SS * ZZ) + (size_t)w * ZZ;
            *reinterpret_cast<ushort4*>(zhist + zo + (lane << 2)) = hv4;
        }
        bar_lds();   // Az8/zf ready for next step's G1
    }
    __syncthreads();

    for (int idx = tid; idx < SS * ZZ; idx += 512) {
        int s = idx >> 8, n = idx & 255;
        out[((size_t)b * SS + s) * ZZ + n] = zf[s][n];
    }

    // ---- kld reduction: wave -> block -> one atomic per block ----
    for (int off = 32; off; off >>= 1) kacc += __shfl_down(kacc, off, 64);
    if (lane == 0) ch[w] = kacc;
    __syncthreads();
    if (tid == 0) {
        float K = 0.f;
        for (int i = 0; i < 8; ++i) K += ch[i];
        float kc = K * (0.5f * DT / (SS * BB));
        atomicAdd(loss + 0, kc);
        atomicAdd(loss + 2, kc);
    }
#undef LOAD_SCALARS
}

// ---------------------------------------------------------------------------
// Parallel post-pass: decoder on z_{t+1} -> recon. (bf16, unchanged)
// ---------------------------------------------------------------------------
__global__ __launch_bounds__(512, 4)
void post_dec(const unsigned short* __restrict__ zhist,
              const unsigned short* __restrict__ PprojQ,
              const float* __restrict__ X, const float* __restrict__ MtQ,
              const float* __restrict__ b2p,
              const unsigned short* __restrict__ PW1z_p,
              const unsigned short* __restrict__ PW2_p,
              float* __restrict__ loss) {
    __shared__ unsigned short Az[4][16][ZZ + 8];
    __shared__ unsigned short Hp[4][16][136];
    __shared__ unsigned short ProjS[8][128];
    __shared__ float b2p_s[DD];
    __shared__ float red[8];
    const int tid = threadIdx.x;
    const int lane = tid & 63;
    const int w = tid >> 6;
    const int q = lane >> 4;
    const int l = lane & 15;
    const int rt = w & 3;
    const int half = w >> 2;
    const int p0 = blockIdx.x << 3;

    for (int idx = tid; idx < 4096; idx += 512) {
        int r = idx >> 6, c4 = (idx & 63) << 2;
        *(ushort4*)&Az[r >> 4][r & 15][c4] =
            *(const ushort4*)&zhist[((size_t)(p0 + BB) * SS + r) * ZZ + c4];  // slot t+1
    }
    if (tid < DD) b2p_s[tid] = b2p[tid];

    f32x4 pacc[4];
    {
        f32x4 z4 = {0.f, 0.f, 0.f, 0.f};
        #pragma unroll
        for (int j = 0; j < 4; ++j) pacc[j] = z4;
    }

    for (int nc = 0; nc < 8; ++nc) {
        if (tid < 256) {
            int pair = tid >> 5, c4 = (tid & 31) << 2;
            *(ushort4*)&ProjS[pair][c4] =
                *(const ushort4*)&PprojQ[(size_t)(p0 + pair) * HH + nc * 128 + c4];
        }
        __syncthreads();

        f32x4 za[4];
        {
            f32x4 z4 = {0.f, 0.f, 0.f, 0.f};
            #pragma unroll
            for (int j = 0; j < 4; ++j) za[j] = z4;
        }
        {
            const unsigned short* wb = PW1z_p + lane * 8;
            bf16x8 wq[4];
            #pragma unroll
            for (int f = 0; f < 4; ++f) {
                int ks = f >> 2, j = f & 3;
                wq[f] = *(const bf16x8*)(wb +
                    ((size_t)((nc * 8 + half * 4 + j) * 8 + ks)) * 512);
            }
            #pragma unroll
            for (int f = 0; f < 32; ++f) {
                int ks = f >> 2, j = f & 3;
                bf16x8 a = *(const bf16x8*)&Az[rt][l][(ks << 5) + (q << 3)];
                za[j] = MFMA(a, wq[f & 3], za[j], 0, 0, 0);
                if (f < 28) {
                    int f2 = f + 4, ks2 = f2 >> 2, j2 = f2 & 3;
                    wq[f & 3] = *(const bf16x8*)(wb +
                        ((size_t)((nc * 8 + half * 4 + j2) * 8 + ks2)) * 512);
                }
            }
        }
        #pragma unroll
        for (int j = 0; j < 4; ++j) {
            int c = (half * 4 + j) * 16 + l;
            #pragma unroll
            for (int i = 0; i < 4; ++i) {
                int r = (q << 2) + i;
                int pair = ((rt << 4) + r) >> 3;
                Hp[rt][r][c] = f2bf(fmaxf(bf2f(ProjS[pair][c]) + za[j][i], 0.f));
            }
        }
        __syncthreads();

        {
            const unsigned short* wb2 = PW2_p + lane * 8;
            bf16x8 wq2[4];
            #pragma unroll
            for (int f = 0; f < 4; ++f) {
                int kk = f >> 2, j = f & 3;
                wq2[f] = *(const bf16x8*)(wb2 +
                    ((size_t)((half * 4 + j) * 32 + nc * 4 + kk)) * 512);
            }
            #pragma unroll
            for (int f = 0; f < 16; ++f) {
                int kk = f >> 2, j = f & 3;
                bf16x8 a = *(const bf16x8*)&Hp[rt][l][(kk << 5) + (q << 3)];
                pacc[j] = MFMA(a, wq2[f & 3], pacc[j], 0, 0, 0);
                if (f < 12) {
                    int f2 = f + 4, kk2 = f2 >> 2, j2 = f2 & 3;
                    wq2[f & 3] = *(const bf16x8*)(wb2 +
                        ((size_t)((half * 4 + j2) * 32 + nc * 4 + kk2)) * 512);
                }
            }
        }
        __syncthreads();
    }

    float rl = 0.f;
    #pragma unroll
    for (int j = 0; j < 4; ++j) {
        int n = ((half << 2) + j) * 16 + l;
        float bias = b2p_s[n];
        #pragma unroll
        for (int i = 0; i < 4; ++i) {
            int r = (rt << 4) + (q << 2) + i;
            int pair = p0 + (r >> 3);
            float p = pacc[j][i] + bias;
            float d = X[(size_t)pair * DD + n] - p;
            rl += (0.5f * (LOG2PIF + d * d)) * MtQ[pair];
        }
    }
    rl *= 1.0f / (SS * BB);
    for (int off = 32; off; off >>= 1) rl += __shfl_down(rl, off, 64);
    if (lane == 0) red[w] = rl;
    __syncthreads();
    if (tid == 0) {
        float R = 0.f;
        for (int i = 0; i < 8; ++i) R += red[i];
        atomicAdd(loss + 0, R);
        atomicAdd(loss + 1, R);
    }
}

extern "C" void kernel_launch(void* const* d_in, const int* in_sizes, int n_in,
                              void* d_out, int out_size, void* d_ws, size_t ws_size,
                              hipStream_t stream) {
    (void)in_sizes; (void)n_in; (void)ws_size;
    const float* X         = (const float*)d_in[0];
    const float* M         = (const float*)d_in[1];
    const float* cov       = (const float*)d_in[2];
    const float* path_h    = (const float*)d_in[3];
    const float* path_hpos = (const float*)d_in[4];
    const float* noise     = (const float*)d_in[5];
    const float* drift_w1  = (const float*)d_in[6];
    const float* drift_b1  = (const float*)d_in[7];
    const float* drift_w2  = (const float*)d_in[8];
    const float* drift_b2  = (const float*)d_in[9];
    const float* diff_w1   = (const float*)d_in[10];
    const float* diff_b1   = (const float*)d_in[11];
    const float* diff_w2   = (const float*)d_in[12];
    const float* diff_b2   = (const float*)d_in[13];
    const float* p_w1      = (const float*)d_in[14];
    const float* p_b1      = (const float*)d_in[15];
    const float* p_w2      = (const float*)d_in[16];
    const float* p_b2      = (const float*)d_in[17];
    const float* cov_w1    = (const float*)d_in[18];
    const float* cov_b1    = (const float*)d_in[19];
    const float* cov_w2    = (const float*)d_in[20];
    const float* cov_b2    = (const float*)d_in[21];

    char* ws = (char*)d_ws;
    size_t off = 0;
    auto alloc = [&](size_t bytes) {
        void* p = ws + off;
        off = (off + bytes + 255) & ~(size_t)255;
        return p;
    };
    unsigned short* HprojQ  = (unsigned short*)alloc((size_t)T_STEPS * BB * HH * 2);
    unsigned short* HpprojQ = (unsigned short*)alloc((size_t)T_STEPS * BB * HH * 2);
    unsigned short* PprojQ  = (unsigned short*)alloc((size_t)T_STEPS * BB * HH * 2);
    float*          DiffQ   = (float*)alloc((size_t)T_STEPS * BB * ZZ * 4);
    float*          MtQ     = (float*)alloc((size_t)T_STEPS * BB * 4);
    unsigned short* zhist   = (unsigned short*)alloc((size_t)(T_STEPS + 1) * BB * SS * ZZ * 2);
    unsigned short* PW1z_p  = (unsigned short*)alloc((size_t)ZZ * HH * 2);
    unsigned short* PW2_p   = (unsigned short*)alloc((size_t)HH * DD * 2);
    unsigned short* W1h_p   = (unsigned short*)alloc((size_t)RR * HH * 2);
    unsigned short* PW1h_p  = (unsigned short*)alloc((size_t)RR * HH * 2);
    unsigned short* DW1_p   = (unsigned short*)alloc((size_t)RR * HH * 2);
    unsigned short* DW2_p   = (unsigned short*)alloc((size_t)HH * ZZ * 2);
    unsigned char*  W1z_f8  = (unsigned char*)alloc((size_t)ZZ * HH);
    unsigned char*  W2_f8   = (unsigned char*)alloc((size_t)HH * ZZ);

    hipMemsetAsync(d_out, 0, (size_t)out_size * sizeof(float), stream);

    auto packLaunch = [&](const float* src, int K, int N, unsigned short* dst) {
        int total = (K / 32) * (N / 16) * 64;
        pack_w<<<(total + 255) / 256, 256, 0, stream>>>(src, K, N, dst);
    };
    auto packLaunch8 = [&](const float* src, int K, int N, unsigned char* dst) {
        int total = (K / 32) * (N / 16) * 64;
        pack_w_fp8<<<(total + 255) / 256, 256, 0, stream>>>(src, K, N, dst);
    };
    packLaunch(p_w1 + (size_t)RR * HH,     ZZ, HH, PW1z_p);
    packLaunch(p_w2,                       HH, DD, PW2_p);
    packLaunch(drift_w1, RR, HH, W1h_p);
    packLaunch(p_w1,     RR, HH, PW1h_p);
    packLaunch(diff_w1,  RR, HH, DW1_p);
    packLaunch(diff_w2,  HH, ZZ, DW2_p);
    packLaunch8(drift_w1 + (size_t)RR * HH, ZZ, HH, W1z_f8);
    packLaunch8(drift_w2,                   HH, ZZ, W2_f8);

    mt_kernel<<<(T_STEPS * BB * 64) / 256, 256, 0, stream>>>(M, MtQ);

    precompute_kernel<<<(T_STEPS * BB) / 16, 256, 0, stream>>>(
        path_h, path_hpos, drift_b1, p_b1, diff_b1, diff_b2,
        W1h_p, PW1h_p, DW1_p, DW2_p, HprojQ, HpprojQ, PprojQ, DiffQ);

    float* outp = (float*)d_out;
    float* loss = outp + (size_t)BB * SS * ZZ;

    scan_kernel<<<BB, 512, 0, stream>>>(
        cov, noise, drift_b2, cov_w1, cov_b1, cov_w2, cov_b2,
        W1z_f8, W2_f8, HpprojQ, HprojQ, DiffQ, zhist, outp, loss);

    post_dec<<<(T_STEPS * BB) / 8, 512, 0, stream>>>(
        zhist, PprojQ, X, MtQ, p_b2, PW1z_p, PW2_p, loss);
}

// Round 9
// 1557.064 us; speedup vs baseline: 2.8813x; 1.1143x over previous
//
#include <hip/hip_runtime.h>
#include <cstddef>
#include <cstdint>

#define T_STEPS 200
#define BB 64
#define SS 8
#define DD 128
#define RR 512
#define ZZ 256
#define HH 1024
#define DT 0.05f
#define SQRT_DT 0.22360679774997896f
#define LOG2PIF 1.8378770664093453f

typedef __attribute__((ext_vector_type(8))) short bf16x8;
typedef __attribute__((ext_vector_type(8))) unsigned short u16x8;
typedef __attribute__((ext_vector_type(4))) float f32x4;
typedef long f8x8;   // 8 fp8-e4m3 values (2 VGPRs)
#define MFMA __builtin_amdgcn_mfma_f32_16x16x32_bf16
#define MFMA8 __builtin_amdgcn_mfma_f32_16x16x32_fp8_fp8

static __device__ __forceinline__ unsigned short f2bf(float x) {
    unsigned int u = __builtin_bit_cast(unsigned int, x);
    u += 0x7fffu + ((u >> 16) & 1u);
    return (unsigned short)(u >> 16);
}
static __device__ __forceinline__ float bf2f(unsigned short h) {
    unsigned int u = ((unsigned int)h) << 16;
    return __builtin_bit_cast(float, u);
}
static __device__ __forceinline__ float fast_tanh(float x) {
    float e = __expf(2.0f * x);
    return 1.0f - 2.0f / (e + 1.0f);
}
// f32 -> fp8 e4m3 via HW converter (consistent with gfx950 fp8 MFMA decode).
static __device__ __forceinline__ unsigned char f2fp8(float x) {
    unsigned int r = 0;
    asm volatile("v_cvt_pk_fp8_f32 %0, %1, %1" : "+v"(r) : "v"(x));
    return (unsigned char)(r & 0xffu);
}
// Pack 4 f32 -> 4 fp8 bytes (same HW conversion as f2fp8, 2 insts).
static __device__ __forceinline__ unsigned int f2fp8x4(float a, float b,
                                                      float c, float d) {
    unsigned int p01 = 0, p23 = 0;
    asm volatile("v_cvt_pk_fp8_f32 %0, %1, %2" : "+v"(p01) : "v"(a), "v"(b));
    asm volatile("v_cvt_pk_fp8_f32 %0, %1, %2" : "+v"(p23) : "v"(c), "v"(d));
    return (p01 & 0xffffu) | (p23 << 16);
}

// LDS-ordering barrier WITHOUT the vmcnt(0) drain __syncthreads would emit:
// producer ds_writes complete (lgkmcnt), all waves meet, no load-queue flush.
// sched_barrier(0) stops post-barrier LDS reads from hoisting above it.
static __device__ __forceinline__ void bar_lds() {
    asm volatile("s_waitcnt lgkmcnt(0)" ::: "memory");
    __builtin_amdgcn_s_barrier();
    __builtin_amdgcn_sched_barrier(0);
}

// ---------------------------------------------------------------------------
// Pack row-major fp32 W[K][N] into bf16 MFMA B-fragment order:
// frag p = nt*(K/32)*64 + ks*64 + lane holds 8 elems: n = nt*16 + (lane&15),
// k = ks*32 + (lane>>4)*8 + i.
// ---------------------------------------------------------------------------
__global__ void pack_w(const float* __restrict__ src, int K, int N,
                       unsigned short* __restrict__ dst) {
    int total = (K >> 5) * (N >> 4) * 64;
    int p = blockIdx.x * blockDim.x + threadIdx.x;
    if (p >= total) return;
    int lane = p & 63;
    int ksteps = K >> 5;
    int ks = (p >> 6) % ksteps;
    int nt = p / (ksteps << 6);
    int n = (nt << 4) + (lane & 15);
    int k0 = (ks << 5) + ((lane >> 4) << 3);
    uint4 u4;
    unsigned short* tmp = reinterpret_cast<unsigned short*>(&u4);
    for (int i = 0; i < 8; ++i) tmp[i] = f2bf(src[(size_t)(k0 + i) * N + n]);
    *reinterpret_cast<uint4*>(dst + (size_t)p * 8) = u4;
}

// Same fragment order, fp8-e4m3 payload (8 B per lane-frag).
__global__ void pack_w_fp8(const float* __restrict__ src, int K, int N,
                           unsigned char* __restrict__ dst) {
    int total = (K >> 5) * (N >> 4) * 64;
    int p = blockIdx.x * blockDim.x + threadIdx.x;
    if (p >= total) return;
    int lane = p & 63;
    int ksteps = K >> 5;
    int ks = (p >> 6) % ksteps;
    int nt = p / (ksteps << 6);
    int n = (nt << 4) + (lane & 15);
    int k0 = (ks << 5) + ((lane >> 4) << 3);
    unsigned long long acc = 0ull;
    for (int i = 0; i < 8; ++i)
        acc |= (unsigned long long)f2fp8(src[(size_t)(k0 + i) * N + n]) << (8 * i);
    *reinterpret_cast<unsigned long long*>(dst + (size_t)p * 8) = acc;
}

// Mt[t,b] = mean over D of M[t,b,:]
__global__ void mt_kernel(const float* __restrict__ M, float* __restrict__ Mt) {
    int wv = (blockIdx.x * blockDim.x + threadIdx.x) >> 6;
    int lane = threadIdx.x & 63;
    if (wv >= T_STEPS * BB) return;
    const float* row = M + (size_t)wv * DD;
    float s = row[lane] + row[lane + 64];
    for (int off = 32; off; off >>= 1) s += __shfl_down(s, off, 64);
    if (lane == 0) Mt[wv] = s * (1.0f / DD);
}

// ---------------------------------------------------------------------------
// Precompute h-only projections (parallel over T*B, 16 rows/block).
// HprojQ/HpprojQ are written in SCAN-layout (their only consumer):
// perm(n) = (n&~127) | ((n&15)<<3) | ((n>>4)&7)  ->  scan reads ushort8/lane.
// PprojQ stays in linear layout (post_dec consumes it).
// ---------------------------------------------------------------------------
#define PC_GEMM_1024(Asrc, Bp, biasArr, EMIT)                                    \
    {                                                                            \
        f32x4 acc[16];                                                           \
        f32x4 z4 = {0.f, 0.f, 0.f, 0.f};                                        \
        for (int ntl = 0; ntl < 16; ++ntl) acc[ntl] = z4;                        \
        for (int ks = 0; ks < 16; ++ks) {                                        \
            bf16x8 a = *(const bf16x8*)&Asrc[l][(ks << 5) + (q << 3)];           \
            for (int ntl = 0; ntl < 16; ++ntl) {                                 \
                int ntg = (w << 4) + ntl;                                        \
                bf16x8 bb = *(const bf16x8*)(Bp +                                \
                             (((size_t)ntg * 16 + ks) * 64 + lane) * 8);         \
                acc[ntl] = MFMA(a, bb, acc[ntl], 0, 0, 0);                       \
            }                                                                    \
        }                                                                        \
        for (int ntl = 0; ntl < 16; ++ntl) {                                     \
            int n = (((w << 4) + ntl) << 4) + l;                                 \
            float bv = biasArr[n];                                               \
            for (int i = 0; i < 4; ++i) {                                        \
                int rr = (q << 2) + i;                                           \
                float v = acc[ntl][i] + bv;                                      \
                EMIT;                                                            \
            }                                                                    \
        }                                                                        \
    }

#define SCAN_PERM(n) (((n) & ~127) | (((n) & 15) << 3) | (((n) >> 4) & 7))

__global__ __launch_bounds__(256)
void precompute_kernel(const float* __restrict__ h, const float* __restrict__ hpos,
                       const float* __restrict__ b1d, const float* __restrict__ b1p,
                       const float* __restrict__ b1f, const float* __restrict__ b2f,
                       const unsigned short* __restrict__ W1h_p,
                       const unsigned short* __restrict__ PW1h_p,
                       const unsigned short* __restrict__ DW1_p,
                       const unsigned short* __restrict__ DW2_p,
                       unsigned short* __restrict__ HprojQ,
                       unsigned short* __restrict__ HpprojQ,
                       unsigned short* __restrict__ PprojQ,
                       float* __restrict__ DiffQ) {
    __shared__ unsigned short Ahh[16][RR + 8];
    __shared__ unsigned short Ahp[16][RR + 8];
    __shared__ unsigned short Adh[16][HH + 8];
    const int tid = threadIdx.x;
    const int lane = tid & 63;
    const int w = tid >> 6;
    const int q = lane >> 4;
    const int l = lane & 15;
    const int r0 = blockIdx.x << 4;

    for (int idx = tid; idx < (RR << 4); idx += 256) {
        int r = idx >> 9, c = idx & (RR - 1);
        Ahh[r][c] = f2bf(h[(size_t)(r0 + r) * RR + c]);
        Ahp[r][c] = f2bf(hpos[(size_t)(r0 + r) * RR + c]);
    }
    __syncthreads();

    PC_GEMM_1024(Ahh, W1h_p,  b1d,
                 (HprojQ [(size_t)(r0 + rr) * HH + SCAN_PERM(n)] = f2bf(v)));
    PC_GEMM_1024(Ahp, W1h_p,  b1d,
                 (HpprojQ[(size_t)(r0 + rr) * HH + SCAN_PERM(n)] = f2bf(v)));
    PC_GEMM_1024(Ahh, PW1h_p, b1p, (PprojQ [(size_t)(r0 + rr) * HH + n] = f2bf(v)));
    PC_GEMM_1024(Ahh, DW1_p,  b1f, (Adh[rr][n] = f2bf(fmaxf(v, 0.f))));
    __syncthreads();

    {
        f32x4 acc[4];
        f32x4 z4 = {0.f, 0.f, 0.f, 0.f};
        for (int ntl = 0; ntl < 4; ++ntl) acc[ntl] = z4;
        for (int ks = 0; ks < 32; ++ks) {
            bf16x8 a = *(const bf16x8*)&Adh[l][(ks << 5) + (q << 3)];
            for (int ntl = 0; ntl < 4; ++ntl) {
                int ntg = (w << 2) + ntl;
                bf16x8 bb = *(const bf16x8*)(DW2_p +
                             (((size_t)ntg * 32 + ks) * 64 + lane) * 8);
                acc[ntl] = MFMA(a, bb, acc[ntl], 0, 0, 0);
            }
        }
        for (int ntl = 0; ntl < 4; ++ntl) {
            int n = (((w << 2) + ntl) << 4) + l;
            float bv = b2f[n];
            for (int i = 0; i < 4; ++i) {
                int rr = (q << 2) + i;
                DiffQ[(size_t)(r0 + rr) * ZZ + n] = __expf(acc[ntl][i] + bv);
            }
        }
    }
}

// ---------------------------------------------------------------------------
// Sequential scan, WEIGHT-RESIDENT fp8, PRIOR PATH FUSED. 64 blocks x 512 thr.
// Round-8 deltas (all bit-exact vs round 7):
//  - tanh computed on ALL lanes before the shfl (each lane owns its own pre);
//    shfl exchanges the tanh RESULT. Halves tanh issue slots (16 -> 8/thread).
//  - Hproj/Hpproj read as one aligned ushort8/lane (scan-layout repack in
//    precompute) instead of 8 scattered ushort loads.
//  - Az8 A-fragments hoisted: 8 ds_read_b64 once, reused across both h-halves.
// ---------------------------------------------------------------------------
__global__ __launch_bounds__(512, 2)
void scan_kernel(const float* __restrict__ cov, const float* __restrict__ noise,
                 const float* __restrict__ b2d,
                 const float* __restrict__ cw1, const float* __restrict__ cb1,
                 const float* __restrict__ cw2, const float* __restrict__ cb2,
                 const unsigned char* __restrict__ W1z_f8,
                 const unsigned char* __restrict__ W2_f8,
                 const unsigned short* __restrict__ HpprojQ,
                 const unsigned short* __restrict__ HprojQ,
                 const float* __restrict__ DiffQ,
                 unsigned short* __restrict__ zhist,
                 float* __restrict__ out,
                 float* __restrict__ loss) {
    __shared__ __align__(16) long W2L[256][64];           // 128 KiB: W2 tile-B frags
    __shared__ __align__(8) unsigned char Az8[8][272];    // z fp8 (8 rows)
    __shared__ __align__(8) unsigned char Ah8[16][1032];  // hidden fp8 (post|prior)
    __shared__ __align__(16) float zf[8][256];            // fp32 master z
    __shared__ float ch[64];

    const int tid = threadIdx.x;
    const int lane = tid & 63;
    const int w = tid >> 6;   // 8 waves
    const int q = lane >> 4;
    const int l = lane & 15;
    const int b = blockIdx.x;

    // ---- one-time weight residency ----
    f8x8 w1r[8][8];
    #pragma unroll
    for (int ntl = 0; ntl < 8; ++ntl)
        #pragma unroll
        for (int ks = 0; ks < 8; ++ks)
            w1r[ntl][ks] = *(const f8x8*)(W1z_f8 +
                ((((size_t)(w * 8 + ntl) * 8 + ks) * 64 + lane) << 3));
    f8x8 w2r[32];
    #pragma unroll
    for (int ks = 0; ks < 32; ++ks)
        w2r[ks] = *(const f8x8*)(W2_f8 +
            ((((size_t)(w * 2) * 32 + ks) * 64 + lane) << 3));
    #pragma unroll
    for (int ks = 0; ks < 32; ++ks)
        W2L[w * 32 + ks][lane] = *(const long*)(W2_f8 +
            ((((size_t)(w * 2 + 1) * 32 + ks) * 64 + lane) << 3));

    // ---- prologue: z0 = tanh(MLP(cov)) ----
    if (tid < 64) {
        float s = cb1[tid];
        for (int c = 0; c < 16; ++c) s += cov[b * 16 + c] * cw1[c * 64 + tid];
        ch[tid] = fmaxf(s, 0.f);
    }
    __syncthreads();
    if (tid < ZZ) {
        float v = cb2[tid];
        for (int j = 0; j < 64; ++j) v += ch[j] * cw2[j * ZZ + tid];
        v = fast_tanh(v);
        unsigned short hv = f2bf(v);
        unsigned char zb = f2fp8(v);
        for (int s = 0; s < SS; ++s) {
            zf[s][tid] = v;
            Az8[s][tid] = zb;
            zhist[((size_t)b * SS + s) * ZZ + tid] = hv;   // slot 0
        }
    }

    const int colA = (w << 5) + l;       // z col for G2 tile A
    const int colB = colA + 16;          // tile B
    float b2dA = b2d[colA], b2dB = b2d[colB];
    float kacc = 0.f;                    // kld accumulator (q<2 lanes)

    // per-step scalars, prefetched one step ahead (live across barriers:
    // bar_lds() does not drain vmcnt). hpr: lower lanes = posterior proj,
    // upper lanes = prior proj (each lane only feeds its own output rows).
    float epsA[4], epsB[4], difA = 0.f, difB = 0.f;
    u16x8 hpr;
#define LOAD_SCALARS(TI)                                                        \
    do {                                                                        \
        const size_t tb_ = (size_t)(TI) * BB + b;                               \
        const unsigned short* ps_ = (q < 2) ? HpprojQ : HprojQ;                 \
        hpr = *(const u16x8*)&ps_[tb_ * HH + (w << 7) + (l << 3)];              \
        if (q < 2) {                                                            \
            _Pragma("unroll")                                                   \
            for (int i = 0; i < 4; ++i) {                                       \
                epsA[i] = noise[((tb_ << 3) + (q << 2) + i) * ZZ + colA];       \
                epsB[i] = noise[((tb_ << 3) + (q << 2) + i) * ZZ + colB];       \
            }                                                                   \
            difA = DiffQ[tb_ * ZZ + colA];                                      \
            difB = DiffQ[tb_ * ZZ + colB];                                      \
        }                                                                       \
    } while (0)

    LOAD_SCALARS(0);
    __syncthreads();   // z0/weights visible (one-time full drain is fine)

    for (int t = 0; t < T_STEPS; ++t) {
        // ---- G1: hidden[16][1024] = relu(proj + z @ W1z); rows 8-15 reuse
        //      the duplicate-z MFMA rows for the PRIOR path (free).
        f8x8 a1f[8];
        #pragma unroll
        for (int ks = 0; ks < 8; ++ks)
            a1f[ks] = *(const f8x8*)&Az8[l & 7][(ks << 5) + (q << 3)];
        #pragma unroll
        for (int h = 0; h < 2; ++h) {
            f32x4 acc[4];
            {
                f32x4 z4 = {0.f, 0.f, 0.f, 0.f};
                #pragma unroll
                for (int j = 0; j < 4; ++j) acc[j] = z4;
            }
            #pragma unroll
            for (int ks = 0; ks < 8; ++ks) {
                #pragma unroll
                for (int j = 0; j < 4; ++j)
                    acc[j] = MFMA8(a1f[ks], w1r[h * 4 + j][ks], acc[j], 0, 0, 0);
            }
            #pragma unroll
            for (int j = 0; j < 4; ++j) {
                int ntl = h * 4 + j;
                int n = (w * 8 + ntl) * 16 + l;
                float hp = bf2f(hpr[ntl]);
                #pragma unroll
                for (int i = 0; i < 4; ++i)
                    Ah8[(q << 2) + i][n] = f2fp8(fmaxf(hp + acc[j][i], 0.f));
            }
        }
        bar_lds();

        // ---- G2: drift[16][256] = hidden @ W2 (rows 0-7 post, 8-15 prior)
        f32x4 aA[2], aB[2];
        {
            f32x4 z4 = {0.f, 0.f, 0.f, 0.f};
            aA[0] = z4; aA[1] = z4; aB[0] = z4; aB[1] = z4;
        }
        #pragma unroll
        for (int ks = 0; ks < 32; ++ks) {
            f8x8 a2 = *(const f8x8*)&Ah8[l][(ks << 5) + (q << 3)];
            f8x8 bB = (f8x8)W2L[w * 32 + ks][lane];
            aA[ks & 1] = MFMA8(a2, w2r[ks], aA[ks & 1], 0, 0, 0);
            aB[ks & 1] = MFMA8(a2, bB, aB[ks & 1], 0, 0, 0);
        }
        #pragma unroll
        for (int i = 0; i < 4; ++i) {
            // tanh on ALL lanes (each lane's own pre), then exchange results.
            float poA = 0.1f * fast_tanh(aA[0][i] + aA[1][i] + b2dA);
            float poB = 0.1f * fast_tanh(aB[0][i] + aB[1][i] + b2dB);
            float prA = __shfl_xor(poA, 32, 64);   // partner's drift
            float prB = __shfl_xor(poB, 32, 64);
            if (q < 2) {
                int s = (q << 2) + i;
                float eA = (prA - poA) / difA;
                float eB = (prB - poB) / difB;
                kacc += eA * eA + eB * eB;
                zf[s][colA] += DT * poA + SQRT_DT * difA * epsA[i];
                zf[s][colB] += DT * poB + SQRT_DT * difB * epsB[i];
            }
        }
        // prefetch next step's scalars (loads stay in flight across raw barriers)
        if (t + 1 < T_STEPS) LOAD_SCALARS(t + 1);
        bar_lds();

        // ---- normalize: wave w owns z-row w; lane owns cols 4*lane..4*lane+3
        {
            float4 vv = *(const float4*)&zf[w][lane << 2];
            float mn = fminf(fminf(vv.x, vv.y), fminf(vv.z, vv.w));
            float mx = fmaxf(fmaxf(vv.x, vv.y), fmaxf(vv.z, vv.w));
            for (int off = 32; off; off >>= 1) {
                mn = fminf(mn, __shfl_xor(mn, off, 64));
                mx = fmaxf(mx, __shfl_xor(mx, off, 64));
            }
            float sc = 1.0f / (mx - mn);
            vv.x = (vv.x - mn) * sc; vv.y = (vv.y - mn) * sc;
            vv.z = (vv.z - mn) * sc; vv.w = (vv.w - mn) * sc;
            *(float4*)&zf[w][lane << 2] = vv;
            *(unsigned int*)&Az8[w][lane << 2] = f2fp8x4(vv.x, vv.y, vv.z, vv.w);
            ushort4 hv4;
            hv4.x = f2bf(vv.x); hv4.y = f2bf(vv.y);
            hv4.z = f2bf(vv.z); hv4.w = f2bf(vv.w);
            size_t zo = ((size_t)(t + 1) * BB + b) * (SS * ZZ) + (size_t)w * ZZ;
            *reinterpret_cast<ushort4*>(zhist + zo + (lane << 2)) = hv4;
        }
        bar_lds();   // Az8/zf ready for next step's G1
    }
    __syncthreads();

    for (int idx = tid; idx < SS * ZZ; idx += 512) {
        int s = idx >> 8, n = idx & 255;
        out[((size_t)b * SS + s) * ZZ + n] = zf[s][n];
    }

    // ---- kld reduction: wave -> block -> one atomic per block ----
    for (int off = 32; off; off >>= 1) kacc += __shfl_down(kacc, off, 64);
    if (lane == 0) ch[w] = kacc;
    __syncthreads();
    if (tid == 0) {
        float K = 0.f;
        for (int i = 0; i < 8; ++i) K += ch[i];
        float kc = K * (0.5f * DT / (SS * BB));
        atomicAdd(loss + 0, kc);
        atomicAdd(loss + 2, kc);
    }
#undef LOAD_SCALARS
}

// ---------------------------------------------------------------------------
// Parallel post-pass: decoder on z_{t+1} -> recon. (bf16, unchanged)
// ---------------------------------------------------------------------------
__global__ __launch_bounds__(512, 4)
void post_dec(const unsigned short* __restrict__ zhist,
              const unsigned short* __restrict__ PprojQ,
              const float* __restrict__ X, const float* __restrict__ MtQ,
              const float* __restrict__ b2p,
              const unsigned short* __restrict__ PW1z_p,
              const unsigned short* __restrict__ PW2_p,
              float* __restrict__ loss) {
    __shared__ unsigned short Az[4][16][ZZ + 8];
    __shared__ unsigned short Hp[4][16][136];
    __shared__ unsigned short ProjS[8][128];
    __shared__ float b2p_s[DD];
    __shared__ float red[8];
    const int tid = threadIdx.x;
    const int lane = tid & 63;
    const int w = tid >> 6;
    const int q = lane >> 4;
    const int l = lane & 15;
    const int rt = w & 3;
    const int half = w >> 2;
    const int p0 = blockIdx.x << 3;

    for (int idx = tid; idx < 4096; idx += 512) {
        int r = idx >> 6, c4 = (idx & 63) << 2;
        *(ushort4*)&Az[r >> 4][r & 15][c4] =
            *(const ushort4*)&zhist[((size_t)(p0 + BB) * SS + r) * ZZ + c4];  // slot t+1
    }
    if (tid < DD) b2p_s[tid] = b2p[tid];

    f32x4 pacc[4];
    {
        f32x4 z4 = {0.f, 0.f, 0.f, 0.f};
        #pragma unroll
        for (int j = 0; j < 4; ++j) pacc[j] = z4;
    }

    for (int nc = 0; nc < 8; ++nc) {
        if (tid < 256) {
            int pair = tid >> 5, c4 = (tid & 31) << 2;
            *(ushort4*)&ProjS[pair][c4] =
                *(const ushort4*)&PprojQ[(size_t)(p0 + pair) * HH + nc * 128 + c4];
        }
        __syncthreads();

        f32x4 za[4];
        {
            f32x4 z4 = {0.f, 0.f, 0.f, 0.f};
            #pragma unroll
            for (int j = 0; j < 4; ++j) za[j] = z4;
        }
        {
            const unsigned short* wb = PW1z_p + lane * 8;
            bf16x8 wq[4];
            #pragma unroll
            for (int f = 0; f < 4; ++f) {
                int ks = f >> 2, j = f & 3;
                wq[f] = *(const bf16x8*)(wb +
                    ((size_t)((nc * 8 + half * 4 + j) * 8 + ks)) * 512);
            }
            #pragma unroll
            for (int f = 0; f < 32; ++f) {
                int ks = f >> 2, j = f & 3;
                bf16x8 a = *(const bf16x8*)&Az[rt][l][(ks << 5) + (q << 3)];
                za[j] = MFMA(a, wq[f & 3], za[j], 0, 0, 0);
                if (f < 28) {
                    int f2 = f + 4, ks2 = f2 >> 2, j2 = f2 & 3;
                    wq[f & 3] = *(const bf16x8*)(wb +
                        ((size_t)((nc * 8 + half * 4 + j2) * 8 + ks2)) * 512);
                }
            }
        }
        #pragma unroll
        for (int j = 0; j < 4; ++j) {
            int c = (half * 4 + j) * 16 + l;
            #pragma unroll
            for (int i = 0; i < 4; ++i) {
                int r = (q << 2) + i;
                int pair = ((rt << 4) + r) >> 3;
                Hp[rt][r][c] = f2bf(fmaxf(bf2f(ProjS[pair][c]) + za[j][i], 0.f));
            }
        }
        __syncthreads();

        {
            const unsigned short* wb2 = PW2_p + lane * 8;
            bf16x8 wq2[4];
            #pragma unroll
            for (int f = 0; f < 4; ++f) {
                int kk = f >> 2, j = f & 3;
                wq2[f] = *(const bf16x8*)(wb2 +
                    ((size_t)((half * 4 + j) * 32 + nc * 4 + kk)) * 512);
            }
            #pragma unroll
            for (int f = 0; f < 16; ++f) {
                int kk = f >> 2, j = f & 3;
                bf16x8 a = *(const bf16x8*)&Hp[rt][l][(kk << 5) + (q << 3)];
                pacc[j] = MFMA(a, wq2[f & 3], pacc[j], 0, 0, 0);
                if (f < 12) {
                    int f2 = f + 4, kk2 = f2 >> 2, j2 = f2 & 3;
                    wq2[f & 3] = *(const bf16x8*)(wb2 +
                        ((size_t)((half * 4 + j2) * 32 + nc * 4 + kk2)) * 512);
                }
            }
        }
        __syncthreads();
    }

    float rl = 0.f;
    #pragma unroll
    for (int j = 0; j < 4; ++j) {
        int n = ((half << 2) + j) * 16 + l;
        float bias = b2p_s[n];
        #pragma unroll
        for (int i = 0; i < 4; ++i) {
            int r = (rt << 4) + (q << 2) + i;
            int pair = p0 + (r >> 3);
            float p = pacc[j][i] + bias;
            float d = X[(size_t)pair * DD + n] - p;
            rl += (0.5f * (LOG2PIF + d * d)) * MtQ[pair];
        }
    }
    rl *= 1.0f / (SS * BB);
    for (int off = 32; off; off >>= 1) rl += __shfl_down(rl, off, 64);
    if (lane == 0) red[w] = rl;
    __syncthreads();
    if (tid == 0) {
        float R = 0.f;
        for (int i = 0; i < 8; ++i) R += red[i];
        atomicAdd(loss + 0, R);
        atomicAdd(loss + 1, R);
    }
}

extern "C" void kernel_launch(void* const* d_in, const int* in_sizes, int n_in,
                              void* d_out, int out_size, void* d_ws, size_t ws_size,
                              hipStream_t stream) {
    (void)in_sizes; (void)n_in; (void)ws_size;
    const float* X         = (const float*)d_in[0];
    const float* M         = (const float*)d_in[1];
    const float* cov       = (const float*)d_in[2];
    const float* path_h    = (const float*)d_in[3];
    const float* path_hpos = (const float*)d_in[4];
    const float* noise     = (const float*)d_in[5];
    const float* drift_w1  = (const float*)d_in[6];
    const float* drift_b1  = (const float*)d_in[7];
    const float* drift_w2  = (const float*)d_in[8];
    const float* drift_b2  = (const float*)d_in[9];
    const float* diff_w1   = (const float*)d_in[10];
    const float* diff_b1   = (const float*)d_in[11];
    const float* diff_w2   = (const float*)d_in[12];
    const float* diff_b2   = (const float*)d_in[13];
    const float* p_w1      = (const float*)d_in[14];
    const float* p_b1      = (const float*)d_in[15];
    const float* p_w2      = (const float*)d_in[16];
    const float* p_b2      = (const float*)d_in[17];
    const float* cov_w1    = (const float*)d_in[18];
    const float* cov_b1    = (const float*)d_in[19];
    const float* cov_w2    = (const float*)d_in[20];
    const float* cov_b2    = (const float*)d_in[21];

    char* ws = (char*)d_ws;
    size_t off = 0;
    auto alloc = [&](size_t bytes) {
        void* p = ws + off;
        off = (off + bytes + 255) & ~(size_t)255;
        return p;
    };
    unsigned short* HprojQ  = (unsigned short*)alloc((size_t)T_STEPS * BB * HH * 2);
    unsigned short* HpprojQ = (unsigned short*)alloc((size_t)T_STEPS * BB * HH * 2);
    unsigned short* PprojQ  = (unsigned short*)alloc((size_t)T_STEPS * BB * HH * 2);
    float*          DiffQ   = (float*)alloc((size_t)T_STEPS * BB * ZZ * 4);
    float*          MtQ     = (float*)alloc((size_t)T_STEPS * BB * 4);
    unsigned short* zhist   = (unsigned short*)alloc((size_t)(T_STEPS + 1) * BB * SS * ZZ * 2);
    unsigned short* PW1z_p  = (unsigned short*)alloc((size_t)ZZ * HH * 2);
    unsigned short* PW2_p   = (unsigned short*)alloc((size_t)HH * DD * 2);
    unsigned short* W1h_p   = (unsigned short*)alloc((size_t)RR * HH * 2);
    unsigned short* PW1h_p  = (unsigned short*)alloc((size_t)RR * HH * 2);
    unsigned short* DW1_p   = (unsigned short*)alloc((size_t)RR * HH * 2);
    unsigned short* DW2_p   = (unsigned short*)alloc((size_t)HH * ZZ * 2);
    unsigned char*  W1z_f8  = (unsigned char*)alloc((size_t)ZZ * HH);
    unsigned char*  W2_f8   = (unsigned char*)alloc((size_t)HH * ZZ);

    hipMemsetAsync(d_out, 0, (size_t)out_size * sizeof(float), stream);

    auto packLaunch = [&](const float* src, int K, int N, unsigned short* dst) {
        int total = (K / 32) * (N / 16) * 64;
        pack_w<<<(total + 255) / 256, 256, 0, stream>>>(src, K, N, dst);
    };
    auto packLaunch8 = [&](const float* src, int K, int N, unsigned char* dst) {
        int total = (K / 32) * (N / 16) * 64;
        pack_w_fp8<<<(total + 255) / 256, 256, 0, stream>>>(src, K, N, dst);
    };
    packLaunch(p_w1 + (size_t)RR * HH,     ZZ, HH, PW1z_p);
    packLaunch(p_w2,                       HH, DD, PW2_p);
    packLaunch(drift_w1, RR, HH, W1h_p);
    packLaunch(p_w1,     RR, HH, PW1h_p);
    packLaunch(diff_w1,  RR, HH, DW1_p);
    packLaunch(diff_w2,  HH, ZZ, DW2_p);
    packLaunch8(drift_w1 + (size_t)RR * HH, ZZ, HH, W1z_f8);
    packLaunch8(drift_w2,                   HH, ZZ, W2_f8);

    mt_kernel<<<(T_STEPS * BB * 64) / 256, 256, 0, stream>>>(M, MtQ);

    precompute_kernel<<<(T_STEPS * BB) / 16, 256, 0, stream>>>(
        path_h, path_hpos, drift_b1, p_b1, diff_b1, diff_b2,
        W1h_p, PW1h_p, DW1_p, DW2_p, HprojQ, HpprojQ, PprojQ, DiffQ);

    float* outp = (float*)d_out;
    float* loss = outp + (size_t)BB * SS * ZZ;

    scan_kernel<<<BB, 512, 0, stream>>>(
        cov, noise, drift_b2, cov_w1, cov_b1, cov_w2, cov_b2,
        W1z_f8, W2_f8, HpprojQ, HprojQ, DiffQ, zhist, outp, loss);

    post_dec<<<(T_STEPS * BB) / 8, 512, 0, stream>>>(
        zhist, PprojQ, X, MtQ, p_b2, PW1z_p, PW2_p, loss);
}

// Round 10
// 1553.690 us; speedup vs baseline: 2.8876x; 1.0022x over previous
//
#include <hip/hip_runtime.h>
#include <cstddef>
#include <cstdint>

#define T_STEPS 200
#define BB 64
#define SS 8
#define DD 128
#define RR 512
#define ZZ 256
#define HH 1024
#define DT 0.05f
#define SQRT_DT 0.22360679774997896f
#define LOG2PIF 1.8378770664093453f

typedef __attribute__((ext_vector_type(8))) short bf16x8;
typedef __attribute__((ext_vector_type(8))) unsigned short u16x8;
typedef __attribute__((ext_vector_type(4))) float f32x4;
typedef long f8x8;   // 8 fp8-e4m3 values (2 VGPRs)
#define MFMA __builtin_amdgcn_mfma_f32_16x16x32_bf16
#define MFMA8 __builtin_amdgcn_mfma_f32_16x16x32_fp8_fp8

static __device__ __forceinline__ unsigned short f2bf(float x) {
    unsigned int u = __builtin_bit_cast(unsigned int, x);
    u += 0x7fffu + ((u >> 16) & 1u);
    return (unsigned short)(u >> 16);
}
static __device__ __forceinline__ float bf2f(unsigned short h) {
    unsigned int u = ((unsigned int)h) << 16;
    return __builtin_bit_cast(float, u);
}
static __device__ __forceinline__ float fast_tanh(float x) {
    float e = __expf(2.0f * x);
    return 1.0f - 2.0f / (e + 1.0f);
}
// f32 -> fp8 e4m3 via HW converter (consistent with gfx950 fp8 MFMA decode).
static __device__ __forceinline__ unsigned char f2fp8(float x) {
    unsigned int r = 0;
    asm volatile("v_cvt_pk_fp8_f32 %0, %1, %1" : "+v"(r) : "v"(x));
    return (unsigned char)(r & 0xffu);
}
// Pack 4 f32 -> 4 fp8 bytes (same HW conversion as f2fp8, 2 insts).
static __device__ __forceinline__ unsigned int f2fp8x4(float a, float b,
                                                      float c, float d) {
    unsigned int p01 = 0, p23 = 0;
    asm volatile("v_cvt_pk_fp8_f32 %0, %1, %2" : "+v"(p01) : "v"(a), "v"(b));
    asm volatile("v_cvt_pk_fp8_f32 %0, %1, %2" : "+v"(p23) : "v"(c), "v"(d));
    return (p01 & 0xffffu) | (p23 << 16);
}

// LDS-ordering barrier WITHOUT the vmcnt(0) drain __syncthreads would emit:
// producer ds_writes complete (lgkmcnt), all waves meet, no load-queue flush.
// sched_barrier(0) stops post-barrier LDS reads from hoisting above it.
static __device__ __forceinline__ void bar_lds() {
    asm volatile("s_waitcnt lgkmcnt(0)" ::: "memory");
    __builtin_amdgcn_s_barrier();
    __builtin_amdgcn_sched_barrier(0);
}

// ---------------------------------------------------------------------------
// Pack row-major fp32 W[K][N] into bf16 MFMA B-fragment order:
// frag p = nt*(K/32)*64 + ks*64 + lane holds 8 elems: n = nt*16 + (lane&15),
// k = ks*32 + (lane>>4)*8 + i.
// ---------------------------------------------------------------------------
__global__ void pack_w(const float* __restrict__ src, int K, int N,
                       unsigned short* __restrict__ dst) {
    int total = (K >> 5) * (N >> 4) * 64;
    int p = blockIdx.x * blockDim.x + threadIdx.x;
    if (p >= total) return;
    int lane = p & 63;
    int ksteps = K >> 5;
    int ks = (p >> 6) % ksteps;
    int nt = p / (ksteps << 6);
    int n = (nt << 4) + (lane & 15);
    int k0 = (ks << 5) + ((lane >> 4) << 3);
    uint4 u4;
    unsigned short* tmp = reinterpret_cast<unsigned short*>(&u4);
    for (int i = 0; i < 8; ++i) tmp[i] = f2bf(src[(size_t)(k0 + i) * N + n]);
    *reinterpret_cast<uint4*>(dst + (size_t)p * 8) = u4;
}

// Same fragment order, fp8-e4m3 payload (8 B per lane-frag).
__global__ void pack_w_fp8(const float* __restrict__ src, int K, int N,
                           unsigned char* __restrict__ dst) {
    int total = (K >> 5) * (N >> 4) * 64;
    int p = blockIdx.x * blockDim.x + threadIdx.x;
    if (p >= total) return;
    int lane = p & 63;
    int ksteps = K >> 5;
    int ks = (p >> 6) % ksteps;
    int nt = p / (ksteps << 6);
    int n = (nt << 4) + (lane & 15);
    int k0 = (ks << 5) + ((lane >> 4) << 3);
    unsigned long long acc = 0ull;
    for (int i = 0; i < 8; ++i)
        acc |= (unsigned long long)f2fp8(src[(size_t)(k0 + i) * N + n]) << (8 * i);
    *reinterpret_cast<unsigned long long*>(dst + (size_t)p * 8) = acc;
}

// Mt[t,b] = mean over D of M[t,b,:]
__global__ void mt_kernel(const float* __restrict__ M, float* __restrict__ Mt) {
    int wv = (blockIdx.x * blockDim.x + threadIdx.x) >> 6;
    int lane = threadIdx.x & 63;
    if (wv >= T_STEPS * BB) return;
    const float* row = M + (size_t)wv * DD;
    float s = row[lane] + row[lane + 64];
    for (int off = 32; off; off >>= 1) s += __shfl_down(s, off, 64);
    if (lane == 0) Mt[wv] = s * (1.0f / DD);
}

// ---------------------------------------------------------------------------
// Precompute h-only projections (parallel over T*B, 16 rows/block).
// HprojQ/HpprojQ are written in SCAN-layout (their only consumer):
// perm(n) = (n&~127) | ((n&15)<<3) | ((n>>4)&7)  ->  scan reads ushort8/lane.
// PprojQ stays in linear layout (decoder consumes it).
// ---------------------------------------------------------------------------
#define PC_GEMM_1024(Asrc, Bp, biasArr, EMIT)                                    \
    {                                                                            \
        f32x4 acc[16];                                                           \
        f32x4 z4 = {0.f, 0.f, 0.f, 0.f};                                        \
        for (int ntl = 0; ntl < 16; ++ntl) acc[ntl] = z4;                        \
        for (int ks = 0; ks < 16; ++ks) {                                        \
            bf16x8 a = *(const bf16x8*)&Asrc[l][(ks << 5) + (q << 3)];           \
            for (int ntl = 0; ntl < 16; ++ntl) {                                 \
                int ntg = (w << 4) + ntl;                                        \
                bf16x8 bb = *(const bf16x8*)(Bp +                                \
                             (((size_t)ntg * 16 + ks) * 64 + lane) * 8);         \
                acc[ntl] = MFMA(a, bb, acc[ntl], 0, 0, 0);                       \
            }                                                                    \
        }                                                                        \
        for (int ntl = 0; ntl < 16; ++ntl) {                                     \
            int n = (((w << 4) + ntl) << 4) + l;                                 \
            float bv = biasArr[n];                                               \
            for (int i = 0; i < 4; ++i) {                                        \
                int rr = (q << 2) + i;                                           \
                float v = acc[ntl][i] + bv;                                      \
                EMIT;                                                            \
            }                                                                    \
        }                                                                        \
    }

#define SCAN_PERM(n) (((n) & ~127) | (((n) & 15) << 3) | (((n) >> 4) & 7))

__global__ __launch_bounds__(256)
void precompute_kernel(const float* __restrict__ h, const float* __restrict__ hpos,
                       const float* __restrict__ b1d, const float* __restrict__ b1p,
                       const float* __restrict__ b1f, const float* __restrict__ b2f,
                       const unsigned short* __restrict__ W1h_p,
                       const unsigned short* __restrict__ PW1h_p,
                       const unsigned short* __restrict__ DW1_p,
                       const unsigned short* __restrict__ DW2_p,
                       unsigned short* __restrict__ HprojQ,
                       unsigned short* __restrict__ HpprojQ,
                       unsigned short* __restrict__ PprojQ,
                       float* __restrict__ DiffQ) {
    __shared__ unsigned short Ahh[16][RR + 8];
    __shared__ unsigned short Ahp[16][RR + 8];
    __shared__ unsigned short Adh[16][HH + 8];
    const int tid = threadIdx.x;
    const int lane = tid & 63;
    const int w = tid >> 6;
    const int q = lane >> 4;
    const int l = lane & 15;
    const int r0 = blockIdx.x << 4;

    for (int idx = tid; idx < (RR << 4); idx += 256) {
        int r = idx >> 9, c = idx & (RR - 1);
        Ahh[r][c] = f2bf(h[(size_t)(r0 + r) * RR + c]);
        Ahp[r][c] = f2bf(hpos[(size_t)(r0 + r) * RR + c]);
    }
    __syncthreads();

    PC_GEMM_1024(Ahh, W1h_p,  b1d,
                 (HprojQ [(size_t)(r0 + rr) * HH + SCAN_PERM(n)] = f2bf(v)));
    PC_GEMM_1024(Ahp, W1h_p,  b1d,
                 (HpprojQ[(size_t)(r0 + rr) * HH + SCAN_PERM(n)] = f2bf(v)));
    PC_GEMM_1024(Ahh, PW1h_p, b1p, (PprojQ [(size_t)(r0 + rr) * HH + n] = f2bf(v)));
    PC_GEMM_1024(Ahh, DW1_p,  b1f, (Adh[rr][n] = f2bf(fmaxf(v, 0.f))));
    __syncthreads();

    {
        f32x4 acc[4];
        f32x4 z4 = {0.f, 0.f, 0.f, 0.f};
        for (int ntl = 0; ntl < 4; ++ntl) acc[ntl] = z4;
        for (int ks = 0; ks < 32; ++ks) {
            bf16x8 a = *(const bf16x8*)&Adh[l][(ks << 5) + (q << 3)];
            for (int ntl = 0; ntl < 4; ++ntl) {
                int ntg = (w << 2) + ntl;
                bf16x8 bb = *(const bf16x8*)(DW2_p +
                             (((size_t)ntg * 32 + ks) * 64 + lane) * 8);
                acc[ntl] = MFMA(a, bb, acc[ntl], 0, 0, 0);
            }
        }
        for (int ntl = 0; ntl < 4; ++ntl) {
            int n = (((w << 2) + ntl) << 4) + l;
            float bv = b2f[n];
            for (int i = 0; i < 4; ++i) {
                int rr = (q << 2) + i;
                DiffQ[(size_t)(r0 + rr) * ZZ + n] = __expf(acc[ntl][i] + bv);
            }
        }
    }
}

// ---------------------------------------------------------------------------
// MEGA-KERNEL: 256 blocks x 512 thr, 1 block/CU (158 KB LDS union).
//  blocks 0-63   : scan (round-9 structure, UNCHANGED math) — producers.
//    Every 32 steps + at the end: __syncthreads (drain vmem) + threadfence +
//    release-store progress[b] = completed steps. 7 fences total per block
//    (round 3 showed per-STEP fencing costs ~7us/step; 7 coarse fences ~=
//    20-30us total).
//  blocks 64-255 : decoder (old post_dec) chunks — consumers. Each handles
//    chunks c = cons, cons+192, ... of 8 (t,b) pairs; relax-polls progress
//    for the 8 producer blocks it needs, then one acquire fence, then the
//    unchanged decoder math. Producers NEVER wait on consumers -> no
//    deadlock; worst case consumers run late (serial fallback).
// ---------------------------------------------------------------------------
__global__ __launch_bounds__(512, 2)
void mega_kernel(const float* __restrict__ cov, const float* __restrict__ noise,
                 const float* __restrict__ b2d,
                 const float* __restrict__ cw1, const float* __restrict__ cb1,
                 const float* __restrict__ cw2, const float* __restrict__ cb2,
                 const unsigned char* __restrict__ W1z_f8,
                 const unsigned char* __restrict__ W2_f8,
                 const unsigned short* __restrict__ HpprojQ,
                 const unsigned short* __restrict__ HprojQ,
                 const float* __restrict__ DiffQ,
                 unsigned short* __restrict__ zhist,
                 float* __restrict__ out,
                 float* __restrict__ loss,
                 const unsigned short* __restrict__ PprojQ,
                 const float* __restrict__ X, const float* __restrict__ MtQ,
                 const float* __restrict__ b2p,
                 const unsigned short* __restrict__ PW1z_p,
                 const unsigned short* __restrict__ PW2_p,
                 unsigned int* __restrict__ progress) {
    __shared__ __align__(16) char smem[158208];

    const int tid = threadIdx.x;
    const int lane = tid & 63;
    const int w = tid >> 6;   // 8 waves
    const int q = lane >> 4;
    const int l = lane & 15;

    if (blockIdx.x < BB) {
        // =================== PRODUCER: scan (round-9 verbatim) ===============
        long (*W2L)[64]            = reinterpret_cast<long(*)[64]>(smem);
        unsigned char (*Az8)[272]  = reinterpret_cast<unsigned char(*)[272]>(smem + 131072);
        unsigned char (*Ah8)[1032] = reinterpret_cast<unsigned char(*)[1032]>(smem + 133248);
        float (*zf)[256]           = reinterpret_cast<float(*)[256]>(smem + 149760);
        float* ch                  = reinterpret_cast<float*>(smem + 157952);
        const int b = blockIdx.x;

        // ---- one-time weight residency ----
        f8x8 w1r[8][8];
        #pragma unroll
        for (int ntl = 0; ntl < 8; ++ntl)
            #pragma unroll
            for (int ks = 0; ks < 8; ++ks)
                w1r[ntl][ks] = *(const f8x8*)(W1z_f8 +
                    ((((size_t)(w * 8 + ntl) * 8 + ks) * 64 + lane) << 3));
        f8x8 w2r[32];
        #pragma unroll
        for (int ks = 0; ks < 32; ++ks)
            w2r[ks] = *(const f8x8*)(W2_f8 +
                ((((size_t)(w * 2) * 32 + ks) * 64 + lane) << 3));
        #pragma unroll
        for (int ks = 0; ks < 32; ++ks)
            W2L[w * 32 + ks][lane] = *(const long*)(W2_f8 +
                ((((size_t)(w * 2 + 1) * 32 + ks) * 64 + lane) << 3));

        // ---- prologue: z0 = tanh(MLP(cov)) ----
        if (tid < 64) {
            float s = cb1[tid];
            for (int c = 0; c < 16; ++c) s += cov[b * 16 + c] * cw1[c * 64 + tid];
            ch[tid] = fmaxf(s, 0.f);
        }
        __syncthreads();
        if (tid < ZZ) {
            float v = cb2[tid];
            for (int j = 0; j < 64; ++j) v += ch[j] * cw2[j * ZZ + tid];
            v = fast_tanh(v);
            unsigned short hv = f2bf(v);
            unsigned char zb = f2fp8(v);
            for (int s = 0; s < SS; ++s) {
                zf[s][tid] = v;
                Az8[s][tid] = zb;
                zhist[((size_t)b * SS + s) * ZZ + tid] = hv;   // slot 0
            }
        }

        const int colA = (w << 5) + l;
        const int colB = colA + 16;
        float b2dA = b2d[colA], b2dB = b2d[colB];
        float kacc = 0.f;

        float epsA[4], epsB[4], difA = 0.f, difB = 0.f;
        u16x8 hpr;
#define LOAD_SCALARS(TI)                                                        \
    do {                                                                        \
        const size_t tb_ = (size_t)(TI) * BB + b;                               \
        const unsigned short* ps_ = (q < 2) ? HpprojQ : HprojQ;                 \
        hpr = *(const u16x8*)&ps_[tb_ * HH + (w << 7) + (l << 3)];              \
        if (q < 2) {                                                            \
            _Pragma("unroll")                                                   \
            for (int i = 0; i < 4; ++i) {                                       \
                epsA[i] = noise[((tb_ << 3) + (q << 2) + i) * ZZ + colA];       \
                epsB[i] = noise[((tb_ << 3) + (q << 2) + i) * ZZ + colB];       \
            }                                                                   \
            difA = DiffQ[tb_ * ZZ + colA];                                      \
            difB = DiffQ[tb_ * ZZ + colB];                                      \
        }                                                                       \
    } while (0)

        LOAD_SCALARS(0);
        __syncthreads();

        for (int t = 0; t < T_STEPS; ++t) {
            f8x8 a1f[8];
            #pragma unroll
            for (int ks = 0; ks < 8; ++ks)
                a1f[ks] = *(const f8x8*)&Az8[l & 7][(ks << 5) + (q << 3)];
            #pragma unroll
            for (int h = 0; h < 2; ++h) {
                f32x4 acc[4];
                {
                    f32x4 z4 = {0.f, 0.f, 0.f, 0.f};
                    #pragma unroll
                    for (int j = 0; j < 4; ++j) acc[j] = z4;
                }
                #pragma unroll
                for (int ks = 0; ks < 8; ++ks) {
                    #pragma unroll
                    for (int j = 0; j < 4; ++j)
                        acc[j] = MFMA8(a1f[ks], w1r[h * 4 + j][ks], acc[j], 0, 0, 0);
                }
                #pragma unroll
                for (int j = 0; j < 4; ++j) {
                    int ntl = h * 4 + j;
                    int n = (w * 8 + ntl) * 16 + l;
                    float hp = bf2f(hpr[ntl]);
                    #pragma unroll
                    for (int i = 0; i < 4; ++i)
                        Ah8[(q << 2) + i][n] = f2fp8(fmaxf(hp + acc[j][i], 0.f));
                }
            }
            bar_lds();

            f32x4 aA[2], aB[2];
            {
                f32x4 z4 = {0.f, 0.f, 0.f, 0.f};
                aA[0] = z4; aA[1] = z4; aB[0] = z4; aB[1] = z4;
            }
            #pragma unroll
            for (int ks = 0; ks < 32; ++ks) {
                f8x8 a2 = *(const f8x8*)&Ah8[l][(ks << 5) + (q << 3)];
                f8x8 bB = (f8x8)W2L[w * 32 + ks][lane];
                aA[ks & 1] = MFMA8(a2, w2r[ks], aA[ks & 1], 0, 0, 0);
                aB[ks & 1] = MFMA8(a2, bB, aB[ks & 1], 0, 0, 0);
            }
            #pragma unroll
            for (int i = 0; i < 4; ++i) {
                float poA = 0.1f * fast_tanh(aA[0][i] + aA[1][i] + b2dA);
                float poB = 0.1f * fast_tanh(aB[0][i] + aB[1][i] + b2dB);
                float prA = __shfl_xor(poA, 32, 64);
                float prB = __shfl_xor(poB, 32, 64);
                if (q < 2) {
                    int s = (q << 2) + i;
                    float eA = (prA - poA) / difA;
                    float eB = (prB - poB) / difB;
                    kacc += eA * eA + eB * eB;
                    zf[s][colA] += DT * poA + SQRT_DT * difA * epsA[i];
                    zf[s][colB] += DT * poB + SQRT_DT * difB * epsB[i];
                }
            }
            if (t + 1 < T_STEPS) LOAD_SCALARS(t + 1);
            bar_lds();

            {
                float4 vv = *(const float4*)&zf[w][lane << 2];
                float mn = fminf(fminf(vv.x, vv.y), fminf(vv.z, vv.w));
                float mx = fmaxf(fmaxf(vv.x, vv.y), fmaxf(vv.z, vv.w));
                for (int off = 32; off; off >>= 1) {
                    mn = fminf(mn, __shfl_xor(mn, off, 64));
                    mx = fmaxf(mx, __shfl_xor(mx, off, 64));
                }
                float sc = 1.0f / (mx - mn);
                vv.x = (vv.x - mn) * sc; vv.y = (vv.y - mn) * sc;
                vv.z = (vv.z - mn) * sc; vv.w = (vv.w - mn) * sc;
                *(float4*)&zf[w][lane << 2] = vv;
                *(unsigned int*)&Az8[w][lane << 2] = f2fp8x4(vv.x, vv.y, vv.z, vv.w);
                ushort4 hv4;
                hv4.x = f2bf(vv.x); hv4.y = f2bf(vv.y);
                hv4.z = f2bf(vv.z); hv4.w = f2bf(vv.w);
                size_t zo = ((size_t)(t + 1) * BB + b) * (SS * ZZ) + (size_t)w * ZZ;
                *reinterpret_cast<ushort4*>(zhist + zo + (lane << 2)) = hv4;
            }
            bar_lds();

            // ---- coarse release: zhist slots <= t+1 visible device-wide ----
            if (((t + 1) & 31) == 0) {
                __syncthreads();   // drains all waves' vmem stores
                if (tid == 0) {
                    __threadfence();
                    __hip_atomic_store(&progress[b], (unsigned)(t + 1),
                                       __ATOMIC_RELEASE, __HIP_MEMORY_SCOPE_AGENT);
                }
            }
        }
        __syncthreads();
        if (tid == 0) {
            __threadfence();
            __hip_atomic_store(&progress[b], (unsigned)T_STEPS,
                               __ATOMIC_RELEASE, __HIP_MEMORY_SCOPE_AGENT);
        }

        for (int idx = tid; idx < SS * ZZ; idx += 512) {
            int s = idx >> 8, n = idx & 255;
            out[((size_t)b * SS + s) * ZZ + n] = zf[s][n];
        }

        for (int off = 32; off; off >>= 1) kacc += __shfl_down(kacc, off, 64);
        if (lane == 0) ch[w] = kacc;
        __syncthreads();
        if (tid == 0) {
            float K = 0.f;
            for (int i = 0; i < 8; ++i) K += ch[i];
            float kc = K * (0.5f * DT / (SS * BB));
            atomicAdd(loss + 0, kc);
            atomicAdd(loss + 2, kc);
        }
#undef LOAD_SCALARS
    } else {
        // =================== CONSUMER: decoder chunks =======================
        unsigned short (*AzD)[16][264] = reinterpret_cast<unsigned short(*)[16][264]>(smem);
        unsigned short (*HpD)[16][136] = reinterpret_cast<unsigned short(*)[16][136]>(smem + 33792);
        unsigned short (*ProjS)[128]   = reinterpret_cast<unsigned short(*)[128]>(smem + 51200);
        float* b2p_s                   = reinterpret_cast<float*>(smem + 53248);
        float* red                     = reinterpret_cast<float*>(smem + 53760);
        const int rt = w & 3;
        const int half = w >> 2;
        const int cons = blockIdx.x - BB;   // 0..191

        if (tid < DD) b2p_s[tid] = b2p[tid];

        for (int c = cons; c < (T_STEPS * BB) / 8; c += 192) {
            const int p0 = c << 3;
            const unsigned tneed = (unsigned)((p0 >> 6) + 1);
            const int bbase = p0 & 63;
            // wait for the 8 producer blocks this chunk reads from
            if (tid == 0) {
                for (int j = 0; j < 8; ++j) {
                    while (__hip_atomic_load(&progress[bbase + j], __ATOMIC_RELAXED,
                                             __HIP_MEMORY_SCOPE_AGENT) < tneed)
                        __builtin_amdgcn_s_sleep(4);
                }
                __threadfence();   // acquire: invalidate stale cache lines
            }
            __syncthreads();       // also covers b2p_s on first chunk

            for (int idx = tid; idx < 4096; idx += 512) {
                int r = idx >> 6, c4 = (idx & 63) << 2;
                *(ushort4*)&AzD[r >> 4][r & 15][c4] =
                    *(const ushort4*)&zhist[((size_t)(p0 + BB) * SS + r) * ZZ + c4];
            }

            f32x4 pacc[4];
            {
                f32x4 z4 = {0.f, 0.f, 0.f, 0.f};
                #pragma unroll
                for (int j = 0; j < 4; ++j) pacc[j] = z4;
            }

            for (int nc = 0; nc < 8; ++nc) {
                if (tid < 256) {
                    int pair = tid >> 5, c4 = (tid & 31) << 2;
                    *(ushort4*)&ProjS[pair][c4] =
                        *(const ushort4*)&PprojQ[(size_t)(p0 + pair) * HH + nc * 128 + c4];
                }
                __syncthreads();

                f32x4 za[4];
                {
                    f32x4 z4 = {0.f, 0.f, 0.f, 0.f};
                    #pragma unroll
                    for (int j = 0; j < 4; ++j) za[j] = z4;
                }
                {
                    const unsigned short* wb = PW1z_p + lane * 8;
                    bf16x8 wq[4];
                    #pragma unroll
                    for (int f = 0; f < 4; ++f) {
                        int ks = f >> 2, j = f & 3;
                        wq[f] = *(const bf16x8*)(wb +
                            ((size_t)((nc * 8 + half * 4 + j) * 8 + ks)) * 512);
                    }
                    #pragma unroll
                    for (int f = 0; f < 32; ++f) {
                        int ks = f >> 2, j = f & 3;
                        bf16x8 a = *(const bf16x8*)&AzD[rt][l][(ks << 5) + (q << 3)];
                        za[j] = MFMA(a, wq[f & 3], za[j], 0, 0, 0);
                        if (f < 28) {
                            int f2 = f + 4, ks2 = f2 >> 2, j2 = f2 & 3;
                            wq[f & 3] = *(const bf16x8*)(wb +
                                ((size_t)((nc * 8 + half * 4 + j2) * 8 + ks2)) * 512);
                        }
                    }
                }
                #pragma unroll
                for (int j = 0; j < 4; ++j) {
                    int cc = (half * 4 + j) * 16 + l;
                    #pragma unroll
                    for (int i = 0; i < 4; ++i) {
                        int r = (q << 2) + i;
                        int pair = ((rt << 4) + r) >> 3;
                        HpD[rt][r][cc] =
                            f2bf(fmaxf(bf2f(ProjS[pair][cc]) + za[j][i], 0.f));
                    }
                }
                __syncthreads();

                {
                    const unsigned short* wb2 = PW2_p + lane * 8;
                    bf16x8 wq2[4];
                    #pragma unroll
                    for (int f = 0; f < 4; ++f) {
                        int kk = f >> 2, j = f & 3;
                        wq2[f] = *(const bf16x8*)(wb2 +
                            ((size_t)((half * 4 + j) * 32 + nc * 4 + kk)) * 512);
                    }
                    #pragma unroll
                    for (int f = 0; f < 16; ++f) {
                        int kk = f >> 2, j = f & 3;
                        bf16x8 a = *(const bf16x8*)&HpD[rt][l][(kk << 5) + (q << 3)];
                        pacc[j] = MFMA(a, wq2[f & 3], pacc[j], 0, 0, 0);
                        if (f < 12) {
                            int f2 = f + 4, kk2 = f2 >> 2, j2 = f2 & 3;
                            wq2[f & 3] = *(const bf16x8*)(wb2 +
                                ((size_t)((half * 4 + j2) * 32 + nc * 4 + kk2)) * 512);
                        }
                    }
                }
                __syncthreads();
            }

            float rl = 0.f;
            #pragma unroll
            for (int j = 0; j < 4; ++j) {
                int n = ((half << 2) + j) * 16 + l;
                float bias = b2p_s[n];
                #pragma unroll
                for (int i = 0; i < 4; ++i) {
                    int r = (rt << 4) + (q << 2) + i;
                    int pair = p0 + (r >> 3);
                    float p = pacc[j][i] + bias;
                    float d = X[(size_t)pair * DD + n] - p;
                    rl += (0.5f * (LOG2PIF + d * d)) * MtQ[pair];
                }
            }
            rl *= 1.0f / (SS * BB);
            for (int off = 32; off; off >>= 1) rl += __shfl_down(rl, off, 64);
            if (lane == 0) red[w] = rl;
            __syncthreads();
            if (tid == 0) {
                float R = 0.f;
                for (int i = 0; i < 8; ++i) R += red[i];
                atomicAdd(loss + 0, R);
                atomicAdd(loss + 1, R);
            }
        }
    }
}

extern "C" void kernel_launch(void* const* d_in, const int* in_sizes, int n_in,
                              void* d_out, int out_size, void* d_ws, size_t ws_size,
                              hipStream_t stream) {
    (void)in_sizes; (void)n_in; (void)ws_size;
    const float* X         = (const float*)d_in[0];
    const float* M         = (const float*)d_in[1];
    const float* cov       = (const float*)d_in[2];
    const float* path_h    = (const float*)d_in[3];
    const float* path_hpos = (const float*)d_in[4];
    const float* noise     = (const float*)d_in[5];
    const float* drift_w1  = (const float*)d_in[6];
    const float* drift_b1  = (const float*)d_in[7];
    const float* drift_w2  = (const float*)d_in[8];
    const float* drift_b2  = (const float*)d_in[9];
    const float* diff_w1   = (const float*)d_in[10];
    const float* diff_b1   = (const float*)d_in[11];
    const float* diff_w2   = (const float*)d_in[12];
    const float* diff_b2   = (const float*)d_in[13];
    const float* p_w1      = (const float*)d_in[14];
    const float* p_b1      = (const float*)d_in[15];
    const float* p_w2      = (const float*)d_in[16];
    const float* p_b2      = (const float*)d_in[17];
    const float* cov_w1    = (const float*)d_in[18];
    const float* cov_b1    = (const float*)d_in[19];
    const float* cov_w2    = (const float*)d_in[20];
    const float* cov_b2    = (const float*)d_in[21];

    char* ws = (char*)d_ws;
    size_t off = 0;
    auto alloc = [&](size_t bytes) {
        void* p = ws + off;
        off = (off + bytes + 255) & ~(size_t)255;
        return p;
    };
    unsigned short* HprojQ  = (unsigned short*)alloc((size_t)T_STEPS * BB * HH * 2);
    unsigned short* HpprojQ = (unsigned short*)alloc((size_t)T_STEPS * BB * HH * 2);
    unsigned short* PprojQ  = (unsigned short*)alloc((size_t)T_STEPS * BB * HH * 2);
    float*          DiffQ   = (float*)alloc((size_t)T_STEPS * BB * ZZ * 4);
    float*          MtQ     = (float*)alloc((size_t)T_STEPS * BB * 4);
    unsigned short* zhist   = (unsigned short*)alloc((size_t)(T_STEPS + 1) * BB * SS * ZZ * 2);
    unsigned short* PW1z_p  = (unsigned short*)alloc((size_t)ZZ * HH * 2);
    unsigned short* PW2_p   = (unsigned short*)alloc((size_t)HH * DD * 2);
    unsigned short* W1h_p   = (unsigned short*)alloc((size_t)RR * HH * 2);
    unsigned short* PW1h_p  = (unsigned short*)alloc((size_t)RR * HH * 2);
    unsigned short* DW1_p   = (unsigned short*)alloc((size_t)RR * HH * 2);
    unsigned short* DW2_p   = (unsigned short*)alloc((size_t)HH * ZZ * 2);
    unsigned char*  W1z_f8  = (unsigned char*)alloc((size_t)ZZ * HH);
    unsigned char*  W2_f8   = (unsigned char*)alloc((size_t)HH * ZZ);
    unsigned int*   progress= (unsigned int*)alloc((size_t)BB * 4);

    hipMemsetAsync(d_out, 0, (size_t)out_size * sizeof(float), stream);
    hipMemsetAsync(progress, 0, (size_t)BB * 4, stream);

    auto packLaunch = [&](const float* src, int K, int N, unsigned short* dst) {
        int total = (K / 32) * (N / 16) * 64;
        pack_w<<<(total + 255) / 256, 256, 0, stream>>>(src, K, N, dst);
    };
    auto packLaunch8 = [&](const float* src, int K, int N, unsigned char* dst) {
        int total = (K / 32) * (N / 16) * 64;
        pack_w_fp8<<<(total + 255) / 256, 256, 0, stream>>>(src, K, N, dst);
    };
    packLaunch(p_w1 + (size_t)RR * HH,     ZZ, HH, PW1z_p);
    packLaunch(p_w2,                       HH, DD, PW2_p);
    packLaunch(drift_w1, RR, HH, W1h_p);
    packLaunch(p_w1,     RR, HH, PW1h_p);
    packLaunch(diff_w1,  RR, HH, DW1_p);
    packLaunch(diff_w2,  HH, ZZ, DW2_p);
    packLaunch8(drift_w1 + (size_t)RR * HH, ZZ, HH, W1z_f8);
    packLaunch8(drift_w2,                   HH, ZZ, W2_f8);

    mt_kernel<<<(T_STEPS * BB * 64) / 256, 256, 0, stream>>>(M, MtQ);

    precompute_kernel<<<(T_STEPS * BB) / 16, 256, 0, stream>>>(
        path_h, path_hpos, drift_b1, p_b1, diff_b1, diff_b2,
        W1h_p, PW1h_p, DW1_p, DW2_p, HprojQ, HpprojQ, PprojQ, DiffQ);

    float* outp = (float*)d_out;
    float* loss = outp + (size_t)BB * SS * ZZ;

    mega_kernel<<<BB + 192, 512, 0, stream>>>(
        cov, noise, drift_b2, cov_w1, cov_b1, cov_w2, cov_b2,
        W1z_f8, W2_f8, HpprojQ, HprojQ, DiffQ, zhist, outp, loss,
        PprojQ, X, MtQ, p_b2, PW1z_p, PW2_p, progress);
}